// Round 4
// baseline (1068.774 us; speedup 1.0000x reference)
//
#include <hip/hip_runtime.h>
#include <cstdint>
#include <cstddef>

#define NA 50000
#define NT 100000
#define FA 128
#define FT 64
#define HID 128
#define OUTF 64
#define HEADS 8
#define E1 500000
#define E2 250000
#define NTOT (2*NT + 2*NA)          // concatenated dst-node space [at|ta|aa|tt]
#define ETOT (2*E1 + 2*E2)          // concatenated edge space
#define NSH 8                       // CSR shards (== XCDs; blockIdx&7 heuristic)

typedef __attribute__((ext_vector_type(8))) short short8;
typedef __attribute__((ext_vector_type(4))) float f32x4;

static __device__ __forceinline__ ushort f2b(float f) {  // f32 -> bf16 RNE
  unsigned int u = __float_as_uint(f);
  return (ushort)((u + 0x7fffu + ((u >> 16) & 1u)) >> 16);
}
static __device__ __forceinline__ float b2f(ushort b) {
  return __uint_as_float(((unsigned int)b) << 16);
}

// ---------------- shared MFMA tile core: 64x64, BK=32, 4 waves -------------
__device__ __forceinline__ void gemm_tile(
    const float* __restrict__ A, const float* __restrict__ W,
    int N, int K, int M, int row0, int col0,
    ushort (*Als)[32], ushort (*Bls)[32], f32x4* acc)
{
  int t = threadIdx.x;
  int w = t >> 6, lane = t & 63;
  int l15 = lane & 15, l4 = lane >> 4;
  int arow = t >> 2, akp = (t & 3) << 3;    // A stage: 64 rows x 32 k
  int bcol = t & 63, bkb = t >> 6;          // B stage: 64 cols x 4 k-blocks
  bool aok = (row0 + arow) < N;
  const float* Ap = A + (size_t)(row0 + arow) * K + akp;

  for (int k0 = 0; k0 < K; k0 += 32) {
    union { ushort u[8]; uint4 v; } pa;
    if (aok) {
      float4 a0 = *reinterpret_cast<const float4*>(Ap + k0);
      float4 a1 = *reinterpret_cast<const float4*>(Ap + k0 + 4);
      pa.u[0]=f2b(a0.x); pa.u[1]=f2b(a0.y); pa.u[2]=f2b(a0.z); pa.u[3]=f2b(a0.w);
      pa.u[4]=f2b(a1.x); pa.u[5]=f2b(a1.y); pa.u[6]=f2b(a1.z); pa.u[7]=f2b(a1.w);
    } else {
      pa.v = make_uint4(0,0,0,0);
    }
    *reinterpret_cast<uint4*>(&Als[arow][akp]) = pa.v;
    union { ushort u[8]; uint4 v; } pb;
#pragma unroll
    for (int j = 0; j < 8; j++)
      pb.u[j] = f2b(W[(size_t)(k0 + bkb*8 + j) * M + col0 + bcol]);
    *reinterpret_cast<uint4*>(&Bls[bcol][(bkb ^ (bcol & 3)) * 8]) = pb.v;
    __syncthreads();
    short8 af = *reinterpret_cast<const short8*>(&Als[16*w + l15][l4 * 8]);
#pragma unroll
    for (int n = 0; n < 4; n++) {
      int bc = 16*n + l15;
      short8 bf = *reinterpret_cast<const short8*>(&Bls[bc][(l4 ^ (bc & 3)) * 8]);
      acc[n] = __builtin_amdgcn_mfma_f32_16x16x32_bf16(af, bf, acc[n], 0, 0, 0);
    }
    __syncthreads();
  }
}

// ====== z-projection GEMM + bf16 store + fused per-node alpha epilogue =====
// DD = head dim (16 for M=128, 8 for M=64); NV alpha vectors.
template<int NV, int DD>
__global__ __launch_bounds__(256) void zgemm_k(
    const float* __restrict__ A, const float* __restrict__ W,
    const float* __restrict__ bias,
    const float* __restrict__ v0, const float* __restrict__ v1,
    const float* __restrict__ v2, const float* __restrict__ v3,
    float* __restrict__ o0, float* __restrict__ o1,
    float* __restrict__ o2, float* __restrict__ o3,
    ushort* __restrict__ Cb, int N, int K, int M)
{
  __shared__ __align__(16) ushort Als[64][32];
  __shared__ __align__(16) ushort Bls[64][32];
  int t = threadIdx.x;
  int row0 = blockIdx.x * 64, col0 = blockIdx.y * 64;
  int w = t >> 6, lane = t & 63;
  int l15 = lane & 15, l4 = lane >> 4;
  f32x4 acc[4] = {{0.f,0.f,0.f,0.f},{0.f,0.f,0.f,0.f},
                  {0.f,0.f,0.f,0.f},{0.f,0.f,0.f,0.f}};
  gemm_tile(A, W, N, K, M, row0, col0, Als, Bls, acc);

  float vals[4][4];
#pragma unroll
  for (int n = 0; n < 4; n++) {
    int col = col0 + 16*n + l15;
    float bv = bias[col];
#pragma unroll
    for (int r = 0; r < 4; r++) {
      int row = row0 + 16*w + l4*4 + r;
      float v = acc[n][r] + bv;
      vals[n][r] = v;
      if (row < N) Cb[(size_t)row * M + col] = f2b(v);
    }
  }
  // alpha epilogue: head dot over DD cols via cross-lane reduce in l15 group
#pragma unroll
  for (int n = 0; n < 4; n++) {
    int head = (DD == 16) ? (blockIdx.y*4 + n) : (n*2 + (l15 >> 3));
    int vi = head * DD + (l15 & (DD - 1));
    float w0 = v0[vi];
    float w1 = (NV > 1) ? v1[vi] : 0.f;
    float w2 = (NV > 2) ? v2[vi] : 0.f;
    float w3 = (NV > 3) ? v3[vi] : 0.f;
#pragma unroll
    for (int r = 0; r < 4; r++) {
      int row = row0 + 16*w + l4*4 + r;
      float zv = vals[n][r];
      float a0 = zv * w0, a1 = zv * w1, a2 = zv * w2, a3 = zv * w3;
#pragma unroll
      for (int o = 1; o < DD; o <<= 1) {
        a0 += __shfl_xor(a0, o);
        if (NV > 1) a1 += __shfl_xor(a1, o);
        if (NV > 2) a2 += __shfl_xor(a2, o);
        if (NV > 3) a3 += __shfl_xor(a3, o);
      }
      if ((l15 & (DD - 1)) == 0 && row < N) {
        o0[(size_t)row * 8 + head] = a0;
        if (NV > 1) o1[(size_t)row * 8 + head] = a1;
        if (NV > 2) o2[(size_t)row * 8 + head] = a2;
        if (NV > 3) o3[(size_t)row * 8 + head] = a3;
      }
    }
  }
}

// ====== multi-task score GEMM: atomicAdd(scp[t], sum tanh(C+b)*q) ==========
__global__ __launch_bounds__(256) void score_k(
    const float* __restrict__ A0, const float* __restrict__ A1,
    const float* __restrict__ A2, const float* __restrict__ A3,
    const float* __restrict__ W, const float* __restrict__ bias,
    const float* __restrict__ qv, float* __restrict__ scp,
    int4 cum, int4 Ns, int4 Gs, int K, int M)
{
  __shared__ __align__(16) ushort Als[64][32];
  __shared__ __align__(16) ushort Bls[64][32];
  __shared__ float red[4];
  int b = blockIdx.x;
  int tsk, base, G, N; const float* A;
  if      (b < cum.x) { tsk=0; base=0;     G=Gs.x; N=Ns.x; A=A0; }
  else if (b < cum.y) { tsk=1; base=cum.x; G=Gs.y; N=Ns.y; A=A1; }
  else if (b < cum.z) { tsk=2; base=cum.y; G=Gs.z; N=Ns.z; A=A2; }
  else                { tsk=3; base=cum.z; G=Gs.w; N=Ns.w; A=A3; }
  int local = b - base;
  int row0 = (local % G) * 64, col0 = (local / G) * 64;
  int t = threadIdx.x;
  int w = t >> 6, lane = t & 63;
  int l15 = lane & 15, l4 = lane >> 4;
  f32x4 acc[4] = {{0.f,0.f,0.f,0.f},{0.f,0.f,0.f,0.f},
                  {0.f,0.f,0.f,0.f},{0.f,0.f,0.f,0.f}};
  gemm_tile(A, W, N, K, M, row0, col0, Als, Bls, acc);

  float local_s = 0.f;
#pragma unroll
  for (int n = 0; n < 4; n++) {
    int col = col0 + 16*n + l15;
    float bv = bias[col], qq = qv[col];
#pragma unroll
    for (int r = 0; r < 4; r++) {
      int row = row0 + 16*w + l4*4 + r;
      if (row < N) local_s += tanhf(acc[n][r] + bv) * qq;
    }
  }
#pragma unroll
  for (int o = 32; o > 0; o >>= 1) local_s += __shfl_xor(local_s, o);
  if (lane == 0) red[w] = local_s;
  __syncthreads();
  if (t == 0) atomicAdd(&scp[tsk], red[0] + red[1] + red[2] + red[3]);
}

// ============== XCD-sharded CSR build ======================================
__global__ void hist4_sh(const int* __restrict__ d0, const int* __restrict__ d1,
    const int* __restrict__ d2, const int* __restrict__ d3,
    int* __restrict__ cnt8, float* __restrict__ scp)
{
  if (blockIdx.x == 0 && threadIdx.x < 8) scp[threadIdx.x] = 0.f;
  int e = blockIdx.x * 256 + threadIdx.x;
  int sh = blockIdx.x & (NSH - 1);
  int d;
  if      (e < E1)          d = d0[e];
  else if (e < 2*E1)        d = d1[e - E1] + NT;
  else if (e < 2*E1 + E2)   d = d2[e - 2*E1] + NT + NA;
  else if (e < ETOT)        d = d3[e - 2*E1 - E2] + NT + 2*NA;
  else return;
  atomicAdd(&cnt8[sh * NTOT + d], 1);
}

__global__ void scatter_sh(const int* __restrict__ s0, const int* __restrict__ d0,
    const int* __restrict__ s1, const int* __restrict__ d1,
    const int* __restrict__ s2, const int* __restrict__ d2,
    const int* __restrict__ s3, const int* __restrict__ d3,
    int* __restrict__ cur8, int* __restrict__ ssrc)
{
  int e = blockIdx.x * 256 + threadIdx.x;
  int sh = blockIdx.x & (NSH - 1);
  int d, s;
  if      (e < E1)          { d = d0[e];                           s = s0[e]; }
  else if (e < 2*E1)        { d = d1[e - E1] + NT;                 s = s1[e - E1]; }
  else if (e < 2*E1 + E2)   { d = d2[e - 2*E1] + NT + NA;          s = s2[e - 2*E1]; }
  else if (e < ETOT)        { d = d3[e - 2*E1 - E2] + NT + 2*NA;   s = s3[e - 2*E1 - E2]; }
  else return;
  int p = atomicAdd(&cur8[sh * NTOT + d], 1);
  ssrc[p] = s;
}

// per-block inclusive scan (256 thr x 8) of in -> rp1 (=rp+1); totals -> bsum
__global__ __launch_bounds__(256) void scan_blk(const int* __restrict__ in,
    int* __restrict__ rp1, int* __restrict__ bsum, int n)
{
  __shared__ int sh[256];
  int base = blockIdx.x * 2048;
  int t = threadIdx.x;
  int v[8]; int s = 0;
#pragma unroll
  for (int k = 0; k < 8; k++) {
    int i = base + t * 8 + k;
    v[k] = (i < n) ? in[i] : 0; s += v[k];
  }
  sh[t] = s; __syncthreads();
  for (int o = 1; o < 256; o <<= 1) {
    int x = (t >= o) ? sh[t - o] : 0;
    __syncthreads(); sh[t] += x; __syncthreads();
  }
  int run = (t == 0) ? 0 : sh[t - 1];
  if (t == 255 && bsum) bsum[blockIdx.x] = sh[255];
#pragma unroll
  for (int k = 0; k < 8; k++) {
    int i = base + t * 8 + k;
    run += v[k];
    if (i < n) rp1[i] = run;
  }
}

// add inclusive block-offsets; writes rp[0]=0 and cursor init cur[i]=rp[i]
__global__ void scan_add2(int* __restrict__ rp, int* __restrict__ cur,
    const int* __restrict__ bsA, int n)
{
  int i = blockIdx.x * blockDim.x + threadIdx.x;
  if (i == 0) { rp[0] = 0; cur[0] = 0; }
  if (i < n) {
    int blk = i >> 11;
    int base = blk ? bsA[blk - 1] : 0;
    int v = rp[i + 1] + base;
    rp[i + 1] = v;
    if (i + 1 < n) cur[i + 1] = v;
  }
}

// =============== atomic-free GAT aggregation over 8 shard-segments =========
struct AggTask {
  int g0, Nd;
  const float* als; const float* ald;
  const ushort* z;  float* out;
};

template<int F>
__global__ __launch_bounds__(256) void agg_multi(const int* __restrict__ rp8,
    const int* __restrict__ ssrc, AggTask T0, AggTask T1, AggTask T2, AggTask T3,
    int c1, int c2, int c3)
{
  int b = blockIdx.x;
  AggTask T; int lb;
  if      (b < c1) { T = T0; lb = b; }
  else if (b < c2) { T = T1; lb = b - c1; }
  else if (b < c3) { T = T2; lb = b - c2; }
  else             { T = T3; lb = b - c3; }
  int wv = threadIdx.x >> 6, lane = threadIdx.x & 63;
  int n = lb * 4 + wv;
  if (n >= T.Nd) return;
  int g = T.g0 + n;
  int st[NSH], en[NSH];
#pragma unroll
  for (int s = 0; s < NSH; s++) {
    st[s] = rp8[s * NTOT + g];
    en[s] = rp8[s * NTOT + g + 1];
  }
  int h = lane >> 3, j = lane & 7;
  float ad_h = T.ald[(size_t)g - 0, (size_t)n * 8 + h];  // (comma op avoided below)
  ad_h = T.ald[(size_t)n * 8 + h];

  float m = -1e30f;
#pragma unroll
  for (int s = 0; s < NSH; s++) {
    for (int e0 = st[s]; e0 < en[s]; e0 += 8) {
      int e = e0 + j;
      if (e < en[s]) {
        int sn = ssrc[e];
        float a = T.als[(size_t)sn * 8 + h] + ad_h;
        a = a > 0.f ? a : 0.2f * a;
        m = fmaxf(m, a);
      }
    }
  }
  m = fmaxf(m, __shfl_xor(m, 1));
  m = fmaxf(m, __shfl_xor(m, 2));
  m = fmaxf(m, __shfl_xor(m, 4));

  float den = 0.f;
#pragma unroll
  for (int s = 0; s < NSH; s++) {
    for (int e0 = st[s]; e0 < en[s]; e0 += 8) {
      int e = e0 + j;
      if (e < en[s]) {
        int sn = ssrc[e];
        float a = T.als[(size_t)sn * 8 + h] + ad_h;
        a = a > 0.f ? a : 0.2f * a;
        den += __expf(a - m);
      }
    }
  }
  den += __shfl_xor(den, 1);
  den += __shfl_xor(den, 2);
  den += __shfl_xor(den, 4);
  float inv = 1.f / fmaxf(den, 1e-16f);

  if (F == 128) {
    float accx = 0.f, accy = 0.f;
#pragma unroll
    for (int s = 0; s < NSH; s++) {
      for (int e = st[s]; e < en[s]; e++) {
        int sn = ssrc[e];
        float a = T.als[(size_t)sn * 8 + h] + ad_h;
        a = a > 0.f ? a : 0.2f * a;
        float wgt = __expf(a - m) * inv;
        unsigned int zv = *reinterpret_cast<const unsigned int*>(T.z + (size_t)sn * 128 + lane * 2);
        accx = fmaf(wgt, __uint_as_float(zv << 16), accx);
        accy = fmaf(wgt, __uint_as_float(zv & 0xffff0000u), accy);
      }
    }
    float2 stv; stv.x = fmaxf(accx, 0.f); stv.y = fmaxf(accy, 0.f);
    *reinterpret_cast<float2*>(T.out + (size_t)n * 128 + lane * 2) = stv;
  } else {
    float acc = 0.f;
#pragma unroll
    for (int s = 0; s < NSH; s++) {
      for (int e = st[s]; e < en[s]; e++) {
        int sn = ssrc[e];
        float a = T.als[(size_t)sn * 8 + h] + ad_h;
        a = a > 0.f ? a : 0.2f * a;
        float wgt = __expf(a - m) * inv;
        acc = fmaf(wgt, b2f(T.z[(size_t)sn * 64 + lane]), acc);
      }
    }
    T.out[(size_t)n * 64 + lane] = fmaxf(acc, 0.f);
  }
}

// ---- semantic softmax (K=2) combine + LayerNorm + ReLU, 2 tasks, F=128 ----
__global__ __launch_bounds__(256) void combine2_k(
    const float* __restrict__ o00, const float* __restrict__ o01,
    const float* __restrict__ sc0, float invn0, float* __restrict__ out0, int N0,
    const float* __restrict__ o10, const float* __restrict__ o11,
    const float* __restrict__ sc1, float invn1, float* __restrict__ out1, int N1,
    const float* __restrict__ g, const float* __restrict__ bb)
{
  int c1 = (N0 + 3) / 4;
  int b = blockIdx.x;
  const float *o0, *o1, *sc; float invn; float* outp; int N, lb;
  if (b < c1) { o0=o00; o1=o01; sc=sc0; invn=invn0; outp=out0; N=N0; lb=b; }
  else        { o0=o10; o1=o11; sc=sc1; invn=invn1; outp=out1; N=N1; lb=b-c1; }
  int wv = threadIdx.x >> 6, lane = threadIdx.x & 63;
  int n = lb * 4 + wv;
  if (n >= N) return;
  float s0 = sc[0] * invn, s1 = sc[1] * invn;
  float mx = fmaxf(s0, s1);
  float e0 = __expf(s0 - mx), e1 = __expf(s1 - mx);
  float w0 = e0 / (e0 + e1), w1 = e1 / (e0 + e1);
  float x[2];
#pragma unroll
  for (int jj = 0; jj < 2; jj++) {
    int idx = lane + 64 * jj;
    x[jj] = w0 * o0[(size_t)n * 128 + idx] + w1 * o1[(size_t)n * 128 + idx];
  }
  float sum = x[0] + x[1];
#pragma unroll
  for (int o = 32; o > 0; o >>= 1) sum += __shfl_xor(sum, o);
  float mu = sum / 128.f;
  float vs = 0.f;
#pragma unroll
  for (int jj = 0; jj < 2; jj++) { float dd = x[jj] - mu; vs = fmaf(dd, dd, vs); }
#pragma unroll
  for (int o = 32; o > 0; o >>= 1) vs += __shfl_xor(vs, o);
  float rstd = rsqrtf(vs / 128.f + 1e-5f);
#pragma unroll
  for (int jj = 0; jj < 2; jj++) {
    int idx = lane + 64 * jj;
    float y = (x[jj] - mu) * rstd * g[idx] + bb[idx];
    outp[(size_t)n * 128 + idx] = fmaxf(y, 0.f);
  }
}

// ---- layer-2 combine + LN + ReLU + final linear [64]->[2], F=64 ----------
__global__ __launch_bounds__(256) void combine_final_k(
    const float* __restrict__ o0, const float* __restrict__ o1,
    const float* __restrict__ sc, float invn,
    const float* __restrict__ g, const float* __restrict__ bb,
    const float* __restrict__ lw, const float* __restrict__ lb,
    float* __restrict__ outp, int N)
{
  int wv = threadIdx.x >> 6, lane = threadIdx.x & 63;
  int n = blockIdx.x * 4 + wv;
  if (n >= N) return;
  float s0 = sc[0] * invn, s1 = sc[1] * invn;
  float mx = fmaxf(s0, s1);
  float e0 = __expf(s0 - mx), e1 = __expf(s1 - mx);
  float w0 = e0 / (e0 + e1), w1 = e1 / (e0 + e1);
  float x = w0 * o0[(size_t)n * 64 + lane] + w1 * o1[(size_t)n * 64 + lane];
  float sum = x;
#pragma unroll
  for (int o = 32; o > 0; o >>= 1) sum += __shfl_xor(sum, o);
  float mu = sum / 64.f;
  float dd = x - mu;
  float vs = dd * dd;
#pragma unroll
  for (int o = 32; o > 0; o >>= 1) vs += __shfl_xor(vs, o);
  float rstd = rsqrtf(vs / 64.f + 1e-5f);
  float y = fmaxf((x - mu) * rstd * g[lane] + bb[lane], 0.f);
  float p0 = y * lw[lane * 2 + 0];
  float p1 = y * lw[lane * 2 + 1];
#pragma unroll
  for (int o = 32; o > 0; o >>= 1) { p0 += __shfl_xor(p0, o); p1 += __shfl_xor(p1, o); }
  if (lane == 0) {
    outp[(size_t)n * 2 + 0] = p0 + lb[0];
    outp[(size_t)n * 2 + 1] = p1 + lb[1];
  }
}

extern "C" void kernel_launch(void* const* d_in, const int* in_sizes, int n_in,
                              void* d_out, int out_size, void* d_ws, size_t ws_size,
                              hipStream_t stream)
{
  (void)in_sizes; (void)n_in; (void)out_size;
  const float* x_a = (const float*)d_in[0];
  const float* x_t = (const float*)d_in[1];
  const int* eat_s = (const int*)d_in[2];
  const int* eat_d = (const int*)d_in[3];
  const int* eta_s = (const int*)d_in[4];
  const int* eta_d = (const int*)d_in[5];
  const int* eaa_s = (const int*)d_in[6];
  const int* eaa_d = (const int*)d_in[7];
  const int* ett_s = (const int*)d_in[8];
  const int* ett_d = (const int*)d_in[9];
  const float* W_a1 = (const float*)d_in[10]; const float* b_a1 = (const float*)d_in[11];
  const float* W_t1 = (const float*)d_in[12]; const float* b_t1 = (const float*)d_in[13];
  const float* as_at1 = (const float*)d_in[14]; const float* ad_at1 = (const float*)d_in[15];
  const float* as_ta1 = (const float*)d_in[16]; const float* ad_ta1 = (const float*)d_in[17];
  const float* as_aa1 = (const float*)d_in[18]; const float* ad_aa1 = (const float*)d_in[19];
  const float* as_tt1 = (const float*)d_in[20]; const float* ad_tt1 = (const float*)d_in[21];
  const float* k1_W = (const float*)d_in[22]; const float* k1_b = (const float*)d_in[23];
  const float* q1   = (const float*)d_in[24];
  const float* W_a2 = (const float*)d_in[25]; const float* b_a2 = (const float*)d_in[26];
  const float* W_t2 = (const float*)d_in[27]; const float* b_t2 = (const float*)d_in[28];
  const float* as_ta2 = (const float*)d_in[31]; const float* ad_ta2 = (const float*)d_in[32];
  const float* as_aa2 = (const float*)d_in[33]; const float* ad_aa2 = (const float*)d_in[34];
  const float* k2_W = (const float*)d_in[37]; const float* k2_b = (const float*)d_in[38];
  const float* q2   = (const float*)d_in[39];
  const float* ln1_g = (const float*)d_in[40]; const float* ln1_b = (const float*)d_in[41];
  const float* ln2_g = (const float*)d_in[42]; const float* ln2_b = (const float*)d_in[43];
  const float* lin_W = (const float*)d_in[44]; const float* lin_b = (const float*)d_in[45];

  char* ws = (char*)d_ws;
  size_t off = 0;
  auto alloc = [&](size_t bytes) {
    size_t o = off; off += (bytes + 255) & ~(size_t)255; return o;
  };
  size_t ZA1 = alloc((size_t)NA * HID * 2);     // bf16 z_a; layer2 za2 aliases
  size_t ZT1 = alloc((size_t)NT * HID * 2);     // bf16 z_t; layer2 zt2 aliases
  size_t OTA = alloc((size_t)NA * HID * 4);     // f32 -> xa1 in-place
  size_t OAA = alloc((size_t)NA * HID * 4);     // f32; layer2 o_ta2|o_aa2 alias
  size_t OAT = alloc((size_t)NT * HID * 4);     // f32 -> xt1 in-place
  size_t OTT = alloc((size_t)NT * HID * 4);
  size_t A_AS_AT = alloc((size_t)NA * 8 * 4);
  size_t A_AD_TA = alloc((size_t)NA * 8 * 4);
  size_t A_AS_AA = alloc((size_t)NA * 8 * 4);
  size_t A_AD_AA = alloc((size_t)NA * 8 * 4);
  size_t A_T_D_AT = alloc((size_t)NT * 8 * 4);
  size_t A_T_S_TA = alloc((size_t)NT * 8 * 4);
  size_t A_T_S_TT = alloc((size_t)NT * 8 * 4);
  size_t A_T_D_TT = alloc((size_t)NT * 8 * 4);
  // sharded CSR: rp8 [NSH][NTOT]+1 ; cur8 doubles as hist counts
  size_t RP8  = alloc(((size_t)NSH * NTOT + 1) * 4);
  size_t CUR8 = alloc((size_t)NSH * NTOT * 4);
  size_t SS   = alloc((size_t)ETOT * 4);
  size_t BSM  = alloc(1280 * 4);
  size_t SC   = alloc(256);                     // 6 score accumulators
  if (off > ws_size) return;                    // fail visibly

  ushort* za1 = (ushort*)(ws + ZA1);
  ushort* zt1 = (ushort*)(ws + ZT1);
  float* ota = (float*)(ws + OTA);
  float* oaa = (float*)(ws + OAA);
  float* oat = (float*)(ws + OAT);
  float* ott = (float*)(ws + OTT);
  float* aASAT = (float*)(ws + A_AS_AT);
  float* aADTA = (float*)(ws + A_AD_TA);
  float* aASAA = (float*)(ws + A_AS_AA);
  float* aADAA = (float*)(ws + A_AD_AA);
  float* aTDAT = (float*)(ws + A_T_D_AT);
  float* aTSTA = (float*)(ws + A_T_S_TA);
  float* aTSTT = (float*)(ws + A_T_S_TT);
  float* aTDTT = (float*)(ws + A_T_D_TT);
  int* rp8  = (int*)(ws + RP8);
  int* cur8 = (int*)(ws + CUR8);   // also hist counts
  int* ssrc = (int*)(ws + SS);
  int* bsum = (int*)(ws + BSM);
  float* scp = (float*)(ws + SC);
  // layer-2 aliases
  ushort* za2 = za1;                                  // [NA,64] bf16
  ushort* zt2 = zt1;                                  // [NT,64] bf16
  float* ota2 = oaa;                                  // [NA,64] f32
  float* oaa2 = (float*)(ws + OAA + (size_t)NA * OUTF * 4);  // [NA,64] f32

  const int GA = (NA + 63) / 64, GT = (NT + 63) / 64;
  const int EBL = (ETOT + 255) / 256;
  const int SCN = NSH * NTOT;                  // 2.4M scan elements
  const int SBL = (SCN + 2047) / 2048;         // 1172 scan blocks

  // ---- sharded CSR build ----
  hipMemsetAsync(cur8, 0, (size_t)SCN * 4, stream);
  hist4_sh<<<EBL, 256, 0, stream>>>(eat_d, eta_d, eaa_d, ett_d, cur8, scp);
  scan_blk<<<SBL, 256, 0, stream>>>(cur8, rp8 + 1, bsum, SCN);
  scan_blk<<<1, 256, 0, stream>>>(bsum, bsum, nullptr, SBL);
  scan_add2<<<(SCN + 255) / 256, 256, 0, stream>>>(rp8, cur8, bsum, SCN);
  scatter_sh<<<EBL, 256, 0, stream>>>(eat_s, eat_d, eta_s, eta_d,
                                      eaa_s, eaa_d, ett_s, ett_d, cur8, ssrc);

  // ============ Layer 1 ============
  zgemm_k<4,16><<<dim3(GA,2),256,0,stream>>>(x_a, W_a1, b_a1,
      as_at1, ad_ta1, as_aa1, ad_aa1, aASAT, aADTA, aASAA, aADAA,
      za1, NA, FA, HID);
  zgemm_k<4,16><<<dim3(GT,2),256,0,stream>>>(x_t, W_t1, b_t1,
      ad_at1, as_ta1, as_tt1, ad_tt1, aTDAT, aTSTA, aTSTT, aTDTT,
      zt1, NT, FT, HID);
  {
    AggTask T0{0,          NT, aASAT, aTDAT, za1, oat};
    AggTask T1{NT,         NA, aTSTA, aADTA, zt1, ota};
    AggTask T2{NT+NA,      NA, aASAA, aADAA, za1, oaa};
    AggTask T3{NT+2*NA,    NT, aTSTT, aTDTT, zt1, ott};
    agg_multi<128><<<2*(NT/4) + 2*(NA/4), 256, 0, stream>>>(rp8, ssrc,
        T0, T1, T2, T3, NT/4, NT/4 + NA/4, NT/4 + 2*(NA/4));
  }
  score_k<<<4*GA + 4*GT, 256, 0, stream>>>(ota, oaa, oat, ott,
      k1_W, k1_b, q1, scp,
      make_int4(2*GA, 4*GA, 4*GA + 2*GT, 4*GA + 4*GT),
      make_int4(NA, NA, NT, NT), make_int4(GA, GA, GT, GT), HID, HID);
  combine2_k<<<(NA/4) + (NT/4), 256, 0, stream>>>(
      ota, oaa, scp + 0, 1.f/NA, ota, NA,
      oat, ott, scp + 2, 1.f/NT, oat, NT, ln1_g, ln1_b);

  // ============ Layer 2 (only the address path feeds the output) ============
  zgemm_k<3,8><<<dim3(GA,1),256,0,stream>>>(ota, W_a2, b_a2,
      ad_ta2, as_aa2, ad_aa2, nullptr, aADTA, aASAA, aADAA, nullptr,
      za2, NA, HID, OUTF);
  zgemm_k<1,8><<<dim3(GT,1),256,0,stream>>>(oat, W_t2, b_t2,
      as_ta2, nullptr, nullptr, nullptr, aTSTA, nullptr, nullptr, nullptr,
      zt2, NT, HID, OUTF);
  {
    AggTask T0{NT,    NA, aTSTA, aADTA, zt2, ota2};
    AggTask T1{NT+NA, NA, aASAA, aADAA, za2, oaa2};
    agg_multi<64><<<2*(NA/4), 256, 0, stream>>>(rp8, ssrc,
        T0, T1, T1, T1, NA/4, 2*(NA/4), 2*(NA/4));
  }
  score_k<<<2*GA, 256, 0, stream>>>(ota2, oaa2, ota2, ota2,
      k2_W, k2_b, q2, scp + 4,
      make_int4(GA, 2*GA, 2*GA, 2*GA),
      make_int4(NA, NA, NA, NA), make_int4(GA, GA, GA, GA), OUTF, OUTF);
  combine_final_k<<<NA/4, 256, 0, stream>>>(ota2, oaa2, scp + 4, 1.f/NA,
      ln2_g, ln2_b, lin_W, lin_b, (float*)d_out, NA);
}

// Round 5
// 749.544 us; speedup vs baseline: 1.4259x; 1.4259x over previous
//
#include <hip/hip_runtime.h>
#include <cstdint>
#include <cstddef>

#define NA 50000
#define NT 100000
#define FA 128
#define FT 64
#define HID 128
#define OUTF 64
#define HEADS 8
#define E1 500000
#define E2 250000
#define NTOT (2*NT + 2*NA)          // concatenated dst-node space [at|ta|aa|tt]
#define ETOT (2*E1 + 2*E2)          // concatenated edge space

typedef __attribute__((ext_vector_type(8))) short short8;
typedef __attribute__((ext_vector_type(4))) float f32x4;

static __device__ __forceinline__ ushort f2b(float f) {  // f32 -> bf16 RNE
  unsigned int u = __float_as_uint(f);
  return (ushort)((u + 0x7fffu + ((u >> 16) & 1u)) >> 16);
}
static __device__ __forceinline__ float b2f(ushort b) {
  return __uint_as_float(((unsigned int)b) << 16);
}
static __device__ __forceinline__ float u2f_lo(unsigned int u) {
  return __uint_as_float(u << 16);
}
static __device__ __forceinline__ float u2f_hi(unsigned int u) {
  return __uint_as_float(u & 0xffff0000u);
}

// ---------------- shared MFMA tile core: 64x64, BK=32, 4 waves -------------
__device__ __forceinline__ void gemm_tile(
    const float* __restrict__ A, const float* __restrict__ W,
    int N, int K, int M, int row0, int col0,
    ushort (*Als)[32], ushort (*Bls)[32], f32x4* acc)
{
  int t = threadIdx.x;
  int w = t >> 6, lane = t & 63;
  int l15 = lane & 15, l4 = lane >> 4;
  int arow = t >> 2, akp = (t & 3) << 3;    // A stage: 64 rows x 32 k
  int bcol = t & 63, bkb = t >> 6;          // B stage: 64 cols x 4 k-blocks
  bool aok = (row0 + arow) < N;
  const float* Ap = A + (size_t)(row0 + arow) * K + akp;

  for (int k0 = 0; k0 < K; k0 += 32) {
    union { ushort u[8]; uint4 v; } pa;
    if (aok) {
      float4 a0 = *reinterpret_cast<const float4*>(Ap + k0);
      float4 a1 = *reinterpret_cast<const float4*>(Ap + k0 + 4);
      pa.u[0]=f2b(a0.x); pa.u[1]=f2b(a0.y); pa.u[2]=f2b(a0.z); pa.u[3]=f2b(a0.w);
      pa.u[4]=f2b(a1.x); pa.u[5]=f2b(a1.y); pa.u[6]=f2b(a1.z); pa.u[7]=f2b(a1.w);
    } else {
      pa.v = make_uint4(0,0,0,0);
    }
    *reinterpret_cast<uint4*>(&Als[arow][akp]) = pa.v;
    union { ushort u[8]; uint4 v; } pb;
#pragma unroll
    for (int j = 0; j < 8; j++)
      pb.u[j] = f2b(W[(size_t)(k0 + bkb*8 + j) * M + col0 + bcol]);
    *reinterpret_cast<uint4*>(&Bls[bcol][(bkb ^ (bcol & 3)) * 8]) = pb.v;
    __syncthreads();
    short8 af = *reinterpret_cast<const short8*>(&Als[16*w + l15][l4 * 8]);
#pragma unroll
    for (int n = 0; n < 4; n++) {
      int bc = 16*n + l15;
      short8 bf = *reinterpret_cast<const short8*>(&Bls[bc][(l4 ^ (bc & 3)) * 8]);
      acc[n] = __builtin_amdgcn_mfma_f32_16x16x32_bf16(af, bf, acc[n], 0, 0, 0);
    }
    __syncthreads();
  }
}

// ====== z-projection GEMM + bf16 store + fused per-node alpha epilogue =====
// DD = head dim (16 for M=128, 8 for M=64); NV alpha vectors.
template<int NV, int DD>
__global__ __launch_bounds__(256) void zgemm_k(
    const float* __restrict__ A, const float* __restrict__ W,
    const float* __restrict__ bias,
    const float* __restrict__ v0, const float* __restrict__ v1,
    const float* __restrict__ v2, const float* __restrict__ v3,
    float* __restrict__ o0, float* __restrict__ o1,
    float* __restrict__ o2, float* __restrict__ o3,
    ushort* __restrict__ Cb, int N, int K, int M)
{
  __shared__ __align__(16) ushort Als[64][32];
  __shared__ __align__(16) ushort Bls[64][32];
  int t = threadIdx.x;
  int row0 = blockIdx.x * 64, col0 = blockIdx.y * 64;
  int w = t >> 6, lane = t & 63;
  int l15 = lane & 15, l4 = lane >> 4;
  f32x4 acc[4] = {{0.f,0.f,0.f,0.f},{0.f,0.f,0.f,0.f},
                  {0.f,0.f,0.f,0.f},{0.f,0.f,0.f,0.f}};
  gemm_tile(A, W, N, K, M, row0, col0, Als, Bls, acc);

  float vals[4][4];
#pragma unroll
  for (int n = 0; n < 4; n++) {
    int col = col0 + 16*n + l15;
    float bv = bias[col];
#pragma unroll
    for (int r = 0; r < 4; r++) {
      int row = row0 + 16*w + l4*4 + r;
      float v = acc[n][r] + bv;
      vals[n][r] = v;
      if (row < N) Cb[(size_t)row * M + col] = f2b(v);
    }
  }
  // alpha epilogue: head dot over DD cols via cross-lane reduce in l15 group
#pragma unroll
  for (int n = 0; n < 4; n++) {
    int head = (DD == 16) ? (blockIdx.y*4 + n) : (n*2 + (l15 >> 3));
    int vi = head * DD + (l15 & (DD - 1));
    float w0 = v0[vi];
    float w1 = (NV > 1) ? v1[vi] : 0.f;
    float w2 = (NV > 2) ? v2[vi] : 0.f;
    float w3 = (NV > 3) ? v3[vi] : 0.f;
#pragma unroll
    for (int r = 0; r < 4; r++) {
      int row = row0 + 16*w + l4*4 + r;
      float zv = vals[n][r];
      float a0 = zv * w0, a1 = zv * w1, a2 = zv * w2, a3 = zv * w3;
#pragma unroll
      for (int o = 1; o < DD; o <<= 1) {
        a0 += __shfl_xor(a0, o);
        if (NV > 1) a1 += __shfl_xor(a1, o);
        if (NV > 2) a2 += __shfl_xor(a2, o);
        if (NV > 3) a3 += __shfl_xor(a3, o);
      }
      if ((l15 & (DD - 1)) == 0 && row < N) {
        o0[(size_t)row * 8 + head] = a0;
        if (NV > 1) o1[(size_t)row * 8 + head] = a1;
        if (NV > 2) o2[(size_t)row * 8 + head] = a2;
        if (NV > 3) o3[(size_t)row * 8 + head] = a3;
      }
    }
  }
}

// ====== multi-task score GEMM: atomicAdd(scp[t], sum tanh(C+b)*q) ==========
__global__ __launch_bounds__(256) void score_k(
    const float* __restrict__ A0, const float* __restrict__ A1,
    const float* __restrict__ A2, const float* __restrict__ A3,
    const float* __restrict__ W, const float* __restrict__ bias,
    const float* __restrict__ qv, float* __restrict__ scp,
    int4 cum, int4 Ns, int4 Gs, int K, int M)
{
  __shared__ __align__(16) ushort Als[64][32];
  __shared__ __align__(16) ushort Bls[64][32];
  __shared__ float red[4];
  int b = blockIdx.x;
  int tsk, base, G, N; const float* A;
  if      (b < cum.x) { tsk=0; base=0;     G=Gs.x; N=Ns.x; A=A0; }
  else if (b < cum.y) { tsk=1; base=cum.x; G=Gs.y; N=Ns.y; A=A1; }
  else if (b < cum.z) { tsk=2; base=cum.y; G=Gs.z; N=Ns.z; A=A2; }
  else                { tsk=3; base=cum.z; G=Gs.w; N=Ns.w; A=A3; }
  int local = b - base;
  int row0 = (local % G) * 64, col0 = (local / G) * 64;
  int t = threadIdx.x;
  int w = t >> 6, lane = t & 63;
  int l15 = lane & 15, l4 = lane >> 4;
  f32x4 acc[4] = {{0.f,0.f,0.f,0.f},{0.f,0.f,0.f,0.f},
                  {0.f,0.f,0.f,0.f},{0.f,0.f,0.f,0.f}};
  gemm_tile(A, W, N, K, M, row0, col0, Als, Bls, acc);

  float local_s = 0.f;
#pragma unroll
  for (int n = 0; n < 4; n++) {
    int col = col0 + 16*n + l15;
    float bv = bias[col], qq = qv[col];
#pragma unroll
    for (int r = 0; r < 4; r++) {
      int row = row0 + 16*w + l4*4 + r;
      if (row < N) local_s += tanhf(acc[n][r] + bv) * qq;
    }
  }
#pragma unroll
  for (int o = 32; o > 0; o >>= 1) local_s += __shfl_xor(local_s, o);
  if (lane == 0) red[w] = local_s;
  __syncthreads();
  if (t == 0) atomicAdd(&scp[tsk], red[0] + red[1] + red[2] + red[3]);
}

// ============== unsharded CSR build (counting sort by concat dst) ==========
__global__ void hist4(const int* __restrict__ d0, const int* __restrict__ d1,
    const int* __restrict__ d2, const int* __restrict__ d3,
    int* __restrict__ cnt, float* __restrict__ scp)
{
  if (blockIdx.x == 0 && threadIdx.x < 8) scp[threadIdx.x] = 0.f;
  int e = blockIdx.x * 256 + threadIdx.x;
  int d;
  if      (e < E1)          d = d0[e];
  else if (e < 2*E1)        d = d1[e - E1] + NT;
  else if (e < 2*E1 + E2)   d = d2[e - 2*E1] + NT + NA;
  else if (e < ETOT)        d = d3[e - 2*E1 - E2] + NT + 2*NA;
  else return;
  atomicAdd(&cnt[d], 1);
}

__global__ void scatter4(const int* __restrict__ s0, const int* __restrict__ d0,
    const int* __restrict__ s1, const int* __restrict__ d1,
    const int* __restrict__ s2, const int* __restrict__ d2,
    const int* __restrict__ s3, const int* __restrict__ d3,
    int* __restrict__ cur, int* __restrict__ ssrc)
{
  int e = blockIdx.x * 256 + threadIdx.x;
  int d, s;
  if      (e < E1)          { d = d0[e];                           s = s0[e]; }
  else if (e < 2*E1)        { d = d1[e - E1] + NT;                 s = s1[e - E1]; }
  else if (e < 2*E1 + E2)   { d = d2[e - 2*E1] + NT + NA;          s = s2[e - 2*E1]; }
  else if (e < ETOT)        { d = d3[e - 2*E1 - E2] + NT + 2*NA;   s = s3[e - 2*E1 - E2]; }
  else return;
  int p = atomicAdd(&cur[d], 1);
  ssrc[p] = s;
}

// per-block inclusive scan (256 thr x 8) of in -> rp1 (=rp+1); totals -> bsum
__global__ __launch_bounds__(256) void scan_blk(const int* __restrict__ in,
    int* __restrict__ rp1, int* __restrict__ bsum, int n)
{
  __shared__ int sh[256];
  int base = blockIdx.x * 2048;
  int t = threadIdx.x;
  int v[8]; int s = 0;
#pragma unroll
  for (int k = 0; k < 8; k++) {
    int i = base + t * 8 + k;
    v[k] = (i < n) ? in[i] : 0; s += v[k];
  }
  sh[t] = s; __syncthreads();
  for (int o = 1; o < 256; o <<= 1) {
    int x = (t >= o) ? sh[t - o] : 0;
    __syncthreads(); sh[t] += x; __syncthreads();
  }
  int run = (t == 0) ? 0 : sh[t - 1];
  if (t == 255 && bsum) bsum[blockIdx.x] = sh[255];
#pragma unroll
  for (int k = 0; k < 8; k++) {
    int i = base + t * 8 + k;
    run += v[k];
    if (i < n) rp1[i] = run;
  }
}

// add inclusive block-offsets; writes rp[0]=0 and cursor init cur[i]=rp[i]
__global__ void scan_add2(int* __restrict__ rp, int* __restrict__ cur,
    const int* __restrict__ bsA, int n)
{
  int i = blockIdx.x * blockDim.x + threadIdx.x;
  if (i == 0) { rp[0] = 0; cur[0] = 0; }
  if (i < n) {
    int blk = i >> 11;
    int base = blk ? bsA[blk - 1] : 0;
    int v = rp[i + 1] + base;
    rp[i + 1] = v;
    if (i + 1 < n) cur[i + 1] = v;
  }
}

// =============== atomic-free GAT aggregation, one wave per dst node ========
// softmax: lane = h*8+j (8 edges x 8 heads in parallel).
// accumulate: wave split into edge-groups (4 groups x 16 lanes for F=128,
// 8 x 8 for F=64) -> 4/8 z-row gathers in flight; register accumulate;
// cross-group shfl reduce; coalesced relu store.
struct AggTask {
  int g0, Nd;
  const float* als; const float* ald;
  const ushort* z;  float* out;
};

template<int F>
__global__ __launch_bounds__(256) void agg_multi(const int* __restrict__ rp,
    const int* __restrict__ ssrc, AggTask T0, AggTask T1, AggTask T2, AggTask T3,
    int c1, int c2, int c3)
{
  int b = blockIdx.x;
  AggTask T; int lb;
  if      (b < c1) { T = T0; lb = b; }
  else if (b < c2) { T = T1; lb = b - c1; }
  else if (b < c3) { T = T2; lb = b - c2; }
  else             { T = T3; lb = b - c3; }
  int wv = threadIdx.x >> 6, lane = threadIdx.x & 63;
  int n = lb * 4 + wv;
  if (n >= T.Nd) return;
  int g = T.g0 + n;
  int start = rp[g], end = rp[g + 1];
  int h = lane >> 3, j = lane & 7;
  float ad_h = T.ald[(size_t)n * 8 + h];

  float m = -1e30f;
  for (int e0 = start; e0 < end; e0 += 8) {
    int e = e0 + j;
    if (e < end) {
      int sn = ssrc[e];
      float a = T.als[(size_t)sn * 8 + h] + ad_h;
      a = a > 0.f ? a : 0.2f * a;
      m = fmaxf(m, a);
    }
  }
  m = fmaxf(m, __shfl_xor(m, 1));
  m = fmaxf(m, __shfl_xor(m, 2));
  m = fmaxf(m, __shfl_xor(m, 4));

  float den = 0.f;
  for (int e0 = start; e0 < end; e0 += 8) {
    int e = e0 + j;
    if (e < end) {
      int sn = ssrc[e];
      float a = T.als[(size_t)sn * 8 + h] + ad_h;
      a = a > 0.f ? a : 0.2f * a;
      den += __expf(a - m);
    }
  }
  den += __shfl_xor(den, 1);
  den += __shfl_xor(den, 2);
  den += __shfl_xor(den, 4);
  float inv = 1.f / fmaxf(den, 1e-16f);

  if (F == 128) {
    int lg = lane & 15, grp = lane >> 4;          // 4 edge-groups x 16 lanes
    int hh = lg >> 1;                             // head of features [lg*8,lg*8+8)
    float mh   = __shfl(m, hh * 8);
    float invh = __shfl(inv, hh * 8);
    float adh  = __shfl(ad_h, hh * 8);
    float acc[8] = {};
    for (int e0 = start; e0 < end; e0 += 4) {
      int e = e0 + grp;
      if (e < end) {
        int sn = ssrc[e];
        float a = T.als[(size_t)sn * 8 + hh] + adh;
        a = a > 0.f ? a : 0.2f * a;
        float wgt = __expf(a - mh) * invh;
        uint4 zv = *reinterpret_cast<const uint4*>(T.z + (size_t)sn * 128 + lg * 8);
        acc[0] = fmaf(wgt, u2f_lo(zv.x), acc[0]);
        acc[1] = fmaf(wgt, u2f_hi(zv.x), acc[1]);
        acc[2] = fmaf(wgt, u2f_lo(zv.y), acc[2]);
        acc[3] = fmaf(wgt, u2f_hi(zv.y), acc[3]);
        acc[4] = fmaf(wgt, u2f_lo(zv.z), acc[4]);
        acc[5] = fmaf(wgt, u2f_hi(zv.z), acc[5]);
        acc[6] = fmaf(wgt, u2f_lo(zv.w), acc[6]);
        acc[7] = fmaf(wgt, u2f_hi(zv.w), acc[7]);
      }
    }
#pragma unroll
    for (int k = 0; k < 8; k++) {
      acc[k] += __shfl_xor(acc[k], 16);
      acc[k] += __shfl_xor(acc[k], 32);
    }
    if (grp == 0) {
      float4 s0, s1;
      s0.x = fmaxf(acc[0], 0.f); s0.y = fmaxf(acc[1], 0.f);
      s0.z = fmaxf(acc[2], 0.f); s0.w = fmaxf(acc[3], 0.f);
      s1.x = fmaxf(acc[4], 0.f); s1.y = fmaxf(acc[5], 0.f);
      s1.z = fmaxf(acc[6], 0.f); s1.w = fmaxf(acc[7], 0.f);
      float* op = T.out + (size_t)n * 128 + lg * 8;
      *reinterpret_cast<float4*>(op) = s0;
      *reinterpret_cast<float4*>(op + 4) = s1;
    }
  } else {
    int lg = lane & 7, grp = lane >> 3;           // 8 edge-groups x 8 lanes
    int hh = lg;                                  // head == lg (D=8)
    float mh   = __shfl(m, hh * 8);
    float invh = __shfl(inv, hh * 8);
    float adh  = __shfl(ad_h, hh * 8);
    float acc[8] = {};
    for (int e0 = start; e0 < end; e0 += 8) {
      int e = e0 + grp;
      if (e < end) {
        int sn = ssrc[e];
        float a = T.als[(size_t)sn * 8 + hh] + adh;
        a = a > 0.f ? a : 0.2f * a;
        float wgt = __expf(a - mh) * invh;
        uint4 zv = *reinterpret_cast<const uint4*>(T.z + (size_t)sn * 64 + lg * 8);
        acc[0] = fmaf(wgt, u2f_lo(zv.x), acc[0]);
        acc[1] = fmaf(wgt, u2f_hi(zv.x), acc[1]);
        acc[2] = fmaf(wgt, u2f_lo(zv.y), acc[2]);
        acc[3] = fmaf(wgt, u2f_hi(zv.y), acc[3]);
        acc[4] = fmaf(wgt, u2f_lo(zv.z), acc[4]);
        acc[5] = fmaf(wgt, u2f_hi(zv.z), acc[5]);
        acc[6] = fmaf(wgt, u2f_lo(zv.w), acc[6]);
        acc[7] = fmaf(wgt, u2f_hi(zv.w), acc[7]);
      }
    }
#pragma unroll
    for (int k = 0; k < 8; k++) {
      acc[k] += __shfl_xor(acc[k], 8);
      acc[k] += __shfl_xor(acc[k], 16);
      acc[k] += __shfl_xor(acc[k], 32);
    }
    if (grp == 0) {
      float4 s0, s1;
      s0.x = fmaxf(acc[0], 0.f); s0.y = fmaxf(acc[1], 0.f);
      s0.z = fmaxf(acc[2], 0.f); s0.w = fmaxf(acc[3], 0.f);
      s1.x = fmaxf(acc[4], 0.f); s1.y = fmaxf(acc[5], 0.f);
      s1.z = fmaxf(acc[6], 0.f); s1.w = fmaxf(acc[7], 0.f);
      float* op = T.out + (size_t)n * 64 + lg * 8;
      *reinterpret_cast<float4*>(op) = s0;
      *reinterpret_cast<float4*>(op + 4) = s1;
    }
  }
}

// ---- semantic softmax (K=2) combine + LayerNorm + ReLU, 2 tasks, F=128 ----
__global__ __launch_bounds__(256) void combine2_k(
    const float* __restrict__ o00, const float* __restrict__ o01,
    const float* __restrict__ sc0, float invn0, float* __restrict__ out0, int N0,
    const float* __restrict__ o10, const float* __restrict__ o11,
    const float* __restrict__ sc1, float invn1, float* __restrict__ out1, int N1,
    const float* __restrict__ g, const float* __restrict__ bb)
{
  int c1 = (N0 + 3) / 4;
  int b = blockIdx.x;
  const float *o0, *o1, *sc; float invn; float* outp; int N, lb;
  if (b < c1) { o0=o00; o1=o01; sc=sc0; invn=invn0; outp=out0; N=N0; lb=b; }
  else        { o0=o10; o1=o11; sc=sc1; invn=invn1; outp=out1; N=N1; lb=b-c1; }
  int wv = threadIdx.x >> 6, lane = threadIdx.x & 63;
  int n = lb * 4 + wv;
  if (n >= N) return;
  float s0 = sc[0] * invn, s1 = sc[1] * invn;
  float mx = fmaxf(s0, s1);
  float e0 = __expf(s0 - mx), e1 = __expf(s1 - mx);
  float w0 = e0 / (e0 + e1), w1 = e1 / (e0 + e1);
  float x[2];
#pragma unroll
  for (int jj = 0; jj < 2; jj++) {
    int idx = lane + 64 * jj;
    x[jj] = w0 * o0[(size_t)n * 128 + idx] + w1 * o1[(size_t)n * 128 + idx];
  }
  float sum = x[0] + x[1];
#pragma unroll
  for (int o = 32; o > 0; o >>= 1) sum += __shfl_xor(sum, o);
  float mu = sum / 128.f;
  float vs = 0.f;
#pragma unroll
  for (int jj = 0; jj < 2; jj++) { float dd = x[jj] - mu; vs = fmaf(dd, dd, vs); }
#pragma unroll
  for (int o = 32; o > 0; o >>= 1) vs += __shfl_xor(vs, o);
  float rstd = rsqrtf(vs / 128.f + 1e-5f);
#pragma unroll
  for (int jj = 0; jj < 2; jj++) {
    int idx = lane + 64 * jj;
    float y = (x[jj] - mu) * rstd * g[idx] + bb[idx];
    outp[(size_t)n * 128 + idx] = fmaxf(y, 0.f);
  }
}

// ---- layer-2 combine + LN + ReLU + final linear [64]->[2], F=64 ----------
__global__ __launch_bounds__(256) void combine_final_k(
    const float* __restrict__ o0, const float* __restrict__ o1,
    const float* __restrict__ sc, float invn,
    const float* __restrict__ g, const float* __restrict__ bb,
    const float* __restrict__ lw, const float* __restrict__ lb,
    float* __restrict__ outp, int N)
{
  int wv = threadIdx.x >> 6, lane = threadIdx.x & 63;
  int n = blockIdx.x * 4 + wv;
  if (n >= N) return;
  float s0 = sc[0] * invn, s1 = sc[1] * invn;
  float mx = fmaxf(s0, s1);
  float e0 = __expf(s0 - mx), e1 = __expf(s1 - mx);
  float w0 = e0 / (e0 + e1), w1 = e1 / (e0 + e1);
  float x = w0 * o0[(size_t)n * 64 + lane] + w1 * o1[(size_t)n * 64 + lane];
  float sum = x;
#pragma unroll
  for (int o = 32; o > 0; o >>= 1) sum += __shfl_xor(sum, o);
  float mu = sum / 64.f;
  float dd = x - mu;
  float vs = dd * dd;
#pragma unroll
  for (int o = 32; o > 0; o >>= 1) vs += __shfl_xor(vs, o);
  float rstd = rsqrtf(vs / 64.f + 1e-5f);
  float y = fmaxf((x - mu) * rstd * g[lane] + bb[lane], 0.f);
  float p0 = y * lw[lane * 2 + 0];
  float p1 = y * lw[lane * 2 + 1];
#pragma unroll
  for (int o = 32; o > 0; o >>= 1) { p0 += __shfl_xor(p0, o); p1 += __shfl_xor(p1, o); }
  if (lane == 0) {
    outp[(size_t)n * 2 + 0] = p0 + lb[0];
    outp[(size_t)n * 2 + 1] = p1 + lb[1];
  }
}

extern "C" void kernel_launch(void* const* d_in, const int* in_sizes, int n_in,
                              void* d_out, int out_size, void* d_ws, size_t ws_size,
                              hipStream_t stream)
{
  (void)in_sizes; (void)n_in; (void)out_size;
  const float* x_a = (const float*)d_in[0];
  const float* x_t = (const float*)d_in[1];
  const int* eat_s = (const int*)d_in[2];
  const int* eat_d = (const int*)d_in[3];
  const int* eta_s = (const int*)d_in[4];
  const int* eta_d = (const int*)d_in[5];
  const int* eaa_s = (const int*)d_in[6];
  const int* eaa_d = (const int*)d_in[7];
  const int* ett_s = (const int*)d_in[8];
  const int* ett_d = (const int*)d_in[9];
  const float* W_a1 = (const float*)d_in[10]; const float* b_a1 = (const float*)d_in[11];
  const float* W_t1 = (const float*)d_in[12]; const float* b_t1 = (const float*)d_in[13];
  const float* as_at1 = (const float*)d_in[14]; const float* ad_at1 = (const float*)d_in[15];
  const float* as_ta1 = (const float*)d_in[16]; const float* ad_ta1 = (const float*)d_in[17];
  const float* as_aa1 = (const float*)d_in[18]; const float* ad_aa1 = (const float*)d_in[19];
  const float* as_tt1 = (const float*)d_in[20]; const float* ad_tt1 = (const float*)d_in[21];
  const float* k1_W = (const float*)d_in[22]; const float* k1_b = (const float*)d_in[23];
  const float* q1   = (const float*)d_in[24];
  const float* W_a2 = (const float*)d_in[25]; const float* b_a2 = (const float*)d_in[26];
  const float* W_t2 = (const float*)d_in[27]; const float* b_t2 = (const float*)d_in[28];
  const float* as_ta2 = (const float*)d_in[31]; const float* ad_ta2 = (const float*)d_in[32];
  const float* as_aa2 = (const float*)d_in[33]; const float* ad_aa2 = (const float*)d_in[34];
  const float* k2_W = (const float*)d_in[37]; const float* k2_b = (const float*)d_in[38];
  const float* q2   = (const float*)d_in[39];
  const float* ln1_g = (const float*)d_in[40]; const float* ln1_b = (const float*)d_in[41];
  const float* ln2_g = (const float*)d_in[42]; const float* ln2_b = (const float*)d_in[43];
  const float* lin_W = (const float*)d_in[44]; const float* lin_b = (const float*)d_in[45];

  char* ws = (char*)d_ws;
  size_t off = 0;
  auto alloc = [&](size_t bytes) {
    size_t o = off; off += (bytes + 255) & ~(size_t)255; return o;
  };
  size_t ZA1 = alloc((size_t)NA * HID * 2);     // bf16 z_a; layer2 za2 aliases
  size_t ZT1 = alloc((size_t)NT * HID * 2);     // bf16 z_t; layer2 zt2 aliases
  size_t OTA = alloc((size_t)NA * HID * 4);     // f32 -> xa1 in-place
  size_t OAA = alloc((size_t)NA * HID * 4);     // f32; layer2 o_ta2|o_aa2 alias
  size_t OAT = alloc((size_t)NT * HID * 4);     // f32 -> xt1 in-place
  size_t OTT = alloc((size_t)NT * HID * 4);
  size_t A_AS_AT = alloc((size_t)NA * 8 * 4);
  size_t A_AD_TA = alloc((size_t)NA * 8 * 4);
  size_t A_AS_AA = alloc((size_t)NA * 8 * 4);
  size_t A_AD_AA = alloc((size_t)NA * 8 * 4);
  size_t A_T_D_AT = alloc((size_t)NT * 8 * 4);
  size_t A_T_S_TA = alloc((size_t)NT * 8 * 4);
  size_t A_T_S_TT = alloc((size_t)NT * 8 * 4);
  size_t A_T_D_TT = alloc((size_t)NT * 8 * 4);
  // unsharded CSR
  size_t RP  = alloc((size_t)(NTOT + 1) * 4);
  size_t CUR = alloc((size_t)NTOT * 4);         // doubles as hist counts
  size_t SS  = alloc((size_t)ETOT * 4);
  size_t BSM = alloc(256 * 4);
  size_t SC  = alloc(256);                      // 6 score accumulators
  if (off > ws_size) return;                    // fail visibly

  ushort* za1 = (ushort*)(ws + ZA1);
  ushort* zt1 = (ushort*)(ws + ZT1);
  float* ota = (float*)(ws + OTA);
  float* oaa = (float*)(ws + OAA);
  float* oat = (float*)(ws + OAT);
  float* ott = (float*)(ws + OTT);
  float* aASAT = (float*)(ws + A_AS_AT);
  float* aADTA = (float*)(ws + A_AD_TA);
  float* aASAA = (float*)(ws + A_AS_AA);
  float* aADAA = (float*)(ws + A_AD_AA);
  float* aTDAT = (float*)(ws + A_T_D_AT);
  float* aTSTA = (float*)(ws + A_T_S_TA);
  float* aTSTT = (float*)(ws + A_T_S_TT);
  float* aTDTT = (float*)(ws + A_T_D_TT);
  int* rp   = (int*)(ws + RP);
  int* cur  = (int*)(ws + CUR);
  int* ssrc = (int*)(ws + SS);
  int* bsum = (int*)(ws + BSM);
  float* scp = (float*)(ws + SC);
  // layer-2 aliases
  ushort* za2 = za1;                                  // [NA,64] bf16
  ushort* zt2 = zt1;                                  // [NT,64] bf16
  float* ota2 = oaa;                                  // [NA,64] f32
  float* oaa2 = (float*)(ws + OAA + (size_t)NA * OUTF * 4);  // [NA,64] f32

  const int GA = (NA + 63) / 64, GT = (NT + 63) / 64;
  const int EBL = (ETOT + 255) / 256;
  const int SBL = (NTOT + 2047) / 2048;        // 147 scan blocks

  // ---- unsharded CSR build ----
  hipMemsetAsync(cur, 0, (size_t)NTOT * 4, stream);
  hist4<<<EBL, 256, 0, stream>>>(eat_d, eta_d, eaa_d, ett_d, cur, scp);
  scan_blk<<<SBL, 256, 0, stream>>>(cur, rp + 1, bsum, NTOT);
  scan_blk<<<1, 256, 0, stream>>>(bsum, bsum, nullptr, SBL);
  scan_add2<<<(NTOT + 255) / 256, 256, 0, stream>>>(rp, cur, bsum, NTOT);
  scatter4<<<EBL, 256, 0, stream>>>(eat_s, eat_d, eta_s, eta_d,
                                    eaa_s, eaa_d, ett_s, ett_d, cur, ssrc);

  // ============ Layer 1 ============
  zgemm_k<4,16><<<dim3(GA,2),256,0,stream>>>(x_a, W_a1, b_a1,
      as_at1, ad_ta1, as_aa1, ad_aa1, aASAT, aADTA, aASAA, aADAA,
      za1, NA, FA, HID);
  zgemm_k<4,16><<<dim3(GT,2),256,0,stream>>>(x_t, W_t1, b_t1,
      ad_at1, as_ta1, as_tt1, ad_tt1, aTDAT, aTSTA, aTSTT, aTDTT,
      zt1, NT, FT, HID);
  {
    AggTask T0{0,          NT, aASAT, aTDAT, za1, oat};
    AggTask T1{NT,         NA, aTSTA, aADTA, zt1, ota};
    AggTask T2{NT+NA,      NA, aASAA, aADAA, za1, oaa};
    AggTask T3{NT+2*NA,    NT, aTSTT, aTDTT, zt1, ott};
    agg_multi<128><<<2*(NT/4) + 2*(NA/4), 256, 0, stream>>>(rp, ssrc,
        T0, T1, T2, T3, NT/4, NT/4 + NA/4, NT/4 + 2*(NA/4));
  }
  score_k<<<4*GA + 4*GT, 256, 0, stream>>>(ota, oaa, oat, ott,
      k1_W, k1_b, q1, scp,
      make_int4(2*GA, 4*GA, 4*GA + 2*GT, 4*GA + 4*GT),
      make_int4(NA, NA, NT, NT), make_int4(GA, GA, GT, GT), HID, HID);
  combine2_k<<<(NA/4) + (NT/4), 256, 0, stream>>>(
      ota, oaa, scp + 0, 1.f/NA, ota, NA,
      oat, ott, scp + 2, 1.f/NT, oat, NT, ln1_g, ln1_b);

  // ============ Layer 2 (only the address path feeds the output) ============
  zgemm_k<3,8><<<dim3(GA,1),256,0,stream>>>(ota, W_a2, b_a2,
      ad_ta2, as_aa2, ad_aa2, nullptr, aADTA, aASAA, aADAA, nullptr,
      za2, NA, HID, OUTF);
  zgemm_k<1,8><<<dim3(GT,1),256,0,stream>>>(oat, W_t2, b_t2,
      as_ta2, nullptr, nullptr, nullptr, aTSTA, nullptr, nullptr, nullptr,
      zt2, NT, HID, OUTF);
  {
    AggTask T0{NT,    NA, aTSTA, aADTA, zt2, ota2};
    AggTask T1{NT+NA, NA, aASAA, aADAA, za2, oaa2};
    agg_multi<64><<<2*(NA/4), 256, 0, stream>>>(rp, ssrc,
        T0, T1, T1, T1, NA/4, 2*(NA/4), 2*(NA/4));
  }
  score_k<<<2*GA, 256, 0, stream>>>(ota2, oaa2, ota2, ota2,
      k2_W, k2_b, q2, scp + 4,
      make_int4(GA, 2*GA, 2*GA, 2*GA),
      make_int4(NA, NA, NA, NA), make_int4(GA, GA, GA, GA), OUTF, OUTF);
  combine_final_k<<<NA/4, 256, 0, stream>>>(ota2, oaa2, scp + 4, 1.f/NA,
      ln2_g, ln2_b, lin_W, lin_b, (float*)d_out, NA);
}

// Round 6
// 719.095 us; speedup vs baseline: 1.4863x; 1.0423x over previous
//
#include <hip/hip_runtime.h>
#include <cstdint>
#include <cstddef>
#include <type_traits>

#define NA 50000
#define NT 100000
#define FA 128
#define FT 64
#define HID 128
#define OUTF 64
#define HEADS 8
#define E1 500000
#define E2 250000
#define NTOT (2*NT + 2*NA)          // concatenated dst-node space [at|ta|aa|tt]
#define ETOT (2*E1 + 2*E2)          // concatenated edge space
#define NSH 8                       // CSR build shards (== XCDs heuristic)

typedef __attribute__((ext_vector_type(8))) short short8;
typedef __attribute__((ext_vector_type(4))) float f32x4;

static __device__ __forceinline__ ushort f2b(float f) {  // f32 -> bf16 RNE
  unsigned int u = __float_as_uint(f);
  return (ushort)((u + 0x7fffu + ((u >> 16) & 1u)) >> 16);
}
static __device__ __forceinline__ float b2f(ushort b) {
  return __uint_as_float(((unsigned int)b) << 16);
}
static __device__ __forceinline__ float u2f_lo(unsigned int u) {
  return __uint_as_float(u << 16);
}
static __device__ __forceinline__ float u2f_hi(unsigned int u) {
  return __uint_as_float(u & 0xffff0000u);
}

// ---------------- shared MFMA tile core: 64x64, BK=32, 4 waves -------------
// AT = float (convert while staging) or ushort (bf16, direct copy)
template<typename AT>
__device__ __forceinline__ void gemm_tile(
    const AT* __restrict__ A, const float* __restrict__ W,
    int N, int K, int M, int row0, int col0,
    ushort (*Als)[32], ushort (*Bls)[32], f32x4* acc)
{
  int t = threadIdx.x;
  int w = t >> 6, lane = t & 63;
  int l15 = lane & 15, l4 = lane >> 4;
  int arow = t >> 2, akp = (t & 3) << 3;    // A stage: 64 rows x 32 k
  int bcol = t & 63, bkb = t >> 6;          // B stage: 64 cols x 4 k-blocks
  bool aok = (row0 + arow) < N;
  const AT* Ap = A + (size_t)(row0 + arow) * K + akp;

  for (int k0 = 0; k0 < K; k0 += 32) {
    union { ushort u[8]; uint4 v; } pa;
    if (aok) {
      if constexpr (std::is_same<AT, float>::value) {
        float4 a0 = *reinterpret_cast<const float4*>(Ap + k0);
        float4 a1 = *reinterpret_cast<const float4*>(Ap + k0 + 4);
        pa.u[0]=f2b(a0.x); pa.u[1]=f2b(a0.y); pa.u[2]=f2b(a0.z); pa.u[3]=f2b(a0.w);
        pa.u[4]=f2b(a1.x); pa.u[5]=f2b(a1.y); pa.u[6]=f2b(a1.z); pa.u[7]=f2b(a1.w);
      } else {
        pa.v = *reinterpret_cast<const uint4*>(Ap + k0);
      }
    } else {
      pa.v = make_uint4(0,0,0,0);
    }
    *reinterpret_cast<uint4*>(&Als[arow][akp]) = pa.v;
    union { ushort u[8]; uint4 v; } pb;
#pragma unroll
    for (int j = 0; j < 8; j++)
      pb.u[j] = f2b(W[(size_t)(k0 + bkb*8 + j) * M + col0 + bcol]);
    *reinterpret_cast<uint4*>(&Bls[bcol][(bkb ^ (bcol & 3)) * 8]) = pb.v;
    __syncthreads();
    short8 af = *reinterpret_cast<const short8*>(&Als[16*w + l15][l4 * 8]);
#pragma unroll
    for (int n = 0; n < 4; n++) {
      int bc = 16*n + l15;
      short8 bf = *reinterpret_cast<const short8*>(&Bls[bc][(l4 ^ (bc & 3)) * 8]);
      acc[n] = __builtin_amdgcn_mfma_f32_16x16x32_bf16(af, bf, acc[n], 0, 0, 0);
    }
    __syncthreads();
  }
}

// ====== z-projection GEMM + bf16 store + fused per-node alpha epilogue =====
// DD = head dim (16 for M=128, 8 for M=64); NV alpha vectors.
template<int NV, int DD, typename AT>
__global__ __launch_bounds__(256) void zgemm_k(
    const AT* __restrict__ A, const float* __restrict__ W,
    const float* __restrict__ bias,
    const float* __restrict__ v0, const float* __restrict__ v1,
    const float* __restrict__ v2, const float* __restrict__ v3,
    float* __restrict__ o0, float* __restrict__ o1,
    float* __restrict__ o2, float* __restrict__ o3,
    ushort* __restrict__ Cb, int N, int K, int M)
{
  __shared__ __align__(16) ushort Als[64][32];
  __shared__ __align__(16) ushort Bls[64][32];
  int t = threadIdx.x;
  int row0 = blockIdx.x * 64, col0 = blockIdx.y * 64;
  int w = t >> 6, lane = t & 63;
  int l15 = lane & 15, l4 = lane >> 4;
  f32x4 acc[4] = {{0.f,0.f,0.f,0.f},{0.f,0.f,0.f,0.f},
                  {0.f,0.f,0.f,0.f},{0.f,0.f,0.f,0.f}};
  gemm_tile<AT>(A, W, N, K, M, row0, col0, Als, Bls, acc);

  float vals[4][4];
#pragma unroll
  for (int n = 0; n < 4; n++) {
    int col = col0 + 16*n + l15;
    float bv = bias[col];
#pragma unroll
    for (int r = 0; r < 4; r++) {
      int row = row0 + 16*w + l4*4 + r;
      float v = acc[n][r] + bv;
      vals[n][r] = v;
      if (row < N) Cb[(size_t)row * M + col] = f2b(v);
    }
  }
  // alpha epilogue: head dot over DD cols via cross-lane reduce in l15 group
#pragma unroll
  for (int n = 0; n < 4; n++) {
    int head = (DD == 16) ? (blockIdx.y*4 + n) : (n*2 + (l15 >> 3));
    int vi = head * DD + (l15 & (DD - 1));
    float w0 = v0[vi];
    float w1 = (NV > 1) ? v1[vi] : 0.f;
    float w2 = (NV > 2) ? v2[vi] : 0.f;
    float w3 = (NV > 3) ? v3[vi] : 0.f;
#pragma unroll
    for (int r = 0; r < 4; r++) {
      int row = row0 + 16*w + l4*4 + r;
      float zv = vals[n][r];
      float a0 = zv * w0, a1 = zv * w1, a2 = zv * w2, a3 = zv * w3;
#pragma unroll
      for (int o = 1; o < DD; o <<= 1) {
        a0 += __shfl_xor(a0, o);
        if (NV > 1) a1 += __shfl_xor(a1, o);
        if (NV > 2) a2 += __shfl_xor(a2, o);
        if (NV > 3) a3 += __shfl_xor(a3, o);
      }
      if ((l15 & (DD - 1)) == 0 && row < N) {
        o0[(size_t)row * 8 + head] = a0;
        if (NV > 1) o1[(size_t)row * 8 + head] = a1;
        if (NV > 2) o2[(size_t)row * 8 + head] = a2;
        if (NV > 3) o3[(size_t)row * 8 + head] = a3;
      }
    }
  }
}

// ====== multi-task score GEMM (bf16 A): atomicAdd(scp[t], sum tanh(C+b)*q) ==
__global__ __launch_bounds__(256) void score_k(
    const ushort* __restrict__ A0, const ushort* __restrict__ A1,
    const ushort* __restrict__ A2, const ushort* __restrict__ A3,
    const float* __restrict__ W, const float* __restrict__ bias,
    const float* __restrict__ qv, float* __restrict__ scp,
    int4 cum, int4 Ns, int4 Gs, int K, int M)
{
  __shared__ __align__(16) ushort Als[64][32];
  __shared__ __align__(16) ushort Bls[64][32];
  __shared__ float red[4];
  int b = blockIdx.x;
  int tsk, base, G, N; const ushort* A;
  if      (b < cum.x) { tsk=0; base=0;     G=Gs.x; N=Ns.x; A=A0; }
  else if (b < cum.y) { tsk=1; base=cum.x; G=Gs.y; N=Ns.y; A=A1; }
  else if (b < cum.z) { tsk=2; base=cum.y; G=Gs.z; N=Ns.z; A=A2; }
  else                { tsk=3; base=cum.z; G=Gs.w; N=Ns.w; A=A3; }
  int local = b - base;
  int row0 = (local % G) * 64, col0 = (local / G) * 64;
  int t = threadIdx.x;
  int w = t >> 6, lane = t & 63;
  int l15 = lane & 15, l4 = lane >> 4;
  f32x4 acc[4] = {{0.f,0.f,0.f,0.f},{0.f,0.f,0.f,0.f},
                  {0.f,0.f,0.f,0.f},{0.f,0.f,0.f,0.f}};
  gemm_tile<ushort>(A, W, N, K, M, row0, col0, Als, Bls, acc);

  float local_s = 0.f;
#pragma unroll
  for (int n = 0; n < 4; n++) {
    int col = col0 + 16*n + l15;
    float bv = bias[col], qq = qv[col];
#pragma unroll
    for (int r = 0; r < 4; r++) {
      int row = row0 + 16*w + l4*4 + r;
      if (row < N) local_s += tanhf(acc[n][r] + bv) * qq;
    }
  }
#pragma unroll
  for (int o = 32; o > 0; o >>= 1) local_s += __shfl_xor(local_s, o);
  if (lane == 0) red[w] = local_s;
  __syncthreads();
  if (t == 0) atomicAdd(&scp[tsk], red[0] + red[1] + red[2] + red[3]);
}

// ============== XCD-sharded CSR build + compaction =========================
__global__ void hist4_sh(const int* __restrict__ d0, const int* __restrict__ d1,
    const int* __restrict__ d2, const int* __restrict__ d3,
    int* __restrict__ cnt8, float* __restrict__ scp)
{
  if (blockIdx.x == 0 && threadIdx.x < 8) scp[threadIdx.x] = 0.f;
  int e = blockIdx.x * 256 + threadIdx.x;
  int sh = blockIdx.x & (NSH - 1);
  int d;
  if      (e < E1)          d = d0[e];
  else if (e < 2*E1)        d = d1[e - E1] + NT;
  else if (e < 2*E1 + E2)   d = d2[e - 2*E1] + NT + NA;
  else if (e < ETOT)        d = d3[e - 2*E1 - E2] + NT + 2*NA;
  else return;
  atomicAdd(&cnt8[sh * NTOT + d], 1);
}

__global__ void scatter_sh(const int* __restrict__ s0, const int* __restrict__ d0,
    const int* __restrict__ s1, const int* __restrict__ d1,
    const int* __restrict__ s2, const int* __restrict__ d2,
    const int* __restrict__ s3, const int* __restrict__ d3,
    int* __restrict__ cur8, int* __restrict__ ssh)
{
  int e = blockIdx.x * 256 + threadIdx.x;
  int sh = blockIdx.x & (NSH - 1);
  int d, s;
  if      (e < E1)          { d = d0[e];                           s = s0[e]; }
  else if (e < 2*E1)        { d = d1[e - E1] + NT;                 s = s1[e - E1]; }
  else if (e < 2*E1 + E2)   { d = d2[e - 2*E1] + NT + NA;          s = s2[e - 2*E1]; }
  else if (e < ETOT)        { d = d3[e - 2*E1 - E2] + NT + 2*NA;   s = s3[e - 2*E1 - E2]; }
  else return;
  int p = atomicAdd(&cur8[sh * NTOT + d], 1);
  ssh[p] = s;
}

// per-node total degree = sum of the 8 shard counts (run before cnt8 scan)
__global__ void sumsh_k(const int* __restrict__ cnt8, int* __restrict__ cnt)
{
  int g = blockIdx.x * 256 + threadIdx.x;
  if (g >= NTOT) return;
  int s = 0;
#pragma unroll
  for (int k = 0; k < NSH; k++) s += cnt8[k * NTOT + g];
  cnt[g] = s;
}

// merge each node's 8 shard-segments into the contiguous final CSR order
__global__ void compact_k(const int* __restrict__ rp8, const int* __restrict__ rp,
    const int* __restrict__ ssh, int* __restrict__ ssrc)
{
  int g = blockIdx.x * 256 + threadIdx.x;
  if (g >= NTOT) return;
  int w = rp[g];
#pragma unroll
  for (int s = 0; s < NSH; s++) {
    int b0 = rp8[s * NTOT + g], b1 = rp8[s * NTOT + g + 1];
    for (int e = b0; e < b1; e++) ssrc[w++] = ssh[e];
  }
}

// per-block inclusive scan (256 thr x 8) of in -> rp1 (=rp+1); totals -> bsum
__global__ __launch_bounds__(256) void scan_blk(const int* __restrict__ in,
    int* __restrict__ rp1, int* __restrict__ bsum, int n)
{
  __shared__ int sh[256];
  int base = blockIdx.x * 2048;
  int t = threadIdx.x;
  int v[8]; int s = 0;
#pragma unroll
  for (int k = 0; k < 8; k++) {
    int i = base + t * 8 + k;
    v[k] = (i < n) ? in[i] : 0; s += v[k];
  }
  sh[t] = s; __syncthreads();
  for (int o = 1; o < 256; o <<= 1) {
    int x = (t >= o) ? sh[t - o] : 0;
    __syncthreads(); sh[t] += x; __syncthreads();
  }
  int run = (t == 0) ? 0 : sh[t - 1];
  if (t == 255 && bsum) bsum[blockIdx.x] = sh[255];
#pragma unroll
  for (int k = 0; k < 8; k++) {
    int i = base + t * 8 + k;
    run += v[k];
    if (i < n) rp1[i] = run;
  }
}

// add inclusive block-offsets; writes rp[0]=0 and cursor init cur[i]=rp[i]
__global__ void scan_add2(int* __restrict__ rp, int* __restrict__ cur,
    const int* __restrict__ bsA, int n)
{
  int i = blockIdx.x * blockDim.x + threadIdx.x;
  if (i == 0) { rp[0] = 0; cur[0] = 0; }
  if (i < n) {
    int blk = i >> 11;
    int base = blk ? bsA[blk - 1] : 0;
    int v = rp[i + 1] + base;
    rp[i + 1] = v;
    if (i + 1 < n) cur[i + 1] = v;
  }
}

// add inclusive block-offsets (no cursor); writes rp[0]=0
__global__ void scan_add(int* __restrict__ rp, const int* __restrict__ bsA, int n)
{
  int i = blockIdx.x * blockDim.x + threadIdx.x;
  if (i == 0) rp[0] = 0;
  if (i < n) {
    int blk = i >> 11;
    int base = blk ? bsA[blk - 1] : 0;
    rp[i + 1] += base;
  }
}

// =============== atomic-free GAT aggregation, one wave per dst node ========
// softmax: lane = h*8+j (8 edges x 8 heads in parallel).
// accumulate: wave split into edge-groups (4x16 for F=128, 8x8 for F=64);
// register accumulate; cross-group shfl reduce; coalesced bf16 relu store.
struct AggTask {
  int g0, Nd;
  const float* als; const float* ald;
  const ushort* z;  ushort* out;
};

template<int F>
__global__ __launch_bounds__(256) void agg_multi(const int* __restrict__ rp,
    const int* __restrict__ ssrc, AggTask T0, AggTask T1, AggTask T2, AggTask T3,
    int c1, int c2, int c3)
{
  int b = blockIdx.x;
  AggTask T; int lb;
  if      (b < c1) { T = T0; lb = b; }
  else if (b < c2) { T = T1; lb = b - c1; }
  else if (b < c3) { T = T2; lb = b - c2; }
  else             { T = T3; lb = b - c3; }
  int wv = threadIdx.x >> 6, lane = threadIdx.x & 63;
  int n = lb * 4 + wv;
  if (n >= T.Nd) return;
  int g = T.g0 + n;
  int start = rp[g], end = rp[g + 1];
  int h = lane >> 3, j = lane & 7;
  float ad_h = T.ald[(size_t)n * 8 + h];

  float m = -1e30f;
  for (int e0 = start; e0 < end; e0 += 8) {
    int e = e0 + j;
    if (e < end) {
      int sn = ssrc[e];
      float a = T.als[(size_t)sn * 8 + h] + ad_h;
      a = a > 0.f ? a : 0.2f * a;
      m = fmaxf(m, a);
    }
  }
  m = fmaxf(m, __shfl_xor(m, 1));
  m = fmaxf(m, __shfl_xor(m, 2));
  m = fmaxf(m, __shfl_xor(m, 4));

  float den = 0.f;
  for (int e0 = start; e0 < end; e0 += 8) {
    int e = e0 + j;
    if (e < end) {
      int sn = ssrc[e];
      float a = T.als[(size_t)sn * 8 + h] + ad_h;
      a = a > 0.f ? a : 0.2f * a;
      den += __expf(a - m);
    }
  }
  den += __shfl_xor(den, 1);
  den += __shfl_xor(den, 2);
  den += __shfl_xor(den, 4);
  float inv = 1.f / fmaxf(den, 1e-16f);

  if (F == 128) {
    int lg = lane & 15, grp = lane >> 4;          // 4 edge-groups x 16 lanes
    int hh = lg >> 1;                             // head of feats [lg*8,lg*8+8)
    float mh   = __shfl(m, hh * 8);
    float invh = __shfl(inv, hh * 8);
    float adh  = __shfl(ad_h, hh * 8);
    float acc[8] = {};
    for (int e0 = start; e0 < end; e0 += 4) {
      int e = e0 + grp;
      if (e < end) {
        int sn = ssrc[e];
        float a = T.als[(size_t)sn * 8 + hh] + adh;
        a = a > 0.f ? a : 0.2f * a;
        float wgt = __expf(a - mh) * invh;
        uint4 zv = *reinterpret_cast<const uint4*>(T.z + (size_t)sn * 128 + lg * 8);
        acc[0] = fmaf(wgt, u2f_lo(zv.x), acc[0]);
        acc[1] = fmaf(wgt, u2f_hi(zv.x), acc[1]);
        acc[2] = fmaf(wgt, u2f_lo(zv.y), acc[2]);
        acc[3] = fmaf(wgt, u2f_hi(zv.y), acc[3]);
        acc[4] = fmaf(wgt, u2f_lo(zv.z), acc[4]);
        acc[5] = fmaf(wgt, u2f_hi(zv.z), acc[5]);
        acc[6] = fmaf(wgt, u2f_lo(zv.w), acc[6]);
        acc[7] = fmaf(wgt, u2f_hi(zv.w), acc[7]);
      }
    }
#pragma unroll
    for (int k = 0; k < 8; k++) {
      acc[k] += __shfl_xor(acc[k], 16);
      acc[k] += __shfl_xor(acc[k], 32);
    }
    if (grp == 0) {
      unsigned int pk[4];
#pragma unroll
      for (int k2 = 0; k2 < 4; k2++)
        pk[k2] = (unsigned int)f2b(fmaxf(acc[2*k2], 0.f))
               | ((unsigned int)f2b(fmaxf(acc[2*k2+1], 0.f)) << 16);
      *reinterpret_cast<uint4*>(T.out + (size_t)n * 128 + lg * 8)
          = make_uint4(pk[0], pk[1], pk[2], pk[3]);
    }
  } else {
    int lg = lane & 7, grp = lane >> 3;           // 8 edge-groups x 8 lanes
    int hh = lg;                                  // head == lg (D=8)
    float mh   = __shfl(m, hh * 8);
    float invh = __shfl(inv, hh * 8);
    float adh  = __shfl(ad_h, hh * 8);
    float acc[8] = {};
    for (int e0 = start; e0 < end; e0 += 8) {
      int e = e0 + grp;
      if (e < end) {
        int sn = ssrc[e];
        float a = T.als[(size_t)sn * 8 + hh] + adh;
        a = a > 0.f ? a : 0.2f * a;
        float wgt = __expf(a - mh) * invh;
        uint4 zv = *reinterpret_cast<const uint4*>(T.z + (size_t)sn * 64 + lg * 8);
        acc[0] = fmaf(wgt, u2f_lo(zv.x), acc[0]);
        acc[1] = fmaf(wgt, u2f_hi(zv.x), acc[1]);
        acc[2] = fmaf(wgt, u2f_lo(zv.y), acc[2]);
        acc[3] = fmaf(wgt, u2f_hi(zv.y), acc[3]);
        acc[4] = fmaf(wgt, u2f_lo(zv.z), acc[4]);
        acc[5] = fmaf(wgt, u2f_hi(zv.z), acc[5]);
        acc[6] = fmaf(wgt, u2f_lo(zv.w), acc[6]);
        acc[7] = fmaf(wgt, u2f_hi(zv.w), acc[7]);
      }
    }
#pragma unroll
    for (int k = 0; k < 8; k++) {
      acc[k] += __shfl_xor(acc[k], 8);
      acc[k] += __shfl_xor(acc[k], 16);
      acc[k] += __shfl_xor(acc[k], 32);
    }
    if (grp == 0) {
      unsigned int pk[4];
#pragma unroll
      for (int k2 = 0; k2 < 4; k2++)
        pk[k2] = (unsigned int)f2b(fmaxf(acc[2*k2], 0.f))
               | ((unsigned int)f2b(fmaxf(acc[2*k2+1], 0.f)) << 16);
      *reinterpret_cast<uint4*>(T.out + (size_t)n * 64 + lg * 8)
          = make_uint4(pk[0], pk[1], pk[2], pk[3]);
    }
  }
}

// ---- semantic softmax (K=2) combine + LayerNorm + ReLU, 2 tasks, F=128 ----
__global__ __launch_bounds__(256) void combine2_k(
    const ushort* __restrict__ o00, const ushort* __restrict__ o01,
    const float* __restrict__ sc0, float invn0, ushort* __restrict__ out0, int N0,
    const ushort* __restrict__ o10, const ushort* __restrict__ o11,
    const float* __restrict__ sc1, float invn1, ushort* __restrict__ out1, int N1,
    const float* __restrict__ g, const float* __restrict__ bb)
{
  int c1 = (N0 + 3) / 4;
  int b = blockIdx.x;
  const ushort *o0, *o1; const float* sc; float invn; ushort* outp; int N, lb;
  if (b < c1) { o0=o00; o1=o01; sc=sc0; invn=invn0; outp=out0; N=N0; lb=b; }
  else        { o0=o10; o1=o11; sc=sc1; invn=invn1; outp=out1; N=N1; lb=b-c1; }
  int wv = threadIdx.x >> 6, lane = threadIdx.x & 63;
  int n = lb * 4 + wv;
  if (n >= N) return;
  float s0 = sc[0] * invn, s1 = sc[1] * invn;
  float mx = fmaxf(s0, s1);
  float e0 = __expf(s0 - mx), e1 = __expf(s1 - mx);
  float w0 = e0 / (e0 + e1), w1 = e1 / (e0 + e1);
  float x[2];
#pragma unroll
  for (int jj = 0; jj < 2; jj++) {
    int idx = lane + 64 * jj;
    x[jj] = w0 * b2f(o0[(size_t)n * 128 + idx]) + w1 * b2f(o1[(size_t)n * 128 + idx]);
  }
  float sum = x[0] + x[1];
#pragma unroll
  for (int o = 32; o > 0; o >>= 1) sum += __shfl_xor(sum, o);
  float mu = sum / 128.f;
  float vs = 0.f;
#pragma unroll
  for (int jj = 0; jj < 2; jj++) { float dd = x[jj] - mu; vs = fmaf(dd, dd, vs); }
#pragma unroll
  for (int o = 32; o > 0; o >>= 1) vs += __shfl_xor(vs, o);
  float rstd = rsqrtf(vs / 128.f + 1e-5f);
#pragma unroll
  for (int jj = 0; jj < 2; jj++) {
    int idx = lane + 64 * jj;
    float y = (x[jj] - mu) * rstd * g[idx] + bb[idx];
    outp[(size_t)n * 128 + idx] = f2b(fmaxf(y, 0.f));
  }
}

// ---- layer-2 combine + LN + ReLU + final linear [64]->[2], F=64 ----------
__global__ __launch_bounds__(256) void combine_final_k(
    const ushort* __restrict__ o0, const ushort* __restrict__ o1,
    const float* __restrict__ sc, float invn,
    const float* __restrict__ g, const float* __restrict__ bb,
    const float* __restrict__ lw, const float* __restrict__ lb,
    float* __restrict__ outp, int N)
{
  int wv = threadIdx.x >> 6, lane = threadIdx.x & 63;
  int n = blockIdx.x * 4 + wv;
  if (n >= N) return;
  float s0 = sc[0] * invn, s1 = sc[1] * invn;
  float mx = fmaxf(s0, s1);
  float e0 = __expf(s0 - mx), e1 = __expf(s1 - mx);
  float w0 = e0 / (e0 + e1), w1 = e1 / (e0 + e1);
  float x = w0 * b2f(o0[(size_t)n * 64 + lane]) + w1 * b2f(o1[(size_t)n * 64 + lane]);
  float sum = x;
#pragma unroll
  for (int o = 32; o > 0; o >>= 1) sum += __shfl_xor(sum, o);
  float mu = sum / 64.f;
  float dd = x - mu;
  float vs = dd * dd;
#pragma unroll
  for (int o = 32; o > 0; o >>= 1) vs += __shfl_xor(vs, o);
  float rstd = rsqrtf(vs / 64.f + 1e-5f);
  float y = fmaxf((x - mu) * rstd * g[lane] + bb[lane], 0.f);
  float p0 = y * lw[lane * 2 + 0];
  float p1 = y * lw[lane * 2 + 1];
#pragma unroll
  for (int o = 32; o > 0; o >>= 1) { p0 += __shfl_xor(p0, o); p1 += __shfl_xor(p1, o); }
  if (lane == 0) {
    outp[(size_t)n * 2 + 0] = p0 + lb[0];
    outp[(size_t)n * 2 + 1] = p1 + lb[1];
  }
}

extern "C" void kernel_launch(void* const* d_in, const int* in_sizes, int n_in,
                              void* d_out, int out_size, void* d_ws, size_t ws_size,
                              hipStream_t stream)
{
  (void)in_sizes; (void)n_in; (void)out_size;
  const float* x_a = (const float*)d_in[0];
  const float* x_t = (const float*)d_in[1];
  const int* eat_s = (const int*)d_in[2];
  const int* eat_d = (const int*)d_in[3];
  const int* eta_s = (const int*)d_in[4];
  const int* eta_d = (const int*)d_in[5];
  const int* eaa_s = (const int*)d_in[6];
  const int* eaa_d = (const int*)d_in[7];
  const int* ett_s = (const int*)d_in[8];
  const int* ett_d = (const int*)d_in[9];
  const float* W_a1 = (const float*)d_in[10]; const float* b_a1 = (const float*)d_in[11];
  const float* W_t1 = (const float*)d_in[12]; const float* b_t1 = (const float*)d_in[13];
  const float* as_at1 = (const float*)d_in[14]; const float* ad_at1 = (const float*)d_in[15];
  const float* as_ta1 = (const float*)d_in[16]; const float* ad_ta1 = (const float*)d_in[17];
  const float* as_aa1 = (const float*)d_in[18]; const float* ad_aa1 = (const float*)d_in[19];
  const float* as_tt1 = (const float*)d_in[20]; const float* ad_tt1 = (const float*)d_in[21];
  const float* k1_W = (const float*)d_in[22]; const float* k1_b = (const float*)d_in[23];
  const float* q1   = (const float*)d_in[24];
  const float* W_a2 = (const float*)d_in[25]; const float* b_a2 = (const float*)d_in[26];
  const float* W_t2 = (const float*)d_in[27]; const float* b_t2 = (const float*)d_in[28];
  const float* as_ta2 = (const float*)d_in[31]; const float* ad_ta2 = (const float*)d_in[32];
  const float* as_aa2 = (const float*)d_in[33]; const float* ad_aa2 = (const float*)d_in[34];
  const float* k2_W = (const float*)d_in[37]; const float* k2_b = (const float*)d_in[38];
  const float* q2   = (const float*)d_in[39];
  const float* ln1_g = (const float*)d_in[40]; const float* ln1_b = (const float*)d_in[41];
  const float* ln2_g = (const float*)d_in[42]; const float* ln2_b = (const float*)d_in[43];
  const float* lin_W = (const float*)d_in[44]; const float* lin_b = (const float*)d_in[45];

  char* ws = (char*)d_ws;
  size_t off = 0;
  auto alloc = [&](size_t bytes) {
    size_t o = off; off += (bytes + 255) & ~(size_t)255; return o;
  };
  size_t ZA1 = alloc((size_t)NA * HID * 2);     // bf16 z_a; layer2 za2 aliases
  size_t ZT1 = alloc((size_t)NT * HID * 2);     // bf16 z_t; layer2 zt2 aliases
  size_t OTA = alloc((size_t)NA * HID * 2);     // bf16 o_ta -> xa1 in-place
  size_t OAA = alloc((size_t)NA * HID * 2);     // bf16 o_aa; L2: ota2|oaa2 alias
  size_t OAT = alloc((size_t)NT * HID * 2);     // bf16 o_at -> xt1 in-place
  size_t OTT = alloc((size_t)NT * HID * 2);
  size_t A_AS_AT = alloc((size_t)NA * 8 * 4);
  size_t A_AD_TA = alloc((size_t)NA * 8 * 4);
  size_t A_AS_AA = alloc((size_t)NA * 8 * 4);
  size_t A_AD_AA = alloc((size_t)NA * 8 * 4);
  size_t A_T_D_AT = alloc((size_t)NT * 8 * 4);
  size_t A_T_S_TA = alloc((size_t)NT * 8 * 4);
  size_t A_T_S_TT = alloc((size_t)NT * 8 * 4);
  size_t A_T_D_TT = alloc((size_t)NT * 8 * 4);
  // sharded CSR build + compacted final CSR
  size_t RP8  = alloc(((size_t)NSH * NTOT + 1) * 4);
  size_t CUR8 = alloc((size_t)NSH * NTOT * 4);  // doubles as sharded hist
  size_t SSH  = alloc((size_t)ETOT * 4);
  size_t RP   = alloc((size_t)(NTOT + 1) * 4);
  size_t CNT  = alloc((size_t)NTOT * 4);
  size_t SS   = alloc((size_t)ETOT * 4);
  size_t BSM  = alloc(2048 * 4);
  size_t BSM2 = alloc(256 * 4);
  size_t SC   = alloc(256);                     // 6 score accumulators
  if (off > ws_size) return;                    // fail visibly

  ushort* za1 = (ushort*)(ws + ZA1);
  ushort* zt1 = (ushort*)(ws + ZT1);
  ushort* ota = (ushort*)(ws + OTA);
  ushort* oaa = (ushort*)(ws + OAA);
  ushort* oat = (ushort*)(ws + OAT);
  ushort* ott = (ushort*)(ws + OTT);
  float* aASAT = (float*)(ws + A_AS_AT);
  float* aADTA = (float*)(ws + A_AD_TA);
  float* aASAA = (float*)(ws + A_AS_AA);
  float* aADAA = (float*)(ws + A_AD_AA);
  float* aTDAT = (float*)(ws + A_T_D_AT);
  float* aTSTA = (float*)(ws + A_T_S_TA);
  float* aTSTT = (float*)(ws + A_T_S_TT);
  float* aTDTT = (float*)(ws + A_T_D_TT);
  int* rp8  = (int*)(ws + RP8);
  int* cur8 = (int*)(ws + CUR8);
  int* ssh  = (int*)(ws + SSH);
  int* rp   = (int*)(ws + RP);
  int* cnt  = (int*)(ws + CNT);
  int* ssrc = (int*)(ws + SS);
  int* bsum = (int*)(ws + BSM);
  int* bsum2= (int*)(ws + BSM2);
  float* scp = (float*)(ws + SC);
  // layer-2 aliases
  ushort* za2 = za1;                                   // [NA,64] bf16
  ushort* zt2 = zt1;                                   // [NT,64] bf16
  ushort* ota2 = oaa;                                  // [NA,64] bf16
  ushort* oaa2 = (ushort*)(ws + OAA + (size_t)NA * OUTF * 2);  // [NA,64] bf16

  const int GA = (NA + 63) / 64, GT = (NT + 63) / 64;
  const int EBL = (ETOT + 255) / 256;
  const int SCN8 = NSH * NTOT;                 // 2.4M sharded scan elements
  const int SBL8 = (SCN8 + 2047) / 2048;       // 1172 (< 2048, 1-block L2 scan)
  const int SBL1 = (NTOT + 2047) / 2048;       // 147

  // ---- sharded CSR build + compact ----
  hipMemsetAsync(cur8, 0, (size_t)SCN8 * 4, stream);
  hist4_sh<<<EBL, 256, 0, stream>>>(eat_d, eta_d, eaa_d, ett_d, cur8, scp);
  sumsh_k<<<(NTOT + 255) / 256, 256, 0, stream>>>(cur8, cnt);
  scan_blk<<<SBL8, 256, 0, stream>>>(cur8, rp8 + 1, bsum, SCN8);
  scan_blk<<<1, 256, 0, stream>>>(bsum, bsum, nullptr, SBL8);
  scan_add2<<<(SCN8 + 255) / 256, 256, 0, stream>>>(rp8, cur8, bsum, SCN8);
  scan_blk<<<SBL1, 256, 0, stream>>>(cnt, rp + 1, bsum2, NTOT);
  scan_blk<<<1, 256, 0, stream>>>(bsum2, bsum2, nullptr, SBL1);
  scan_add<<<(NTOT + 255) / 256, 256, 0, stream>>>(rp, bsum2, NTOT);
  scatter_sh<<<EBL, 256, 0, stream>>>(eat_s, eat_d, eta_s, eta_d,
                                      eaa_s, eaa_d, ett_s, ett_d, cur8, ssh);
  compact_k<<<(NTOT + 255) / 256, 256, 0, stream>>>(rp8, rp, ssh, ssrc);

  // ============ Layer 1 ============
  zgemm_k<4,16,float><<<dim3(GA,2),256,0,stream>>>(x_a, W_a1, b_a1,
      as_at1, ad_ta1, as_aa1, ad_aa1, aASAT, aADTA, aASAA, aADAA,
      za1, NA, FA, HID);
  zgemm_k<4,16,float><<<dim3(GT,2),256,0,stream>>>(x_t, W_t1, b_t1,
      ad_at1, as_ta1, as_tt1, ad_tt1, aTDAT, aTSTA, aTSTT, aTDTT,
      zt1, NT, FT, HID);
  {
    AggTask T0{0,          NT, aASAT, aTDAT, za1, oat};
    AggTask T1{NT,         NA, aTSTA, aADTA, zt1, ota};
    AggTask T2{NT+NA,      NA, aASAA, aADAA, za1, oaa};
    AggTask T3{NT+2*NA,    NT, aTSTT, aTDTT, zt1, ott};
    agg_multi<128><<<2*(NT/4) + 2*(NA/4), 256, 0, stream>>>(rp, ssrc,
        T0, T1, T2, T3, NT/4, NT/4 + NA/4, NT/4 + 2*(NA/4));
  }
  score_k<<<4*GA + 4*GT, 256, 0, stream>>>(ota, oaa, oat, ott,
      k1_W, k1_b, q1, scp,
      make_int4(2*GA, 4*GA, 4*GA + 2*GT, 4*GA + 4*GT),
      make_int4(NA, NA, NT, NT), make_int4(GA, GA, GT, GT), HID, HID);
  combine2_k<<<(NA/4) + (NT/4), 256, 0, stream>>>(
      ota, oaa, scp + 0, 1.f/NA, ota, NA,
      oat, ott, scp + 2, 1.f/NT, oat, NT, ln1_g, ln1_b);

  // ============ Layer 2 (only the address path feeds the output) ============
  zgemm_k<3,8,ushort><<<dim3(GA,1),256,0,stream>>>(ota, W_a2, b_a2,
      ad_ta2, as_aa2, ad_aa2, nullptr, aADTA, aASAA, aADAA, nullptr,
      za2, NA, HID, OUTF);
  zgemm_k<1,8,ushort><<<dim3(GT,1),256,0,stream>>>(oat, W_t2, b_t2,
      as_ta2, nullptr, nullptr, nullptr, aTSTA, nullptr, nullptr, nullptr,
      zt2, NT, HID, OUTF);
  {
    AggTask T0{NT,    NA, aTSTA, aADTA, zt2, ota2};
    AggTask T1{NT+NA, NA, aASAA, aADAA, za2, oaa2};
    agg_multi<64><<<2*(NA/4), 256, 0, stream>>>(rp, ssrc,
        T0, T1, T1, T1, NA/4, 2*(NA/4), 2*(NA/4));
  }
  score_k<<<2*GA, 256, 0, stream>>>(ota2, oaa2, ota2, ota2,
      k2_W, k2_b, q2, scp + 4,
      make_int4(GA, 2*GA, 2*GA, 2*GA),
      make_int4(NA, NA, NA, NA), make_int4(GA, GA, GA, GA), OUTF, OUTF);
  combine_final_k<<<NA/4, 256, 0, stream>>>(ota2, oaa2, scp + 4, 1.f/NA,
      ln2_g, ln2_b, lin_W, lin_b, (float*)d_out, NA);
}

// Round 7
// 603.982 us; speedup vs baseline: 1.7695x; 1.1906x over previous
//
#include <hip/hip_runtime.h>
#include <cstdint>
#include <cstddef>
#include <type_traits>

#define NA 50000
#define NT 100000
#define FA 128
#define FT 64
#define HID 128
#define OUTF 64
#define HEADS 8
#define E1 500000
#define E2 250000
#define NTOT (2*NT + 2*NA)          // concatenated dst-node space [at|ta|aa|tt]
#define ETOT (2*E1 + 2*E2)          // concatenated edge space
#define NSH 8                       // CSR build shards (== XCDs heuristic)

typedef __attribute__((ext_vector_type(8))) short short8;
typedef __attribute__((ext_vector_type(4))) float f32x4;

static __device__ __forceinline__ ushort f2b(float f) {  // f32 -> bf16 RNE
  unsigned int u = __float_as_uint(f);
  return (ushort)((u + 0x7fffu + ((u >> 16) & 1u)) >> 16);
}
static __device__ __forceinline__ float b2f(ushort b) {
  return __uint_as_float(((unsigned int)b) << 16);
}
static __device__ __forceinline__ float u2f_lo(unsigned int u) {
  return __uint_as_float(u << 16);
}
static __device__ __forceinline__ float u2f_hi(unsigned int u) {
  return __uint_as_float(u & 0xffff0000u);
}

// ---------------- shared MFMA tile core: 64x64, BK=32, 4 waves -------------
// AT = float (convert while staging) or ushort (bf16, direct copy)
template<typename AT>
__device__ __forceinline__ void gemm_tile(
    const AT* __restrict__ A, const float* __restrict__ W,
    int N, int K, int M, int row0, int col0,
    ushort (*Als)[32], ushort (*Bls)[32], f32x4* acc)
{
  int t = threadIdx.x;
  int w = t >> 6, lane = t & 63;
  int l15 = lane & 15, l4 = lane >> 4;
  int arow = t >> 2, akp = (t & 3) << 3;    // A stage: 64 rows x 32 k
  int bcol = t & 63, bkb = t >> 6;          // B stage: 64 cols x 4 k-blocks
  bool aok = (row0 + arow) < N;
  const AT* Ap = A + (size_t)(row0 + arow) * K + akp;

  for (int k0 = 0; k0 < K; k0 += 32) {
    union { ushort u[8]; uint4 v; } pa;
    if (aok) {
      if constexpr (std::is_same<AT, float>::value) {
        float4 a0 = *reinterpret_cast<const float4*>(Ap + k0);
        float4 a1 = *reinterpret_cast<const float4*>(Ap + k0 + 4);
        pa.u[0]=f2b(a0.x); pa.u[1]=f2b(a0.y); pa.u[2]=f2b(a0.z); pa.u[3]=f2b(a0.w);
        pa.u[4]=f2b(a1.x); pa.u[5]=f2b(a1.y); pa.u[6]=f2b(a1.z); pa.u[7]=f2b(a1.w);
      } else {
        pa.v = *reinterpret_cast<const uint4*>(Ap + k0);
      }
    } else {
      pa.v = make_uint4(0,0,0,0);
    }
    *reinterpret_cast<uint4*>(&Als[arow][akp]) = pa.v;
    union { ushort u[8]; uint4 v; } pb;
#pragma unroll
    for (int j = 0; j < 8; j++)
      pb.u[j] = f2b(W[(size_t)(k0 + bkb*8 + j) * M + col0 + bcol]);
    *reinterpret_cast<uint4*>(&Bls[bcol][(bkb ^ (bcol & 3)) * 8]) = pb.v;
    __syncthreads();
    short8 af = *reinterpret_cast<const short8*>(&Als[16*w + l15][l4 * 8]);
#pragma unroll
    for (int n = 0; n < 4; n++) {
      int bc = 16*n + l15;
      short8 bf = *reinterpret_cast<const short8*>(&Bls[bc][(l4 ^ (bc & 3)) * 8]);
      acc[n] = __builtin_amdgcn_mfma_f32_16x16x32_bf16(af, bf, acc[n], 0, 0, 0);
    }
    __syncthreads();
  }
}

// ====== z-projection GEMM + bf16 store + fused per-node alpha epilogue =====
// DD = head dim (16 for M=128, 8 for M=64); NV alpha vectors.
template<int NV, int DD, typename AT>
__global__ __launch_bounds__(256) void zgemm_k(
    const AT* __restrict__ A, const float* __restrict__ W,
    const float* __restrict__ bias,
    const float* __restrict__ v0, const float* __restrict__ v1,
    const float* __restrict__ v2, const float* __restrict__ v3,
    float* __restrict__ o0, float* __restrict__ o1,
    float* __restrict__ o2, float* __restrict__ o3,
    ushort* __restrict__ Cb, int N, int K, int M)
{
  __shared__ __align__(16) ushort Als[64][32];
  __shared__ __align__(16) ushort Bls[64][32];
  int t = threadIdx.x;
  int row0 = blockIdx.x * 64, col0 = blockIdx.y * 64;
  int w = t >> 6, lane = t & 63;
  int l15 = lane & 15, l4 = lane >> 4;
  f32x4 acc[4] = {{0.f,0.f,0.f,0.f},{0.f,0.f,0.f,0.f},
                  {0.f,0.f,0.f,0.f},{0.f,0.f,0.f,0.f}};
  gemm_tile<AT>(A, W, N, K, M, row0, col0, Als, Bls, acc);

  float vals[4][4];
#pragma unroll
  for (int n = 0; n < 4; n++) {
    int col = col0 + 16*n + l15;
    float bv = bias[col];
#pragma unroll
    for (int r = 0; r < 4; r++) {
      int row = row0 + 16*w + l4*4 + r;
      float v = acc[n][r] + bv;
      vals[n][r] = v;
      if (row < N) Cb[(size_t)row * M + col] = f2b(v);
    }
  }
  // alpha epilogue: head dot over DD cols via cross-lane reduce in l15 group
#pragma unroll
  for (int n = 0; n < 4; n++) {
    int head = (DD == 16) ? (blockIdx.y*4 + n) : (n*2 + (l15 >> 3));
    int vi = head * DD + (l15 & (DD - 1));
    float w0 = v0[vi];
    float w1 = (NV > 1) ? v1[vi] : 0.f;
    float w2 = (NV > 2) ? v2[vi] : 0.f;
    float w3 = (NV > 3) ? v3[vi] : 0.f;
#pragma unroll
    for (int r = 0; r < 4; r++) {
      int row = row0 + 16*w + l4*4 + r;
      float zv = vals[n][r];
      float a0 = zv * w0, a1 = zv * w1, a2 = zv * w2, a3 = zv * w3;
#pragma unroll
      for (int o = 1; o < DD; o <<= 1) {
        a0 += __shfl_xor(a0, o);
        if (NV > 1) a1 += __shfl_xor(a1, o);
        if (NV > 2) a2 += __shfl_xor(a2, o);
        if (NV > 3) a3 += __shfl_xor(a3, o);
      }
      if ((l15 & (DD - 1)) == 0 && row < N) {
        o0[(size_t)row * 8 + head] = a0;
        if (NV > 1) o1[(size_t)row * 8 + head] = a1;
        if (NV > 2) o2[(size_t)row * 8 + head] = a2;
        if (NV > 3) o3[(size_t)row * 8 + head] = a3;
      }
    }
  }
}

// ====== multi-task score GEMM (bf16 A): atomicAdd(scp[t], sum tanh(C+b)*q) ==
__global__ __launch_bounds__(256) void score_k(
    const ushort* __restrict__ A0, const ushort* __restrict__ A1,
    const ushort* __restrict__ A2, const ushort* __restrict__ A3,
    const float* __restrict__ W, const float* __restrict__ bias,
    const float* __restrict__ qv, float* __restrict__ scp,
    int4 cum, int4 Ns, int4 Gs, int K, int M)
{
  __shared__ __align__(16) ushort Als[64][32];
  __shared__ __align__(16) ushort Bls[64][32];
  __shared__ float red[4];
  int b = blockIdx.x;
  int tsk, base, G, N; const ushort* A;
  if      (b < cum.x) { tsk=0; base=0;     G=Gs.x; N=Ns.x; A=A0; }
  else if (b < cum.y) { tsk=1; base=cum.x; G=Gs.y; N=Ns.y; A=A1; }
  else if (b < cum.z) { tsk=2; base=cum.y; G=Gs.z; N=Ns.z; A=A2; }
  else                { tsk=3; base=cum.z; G=Gs.w; N=Ns.w; A=A3; }
  int local = b - base;
  int row0 = (local % G) * 64, col0 = (local / G) * 64;
  int t = threadIdx.x;
  int w = t >> 6, lane = t & 63;
  int l15 = lane & 15, l4 = lane >> 4;
  f32x4 acc[4] = {{0.f,0.f,0.f,0.f},{0.f,0.f,0.f,0.f},
                  {0.f,0.f,0.f,0.f},{0.f,0.f,0.f,0.f}};
  gemm_tile<ushort>(A, W, N, K, M, row0, col0, Als, Bls, acc);

  float local_s = 0.f;
#pragma unroll
  for (int n = 0; n < 4; n++) {
    int col = col0 + 16*n + l15;
    float bv = bias[col], qq = qv[col];
#pragma unroll
    for (int r = 0; r < 4; r++) {
      int row = row0 + 16*w + l4*4 + r;
      if (row < N) local_s += tanhf(acc[n][r] + bv) * qq;
    }
  }
#pragma unroll
  for (int o = 32; o > 0; o >>= 1) local_s += __shfl_xor(local_s, o);
  if (lane == 0) red[w] = local_s;
  __syncthreads();
  if (t == 0) atomicAdd(&scp[tsk], red[0] + red[1] + red[2] + red[3]);
}

// ============== XCD-sharded CSR build + compaction =========================
__global__ void hist4_sh(const int* __restrict__ d0, const int* __restrict__ d1,
    const int* __restrict__ d2, const int* __restrict__ d3,
    int* __restrict__ cnt8, float* __restrict__ scp)
{
  if (blockIdx.x == 0 && threadIdx.x < 8) scp[threadIdx.x] = 0.f;
  int e = blockIdx.x * 256 + threadIdx.x;
  int sh = blockIdx.x & (NSH - 1);
  int d;
  if      (e < E1)          d = d0[e];
  else if (e < 2*E1)        d = d1[e - E1] + NT;
  else if (e < 2*E1 + E2)   d = d2[e - 2*E1] + NT + NA;
  else if (e < ETOT)        d = d3[e - 2*E1 - E2] + NT + 2*NA;
  else return;
  atomicAdd(&cnt8[sh * NTOT + d], 1);
}

__global__ void scatter_sh(const int* __restrict__ s0, const int* __restrict__ d0,
    const int* __restrict__ s1, const int* __restrict__ d1,
    const int* __restrict__ s2, const int* __restrict__ d2,
    const int* __restrict__ s3, const int* __restrict__ d3,
    int* __restrict__ cur8, int* __restrict__ ssh)
{
  int e = blockIdx.x * 256 + threadIdx.x;
  int sh = blockIdx.x & (NSH - 1);
  int d, s;
  if      (e < E1)          { d = d0[e];                           s = s0[e]; }
  else if (e < 2*E1)        { d = d1[e - E1] + NT;                 s = s1[e - E1]; }
  else if (e < 2*E1 + E2)   { d = d2[e - 2*E1] + NT + NA;          s = s2[e - 2*E1]; }
  else if (e < ETOT)        { d = d3[e - 2*E1 - E2] + NT + 2*NA;   s = s3[e - 2*E1 - E2]; }
  else return;
  int p = atomicAdd(&cur8[sh * NTOT + d], 1);
  ssh[p] = s;
}

// per-node total degree = sum of the 8 shard counts (run before cnt8 scan)
__global__ void sumsh_k(const int* __restrict__ cnt8, int* __restrict__ cnt)
{
  int g = blockIdx.x * 256 + threadIdx.x;
  if (g >= NTOT) return;
  int s = 0;
#pragma unroll
  for (int k = 0; k < NSH; k++) s += cnt8[k * NTOT + g];
  cnt[g] = s;
}

// merge each node's 8 shard-segments into the contiguous final CSR order
__global__ void compact_k(const int* __restrict__ rp8, const int* __restrict__ rp,
    const int* __restrict__ ssh, int* __restrict__ ssrc)
{
  int g = blockIdx.x * 256 + threadIdx.x;
  if (g >= NTOT) return;
  int w = rp[g];
#pragma unroll
  for (int s = 0; s < NSH; s++) {
    int b0 = rp8[s * NTOT + g], b1 = rp8[s * NTOT + g + 1];
    for (int e = b0; e < b1; e++) ssrc[w++] = ssh[e];
  }
}

// per-block inclusive scan (256 thr x 8) of in -> rp1 (=rp+1); totals -> bsum
__global__ __launch_bounds__(256) void scan_blk(const int* __restrict__ in,
    int* __restrict__ rp1, int* __restrict__ bsum, int n)
{
  __shared__ int sh[256];
  int base = blockIdx.x * 2048;
  int t = threadIdx.x;
  int v[8]; int s = 0;
#pragma unroll
  for (int k = 0; k < 8; k++) {
    int i = base + t * 8 + k;
    v[k] = (i < n) ? in[i] : 0; s += v[k];
  }
  sh[t] = s; __syncthreads();
  for (int o = 1; o < 256; o <<= 1) {
    int x = (t >= o) ? sh[t - o] : 0;
    __syncthreads(); sh[t] += x; __syncthreads();
  }
  int run = (t == 0) ? 0 : sh[t - 1];
  if (t == 255 && bsum) bsum[blockIdx.x] = sh[255];
#pragma unroll
  for (int k = 0; k < 8; k++) {
    int i = base + t * 8 + k;
    run += v[k];
    if (i < n) rp1[i] = run;
  }
}

// add inclusive block-offsets; writes rp[0]=0 and cursor init cur[i]=rp[i]
__global__ void scan_add2(int* __restrict__ rp, int* __restrict__ cur,
    const int* __restrict__ bsA, int n)
{
  int i = blockIdx.x * blockDim.x + threadIdx.x;
  if (i == 0) { rp[0] = 0; cur[0] = 0; }
  if (i < n) {
    int blk = i >> 11;
    int base = blk ? bsA[blk - 1] : 0;
    int v = rp[i + 1] + base;
    rp[i + 1] = v;
    if (i + 1 < n) cur[i + 1] = v;
  }
}

// add inclusive block-offsets (no cursor); writes rp[0]=0
__global__ void scan_add(int* __restrict__ rp, const int* __restrict__ bsA, int n)
{
  int i = blockIdx.x * blockDim.x + threadIdx.x;
  if (i == 0) rp[0] = 0;
  if (i < n) {
    int blk = i >> 11;
    int base = blk ? bsA[blk - 1] : 0;
    rp[i + 1] += base;
  }
}

// =============== atomic-free GAT aggregation, node per lane-group ==========
// F=128: 16 lanes/node (4 nodes/wave); F=64: 8 lanes/node (8 nodes/wave).
// Each lane owns 8 contiguous features, all in ONE head (hh=lg>>1 / lg), so
// softmax state (den) is lane-private: NO shuffles, NO cross-group reduce.
// Single pass: exp(a) without max subtraction (alphas O(1); clamp at 30),
// unnormalized accumulate, scale by 1/den at the end. ReLU+bf16 store.
struct AggTask {
  int g0, Nd;
  const float* als; const float* ald;
  const ushort* z;  ushort* out;
};

template<int F>
__global__ __launch_bounds__(256) void agg_multi(const int* __restrict__ rp,
    const int* __restrict__ ssrc, AggTask T0, AggTask T1, AggTask T2, AggTask T3,
    int c1, int c2, int c3)
{
  constexpr int LPN = (F == 128) ? 16 : 8;   // lanes per node
  constexpr int NPW = 64 / LPN;              // nodes per wave
  int b = blockIdx.x;
  AggTask T; int lb;
  if      (b < c1) { T = T0; lb = b; }
  else if (b < c2) { T = T1; lb = b - c1; }
  else if (b < c3) { T = T2; lb = b - c2; }
  else             { T = T3; lb = b - c3; }
  int wv = threadIdx.x >> 6, lane = threadIdx.x & 63;
  int grp = lane / LPN, lg = lane % LPN;
  int n = (lb * 4 + wv) * NPW + grp;
  if (n >= T.Nd) return;
  int g = T.g0 + n;
  int start = rp[g], end = rp[g + 1];
  int hh = (F == 128) ? (lg >> 1) : lg;      // head owning this lane's feats
  float ad_h = T.ald[(size_t)n * 8 + hh];

  float den = 0.f;
  float acc[8] = {};
  for (int e = start; e < end; e++) {
    int sn = ssrc[e];
    uint4 zv = *reinterpret_cast<const uint4*>(T.z + (size_t)sn * F + lg * 8);
    float a = T.als[(size_t)sn * 8 + hh] + ad_h;
    a = a > 0.f ? a : 0.2f * a;
    float p = __expf(fminf(a, 30.f));
    den += p;
    acc[0] = fmaf(p, u2f_lo(zv.x), acc[0]);
    acc[1] = fmaf(p, u2f_hi(zv.x), acc[1]);
    acc[2] = fmaf(p, u2f_lo(zv.y), acc[2]);
    acc[3] = fmaf(p, u2f_hi(zv.y), acc[3]);
    acc[4] = fmaf(p, u2f_lo(zv.z), acc[4]);
    acc[5] = fmaf(p, u2f_hi(zv.z), acc[5]);
    acc[6] = fmaf(p, u2f_lo(zv.w), acc[6]);
    acc[7] = fmaf(p, u2f_hi(zv.w), acc[7]);
  }
  float inv = 1.f / fmaxf(den, 1e-16f);
  unsigned int pk[4];
#pragma unroll
  for (int k2 = 0; k2 < 4; k2++)
    pk[k2] = (unsigned int)f2b(fmaxf(acc[2*k2] * inv, 0.f))
           | ((unsigned int)f2b(fmaxf(acc[2*k2+1] * inv, 0.f)) << 16);
  *reinterpret_cast<uint4*>(T.out + (size_t)n * F + lg * 8)
      = make_uint4(pk[0], pk[1], pk[2], pk[3]);
}

// ---- semantic softmax (K=2) combine + LayerNorm + ReLU, 2 tasks, F=128 ----
__global__ __launch_bounds__(256) void combine2_k(
    const ushort* __restrict__ o00, const ushort* __restrict__ o01,
    const float* __restrict__ sc0, float invn0, ushort* __restrict__ out0, int N0,
    const ushort* __restrict__ o10, const ushort* __restrict__ o11,
    const float* __restrict__ sc1, float invn1, ushort* __restrict__ out1, int N1,
    const float* __restrict__ g, const float* __restrict__ bb)
{
  int c1 = (N0 + 3) / 4;
  int b = blockIdx.x;
  const ushort *o0, *o1; const float* sc; float invn; ushort* outp; int N, lb;
  if (b < c1) { o0=o00; o1=o01; sc=sc0; invn=invn0; outp=out0; N=N0; lb=b; }
  else        { o0=o10; o1=o11; sc=sc1; invn=invn1; outp=out1; N=N1; lb=b-c1; }
  int wv = threadIdx.x >> 6, lane = threadIdx.x & 63;
  int n = lb * 4 + wv;
  if (n >= N) return;
  float s0 = sc[0] * invn, s1 = sc[1] * invn;
  float mx = fmaxf(s0, s1);
  float e0 = __expf(s0 - mx), e1 = __expf(s1 - mx);
  float w0 = e0 / (e0 + e1), w1 = e1 / (e0 + e1);
  float x[2];
#pragma unroll
  for (int jj = 0; jj < 2; jj++) {
    int idx = lane + 64 * jj;
    x[jj] = w0 * b2f(o0[(size_t)n * 128 + idx]) + w1 * b2f(o1[(size_t)n * 128 + idx]);
  }
  float sum = x[0] + x[1];
#pragma unroll
  for (int o = 32; o > 0; o >>= 1) sum += __shfl_xor(sum, o);
  float mu = sum / 128.f;
  float vs = 0.f;
#pragma unroll
  for (int jj = 0; jj < 2; jj++) { float dd = x[jj] - mu; vs = fmaf(dd, dd, vs); }
#pragma unroll
  for (int o = 32; o > 0; o >>= 1) vs += __shfl_xor(vs, o);
  float rstd = rsqrtf(vs / 128.f + 1e-5f);
#pragma unroll
  for (int jj = 0; jj < 2; jj++) {
    int idx = lane + 64 * jj;
    float y = (x[jj] - mu) * rstd * g[idx] + bb[idx];
    outp[(size_t)n * 128 + idx] = f2b(fmaxf(y, 0.f));
  }
}

// ---- layer-2 combine + LN + ReLU + final linear [64]->[2], F=64 ----------
__global__ __launch_bounds__(256) void combine_final_k(
    const ushort* __restrict__ o0, const ushort* __restrict__ o1,
    const float* __restrict__ sc, float invn,
    const float* __restrict__ g, const float* __restrict__ bb,
    const float* __restrict__ lw, const float* __restrict__ lb,
    float* __restrict__ outp, int N)
{
  int wv = threadIdx.x >> 6, lane = threadIdx.x & 63;
  int n = blockIdx.x * 4 + wv;
  if (n >= N) return;
  float s0 = sc[0] * invn, s1 = sc[1] * invn;
  float mx = fmaxf(s0, s1);
  float e0 = __expf(s0 - mx), e1 = __expf(s1 - mx);
  float w0 = e0 / (e0 + e1), w1 = e1 / (e0 + e1);
  float x = w0 * b2f(o0[(size_t)n * 64 + lane]) + w1 * b2f(o1[(size_t)n * 64 + lane]);
  float sum = x;
#pragma unroll
  for (int o = 32; o > 0; o >>= 1) sum += __shfl_xor(sum, o);
  float mu = sum / 64.f;
  float dd = x - mu;
  float vs = dd * dd;
#pragma unroll
  for (int o = 32; o > 0; o >>= 1) vs += __shfl_xor(vs, o);
  float rstd = rsqrtf(vs / 64.f + 1e-5f);
  float y = fmaxf((x - mu) * rstd * g[lane] + bb[lane], 0.f);
  float p0 = y * lw[lane * 2 + 0];
  float p1 = y * lw[lane * 2 + 1];
#pragma unroll
  for (int o = 32; o > 0; o >>= 1) { p0 += __shfl_xor(p0, o); p1 += __shfl_xor(p1, o); }
  if (lane == 0) {
    outp[(size_t)n * 2 + 0] = p0 + lb[0];
    outp[(size_t)n * 2 + 1] = p1 + lb[1];
  }
}

extern "C" void kernel_launch(void* const* d_in, const int* in_sizes, int n_in,
                              void* d_out, int out_size, void* d_ws, size_t ws_size,
                              hipStream_t stream)
{
  (void)in_sizes; (void)n_in; (void)out_size;
  const float* x_a = (const float*)d_in[0];
  const float* x_t = (const float*)d_in[1];
  const int* eat_s = (const int*)d_in[2];
  const int* eat_d = (const int*)d_in[3];
  const int* eta_s = (const int*)d_in[4];
  const int* eta_d = (const int*)d_in[5];
  const int* eaa_s = (const int*)d_in[6];
  const int* eaa_d = (const int*)d_in[7];
  const int* ett_s = (const int*)d_in[8];
  const int* ett_d = (const int*)d_in[9];
  const float* W_a1 = (const float*)d_in[10]; const float* b_a1 = (const float*)d_in[11];
  const float* W_t1 = (const float*)d_in[12]; const float* b_t1 = (const float*)d_in[13];
  const float* as_at1 = (const float*)d_in[14]; const float* ad_at1 = (const float*)d_in[15];
  const float* as_ta1 = (const float*)d_in[16]; const float* ad_ta1 = (const float*)d_in[17];
  const float* as_aa1 = (const float*)d_in[18]; const float* ad_aa1 = (const float*)d_in[19];
  const float* as_tt1 = (const float*)d_in[20]; const float* ad_tt1 = (const float*)d_in[21];
  const float* k1_W = (const float*)d_in[22]; const float* k1_b = (const float*)d_in[23];
  const float* q1   = (const float*)d_in[24];
  const float* W_a2 = (const float*)d_in[25]; const float* b_a2 = (const float*)d_in[26];
  const float* W_t2 = (const float*)d_in[27]; const float* b_t2 = (const float*)d_in[28];
  const float* as_ta2 = (const float*)d_in[31]; const float* ad_ta2 = (const float*)d_in[32];
  const float* as_aa2 = (const float*)d_in[33]; const float* ad_aa2 = (const float*)d_in[34];
  const float* k2_W = (const float*)d_in[37]; const float* k2_b = (const float*)d_in[38];
  const float* q2   = (const float*)d_in[39];
  const float* ln1_g = (const float*)d_in[40]; const float* ln1_b = (const float*)d_in[41];
  const float* ln2_g = (const float*)d_in[42]; const float* ln2_b = (const float*)d_in[43];
  const float* lin_W = (const float*)d_in[44]; const float* lin_b = (const float*)d_in[45];

  char* ws = (char*)d_ws;
  size_t off = 0;
  auto alloc = [&](size_t bytes) {
    size_t o = off; off += (bytes + 255) & ~(size_t)255; return o;
  };
  size_t ZA1 = alloc((size_t)NA * HID * 2);     // bf16 z_a; layer2 za2 aliases
  size_t ZT1 = alloc((size_t)NT * HID * 2);     // bf16 z_t; layer2 zt2 aliases
  size_t OTA = alloc((size_t)NA * HID * 2);     // bf16 o_ta -> xa1 in-place
  size_t OAA = alloc((size_t)NA * HID * 2);     // bf16 o_aa; L2: ota2|oaa2 alias
  size_t OAT = alloc((size_t)NT * HID * 2);     // bf16 o_at -> xt1 in-place
  size_t OTT = alloc((size_t)NT * HID * 2);
  size_t A_AS_AT = alloc((size_t)NA * 8 * 4);
  size_t A_AD_TA = alloc((size_t)NA * 8 * 4);
  size_t A_AS_AA = alloc((size_t)NA * 8 * 4);
  size_t A_AD_AA = alloc((size_t)NA * 8 * 4);
  size_t A_T_D_AT = alloc((size_t)NT * 8 * 4);
  size_t A_T_S_TA = alloc((size_t)NT * 8 * 4);
  size_t A_T_S_TT = alloc((size_t)NT * 8 * 4);
  size_t A_T_D_TT = alloc((size_t)NT * 8 * 4);
  // sharded CSR build + compacted final CSR
  size_t RP8  = alloc(((size_t)NSH * NTOT + 1) * 4);
  size_t CUR8 = alloc((size_t)NSH * NTOT * 4);  // doubles as sharded hist
  size_t SSH  = alloc((size_t)ETOT * 4);
  size_t RP   = alloc((size_t)(NTOT + 1) * 4);
  size_t CNT  = alloc((size_t)NTOT * 4);
  size_t SS   = alloc((size_t)ETOT * 4);
  size_t BSM  = alloc(2048 * 4);
  size_t BSM2 = alloc(256 * 4);
  size_t SC   = alloc(256);                     // 6 score accumulators
  if (off > ws_size) return;                    // fail visibly

  ushort* za1 = (ushort*)(ws + ZA1);
  ushort* zt1 = (ushort*)(ws + ZT1);
  ushort* ota = (ushort*)(ws + OTA);
  ushort* oaa = (ushort*)(ws + OAA);
  ushort* oat = (ushort*)(ws + OAT);
  ushort* ott = (ushort*)(ws + OTT);
  float* aASAT = (float*)(ws + A_AS_AT);
  float* aADTA = (float*)(ws + A_AD_TA);
  float* aASAA = (float*)(ws + A_AS_AA);
  float* aADAA = (float*)(ws + A_AD_AA);
  float* aTDAT = (float*)(ws + A_T_D_AT);
  float* aTSTA = (float*)(ws + A_T_S_TA);
  float* aTSTT = (float*)(ws + A_T_S_TT);
  float* aTDTT = (float*)(ws + A_T_D_TT);
  int* rp8  = (int*)(ws + RP8);
  int* cur8 = (int*)(ws + CUR8);
  int* ssh  = (int*)(ws + SSH);
  int* rp   = (int*)(ws + RP);
  int* cnt  = (int*)(ws + CNT);
  int* ssrc = (int*)(ws + SS);
  int* bsum = (int*)(ws + BSM);
  int* bsum2= (int*)(ws + BSM2);
  float* scp = (float*)(ws + SC);
  // layer-2 aliases
  ushort* za2 = za1;                                   // [NA,64] bf16
  ushort* zt2 = zt1;                                   // [NT,64] bf16
  ushort* ota2 = oaa;                                  // [NA,64] bf16
  ushort* oaa2 = (ushort*)(ws + OAA + (size_t)NA * OUTF * 2);  // [NA,64] bf16

  const int GA = (NA + 63) / 64, GT = (NT + 63) / 64;
  const int EBL = (ETOT + 255) / 256;
  const int SCN8 = NSH * NTOT;                 // 2.4M sharded scan elements
  const int SBL8 = (SCN8 + 2047) / 2048;       // 1172
  const int SBL1 = (NTOT + 2047) / 2048;       // 147

  // ---- sharded CSR build + compact ----
  hipMemsetAsync(cur8, 0, (size_t)SCN8 * 4, stream);
  hist4_sh<<<EBL, 256, 0, stream>>>(eat_d, eta_d, eaa_d, ett_d, cur8, scp);
  sumsh_k<<<(NTOT + 255) / 256, 256, 0, stream>>>(cur8, cnt);
  scan_blk<<<SBL8, 256, 0, stream>>>(cur8, rp8 + 1, bsum, SCN8);
  scan_blk<<<1, 256, 0, stream>>>(bsum, bsum, nullptr, SBL8);
  scan_add2<<<(SCN8 + 255) / 256, 256, 0, stream>>>(rp8, cur8, bsum, SCN8);
  scan_blk<<<SBL1, 256, 0, stream>>>(cnt, rp + 1, bsum2, NTOT);
  scan_blk<<<1, 256, 0, stream>>>(bsum2, bsum2, nullptr, SBL1);
  scan_add<<<(NTOT + 255) / 256, 256, 0, stream>>>(rp, bsum2, NTOT);
  scatter_sh<<<EBL, 256, 0, stream>>>(eat_s, eat_d, eta_s, eta_d,
                                      eaa_s, eaa_d, ett_s, ett_d, cur8, ssh);
  compact_k<<<(NTOT + 255) / 256, 256, 0, stream>>>(rp8, rp, ssh, ssrc);

  // ============ Layer 1 ============
  zgemm_k<4,16,float><<<dim3(GA,2),256,0,stream>>>(x_a, W_a1, b_a1,
      as_at1, ad_ta1, as_aa1, ad_aa1, aASAT, aADTA, aASAA, aADAA,
      za1, NA, FA, HID);
  zgemm_k<4,16,float><<<dim3(GT,2),256,0,stream>>>(x_t, W_t1, b_t1,
      ad_at1, as_ta1, as_tt1, ad_tt1, aTDAT, aTSTA, aTSTT, aTDTT,
      zt1, NT, FT, HID);
  {
    // F=128: 16 nodes per block (4 waves x 4 nodes)
    const int BT = (NT + 15) / 16, BA = (NA + 15) / 16;
    AggTask T0{0,          NT, aASAT, aTDAT, za1, oat};
    AggTask T1{NT,         NA, aTSTA, aADTA, zt1, ota};
    AggTask T2{NT+NA,      NA, aASAA, aADAA, za1, oaa};
    AggTask T3{NT+2*NA,    NT, aTSTT, aTDTT, zt1, ott};
    agg_multi<128><<<2*BT + 2*BA, 256, 0, stream>>>(rp, ssrc,
        T0, T1, T2, T3, BT, BT + BA, BT + 2*BA);
  }
  score_k<<<4*GA + 4*GT, 256, 0, stream>>>(ota, oaa, oat, ott,
      k1_W, k1_b, q1, scp,
      make_int4(2*GA, 4*GA, 4*GA + 2*GT, 4*GA + 4*GT),
      make_int4(NA, NA, NT, NT), make_int4(GA, GA, GT, GT), HID, HID);
  combine2_k<<<(NA/4) + (NT/4), 256, 0, stream>>>(
      ota, oaa, scp + 0, 1.f/NA, ota, NA,
      oat, ott, scp + 2, 1.f/NT, oat, NT, ln1_g, ln1_b);

  // ============ Layer 2 (only the address path feeds the output) ============
  zgemm_k<3,8,ushort><<<dim3(GA,1),256,0,stream>>>(ota, W_a2, b_a2,
      ad_ta2, as_aa2, ad_aa2, nullptr, aADTA, aASAA, aADAA, nullptr,
      za2, NA, HID, OUTF);
  zgemm_k<1,8,ushort><<<dim3(GT,1),256,0,stream>>>(oat, W_t2, b_t2,
      as_ta2, nullptr, nullptr, nullptr, aTSTA, nullptr, nullptr, nullptr,
      zt2, NT, HID, OUTF);
  {
    // F=64: 32 nodes per block (4 waves x 8 nodes)
    const int BA2 = (NA + 31) / 32;
    AggTask T0{NT,    NA, aTSTA, aADTA, zt2, ota2};
    AggTask T1{NT+NA, NA, aASAA, aADAA, za2, oaa2};
    agg_multi<64><<<2*BA2, 256, 0, stream>>>(rp, ssrc,
        T0, T1, T1, T1, BA2, 2*BA2, 2*BA2);
  }
  score_k<<<2*GA, 256, 0, stream>>>(ota2, oaa2, ota2, ota2,
      k2_W, k2_b, q2, scp + 4,
      make_int4(GA, 2*GA, 2*GA, 2*GA),
      make_int4(NA, NA, NA, NA), make_int4(GA, GA, GA, GA), OUTF, OUTF);
  combine_final_k<<<NA/4, 256, 0, stream>>>(ota2, oaa2, scp + 4, 1.f/NA,
      ln2_g, ln2_b, lin_W, lin_b, (float*)d_out, NA);
}

// Round 8
// 600.691 us; speedup vs baseline: 1.7792x; 1.0055x over previous
//
#include <hip/hip_runtime.h>
#include <cstdint>
#include <cstddef>
#include <type_traits>

#define NA 50000
#define NT 100000
#define FA 128
#define FT 64
#define HID 128
#define OUTF 64
#define HEADS 8
#define E1 500000
#define E2 250000
#define NTOT (2*NT + 2*NA)          // concatenated dst-node space [at|ta|aa|tt]
#define ETOT (2*E1 + 2*E2)          // concatenated edge space
#define NSH 8                       // CSR build shards (== XCDs heuristic)

typedef __attribute__((ext_vector_type(8))) short short8;
typedef __attribute__((ext_vector_type(4))) float f32x4;

static __device__ __forceinline__ ushort f2b(float f) {  // f32 -> bf16 RNE
  unsigned int u = __float_as_uint(f);
  return (ushort)((u + 0x7fffu + ((u >> 16) & 1u)) >> 16);
}
static __device__ __forceinline__ float b2f(ushort b) {
  return __uint_as_float(((unsigned int)b) << 16);
}
static __device__ __forceinline__ float u2f_lo(unsigned int u) {
  return __uint_as_float(u << 16);
}
static __device__ __forceinline__ float u2f_hi(unsigned int u) {
  return __uint_as_float(u & 0xffff0000u);
}

// ---------- full-K single-stage MFMA tile: 64 rows x 64 cols x K -----------
// Entire K-panel staged once (padded stride K+8 kills bank alignment), ONE
// barrier, then K/32 x 4 back-to-back MFMAs. AT = float (convert) or ushort.
template<int KK, typename AT>
__device__ __forceinline__ void gemm_fullk(
    const AT* __restrict__ A, const float* __restrict__ W,
    int N, int M, int row0, int col0,
    ushort* __restrict__ Als, ushort* __restrict__ Bls, f32x4* acc)
{
  constexpr int LP = KK + 8;                 // padded LDS row stride
  int t = threadIdx.x;
  int w = t >> 6, lane = t & 63;
  int l15 = lane & 15, l4 = lane >> 4;
  // ---- stage A: 4 threads/row, each KK/4 contiguous cols ----
  {
    int arow = t >> 2, ac0 = (t & 3) * (KK / 4);
    bool aok = (row0 + arow) < N;
    const AT* Ap = A + (size_t)(row0 + arow) * KK + ac0;
#pragma unroll
    for (int j = 0; j < KK / 32; j++) {
      union { ushort u[8]; uint4 v; } pa;
      if (aok) {
        if constexpr (std::is_same<AT, float>::value) {
          float4 a0 = *reinterpret_cast<const float4*>(Ap + j*8);
          float4 a1 = *reinterpret_cast<const float4*>(Ap + j*8 + 4);
          pa.u[0]=f2b(a0.x); pa.u[1]=f2b(a0.y); pa.u[2]=f2b(a0.z); pa.u[3]=f2b(a0.w);
          pa.u[4]=f2b(a1.x); pa.u[5]=f2b(a1.y); pa.u[6]=f2b(a1.z); pa.u[7]=f2b(a1.w);
        } else {
          pa.v = *reinterpret_cast<const uint4*>(Ap + j*8);
        }
      } else {
        pa.v = make_uint4(0,0,0,0);
      }
      *reinterpret_cast<uint4*>(&Als[arow * LP + ac0 + j*8]) = pa.v;
    }
  }
  // ---- stage B: 4 threads/col, each KK/4 k values (strided W reads) ----
  {
    int col = t & 63, kb = t >> 6;
    const float* Wp = W + (size_t)(col0 + col);
#pragma unroll
    for (int j = 0; j < KK / 32; j++) {
      int k0 = kb * (KK / 4) + j * 8;
      union { ushort u[8]; uint4 v; } pb;
#pragma unroll
      for (int i = 0; i < 8; i++)
        pb.u[i] = f2b(Wp[(size_t)(k0 + i) * M]);
      *reinterpret_cast<uint4*>(&Bls[col * LP + k0]) = pb.v;
    }
  }
  __syncthreads();
#pragma unroll
  for (int ks = 0; ks < KK / 32; ks++) {
    short8 af = *reinterpret_cast<const short8*>(
        &Als[(16*w + l15) * LP + ks*32 + l4*8]);
#pragma unroll
    for (int n = 0; n < 4; n++) {
      short8 bf = *reinterpret_cast<const short8*>(
          &Bls[(16*n + l15) * LP + ks*32 + l4*8]);
      acc[n] = __builtin_amdgcn_mfma_f32_16x16x32_bf16(af, bf, acc[n], 0, 0, 0);
    }
  }
}

// ====== z-projection GEMM + bf16 store + fused per-node alpha epilogue =====
// DD = head dim (16 for M=128, 8 for M=64); NV alpha vectors.
template<int NV, int DD, int KK, typename AT>
__global__ __launch_bounds__(256) void zgemm_k(
    const AT* __restrict__ A, const float* __restrict__ W,
    const float* __restrict__ bias,
    const float* __restrict__ v0, const float* __restrict__ v1,
    const float* __restrict__ v2, const float* __restrict__ v3,
    float* __restrict__ o0, float* __restrict__ o1,
    float* __restrict__ o2, float* __restrict__ o3,
    ushort* __restrict__ Cb, int N, int M)
{
  __shared__ __align__(16) ushort Als[64 * (KK + 8)];
  __shared__ __align__(16) ushort Bls[64 * (KK + 8)];
  int t = threadIdx.x;
  int row0 = blockIdx.x * 64, col0 = blockIdx.y * 64;
  int w = t >> 6, lane = t & 63;
  int l15 = lane & 15, l4 = lane >> 4;
  f32x4 acc[4] = {{0.f,0.f,0.f,0.f},{0.f,0.f,0.f,0.f},
                  {0.f,0.f,0.f,0.f},{0.f,0.f,0.f,0.f}};
  gemm_fullk<KK, AT>(A, W, N, M, row0, col0, Als, Bls, acc);

  float vals[4][4];
#pragma unroll
  for (int n = 0; n < 4; n++) {
    int col = col0 + 16*n + l15;
    float bv = bias[col];
#pragma unroll
    for (int r = 0; r < 4; r++) {
      int row = row0 + 16*w + l4*4 + r;
      float v = acc[n][r] + bv;
      vals[n][r] = v;
      if (row < N) Cb[(size_t)row * M + col] = f2b(v);
    }
  }
  // alpha epilogue: head dot over DD cols via cross-lane reduce in l15 group
#pragma unroll
  for (int n = 0; n < 4; n++) {
    int head = (DD == 16) ? (blockIdx.y*4 + n) : (n*2 + (l15 >> 3));
    int vi = head * DD + (l15 & (DD - 1));
    float w0 = v0[vi];
    float w1 = (NV > 1) ? v1[vi] : 0.f;
    float w2 = (NV > 2) ? v2[vi] : 0.f;
    float w3 = (NV > 3) ? v3[vi] : 0.f;
#pragma unroll
    for (int r = 0; r < 4; r++) {
      int row = row0 + 16*w + l4*4 + r;
      float zv = vals[n][r];
      float a0 = zv * w0, a1 = zv * w1, a2 = zv * w2, a3 = zv * w3;
#pragma unroll
      for (int o = 1; o < DD; o <<= 1) {
        a0 += __shfl_xor(a0, o);
        if (NV > 1) a1 += __shfl_xor(a1, o);
        if (NV > 2) a2 += __shfl_xor(a2, o);
        if (NV > 3) a3 += __shfl_xor(a3, o);
      }
      if ((l15 & (DD - 1)) == 0 && row < N) {
        o0[(size_t)row * 8 + head] = a0;
        if (NV > 1) o1[(size_t)row * 8 + head] = a1;
        if (NV > 2) o2[(size_t)row * 8 + head] = a2;
        if (NV > 3) o3[(size_t)row * 8 + head] = a3;
      }
    }
  }
}

// ====== multi-task score GEMM (bf16 A): atomicAdd(scp[t], sum tanh(C+b)*q) ==
template<int KK>
__global__ __launch_bounds__(256) void score_k(
    const ushort* __restrict__ A0, const ushort* __restrict__ A1,
    const ushort* __restrict__ A2, const ushort* __restrict__ A3,
    const float* __restrict__ W, const float* __restrict__ bias,
    const float* __restrict__ qv, float* __restrict__ scp,
    int4 cum, int4 Ns, int4 Gs, int M)
{
  __shared__ __align__(16) ushort Als[64 * (KK + 8)];
  __shared__ __align__(16) ushort Bls[64 * (KK + 8)];
  __shared__ float red[4];
  int b = blockIdx.x;
  int tsk, base, G, N; const ushort* A;
  if      (b < cum.x) { tsk=0; base=0;     G=Gs.x; N=Ns.x; A=A0; }
  else if (b < cum.y) { tsk=1; base=cum.x; G=Gs.y; N=Ns.y; A=A1; }
  else if (b < cum.z) { tsk=2; base=cum.y; G=Gs.z; N=Ns.z; A=A2; }
  else                { tsk=3; base=cum.z; G=Gs.w; N=Ns.w; A=A3; }
  int local = b - base;
  int row0 = (local % G) * 64, col0 = (local / G) * 64;
  int t = threadIdx.x;
  int w = t >> 6, lane = t & 63;
  int l15 = lane & 15, l4 = lane >> 4;
  f32x4 acc[4] = {{0.f,0.f,0.f,0.f},{0.f,0.f,0.f,0.f},
                  {0.f,0.f,0.f,0.f},{0.f,0.f,0.f,0.f}};
  gemm_fullk<KK, ushort>(A, W, N, M, row0, col0, Als, Bls, acc);

  float local_s = 0.f;
#pragma unroll
  for (int n = 0; n < 4; n++) {
    int col = col0 + 16*n + l15;
    float bv = bias[col], qq = qv[col];
#pragma unroll
    for (int r = 0; r < 4; r++) {
      int row = row0 + 16*w + l4*4 + r;
      if (row < N) local_s += tanhf(acc[n][r] + bv) * qq;
    }
  }
#pragma unroll
  for (int o = 32; o > 0; o >>= 1) local_s += __shfl_xor(local_s, o);
  if (lane == 0) red[w] = local_s;
  __syncthreads();
  if (t == 0) atomicAdd(&scp[tsk], red[0] + red[1] + red[2] + red[3]);
}

// ============== XCD-sharded CSR build + compaction =========================
__global__ void hist4_sh(const int* __restrict__ d0, const int* __restrict__ d1,
    const int* __restrict__ d2, const int* __restrict__ d3,
    int* __restrict__ cnt8, float* __restrict__ scp)
{
  if (blockIdx.x == 0 && threadIdx.x < 8) scp[threadIdx.x] = 0.f;
  int e = blockIdx.x * 256 + threadIdx.x;
  int sh = blockIdx.x & (NSH - 1);
  int d;
  if      (e < E1)          d = d0[e];
  else if (e < 2*E1)        d = d1[e - E1] + NT;
  else if (e < 2*E1 + E2)   d = d2[e - 2*E1] + NT + NA;
  else if (e < ETOT)        d = d3[e - 2*E1 - E2] + NT + 2*NA;
  else return;
  atomicAdd(&cnt8[sh * NTOT + d], 1);
}

__global__ void scatter_sh(const int* __restrict__ s0, const int* __restrict__ d0,
    const int* __restrict__ s1, const int* __restrict__ d1,
    const int* __restrict__ s2, const int* __restrict__ d2,
    const int* __restrict__ s3, const int* __restrict__ d3,
    int* __restrict__ cur8, int* __restrict__ ssh)
{
  int e = blockIdx.x * 256 + threadIdx.x;
  int sh = blockIdx.x & (NSH - 1);
  int d, s;
  if      (e < E1)          { d = d0[e];                           s = s0[e]; }
  else if (e < 2*E1)        { d = d1[e - E1] + NT;                 s = s1[e - E1]; }
  else if (e < 2*E1 + E2)   { d = d2[e - 2*E1] + NT + NA;          s = s2[e - 2*E1]; }
  else if (e < ETOT)        { d = d3[e - 2*E1 - E2] + NT + 2*NA;   s = s3[e - 2*E1 - E2]; }
  else return;
  int p = atomicAdd(&cur8[sh * NTOT + d], 1);
  ssh[p] = s;
}

// per-node total degree = sum of the 8 shard counts (run before cnt8 scan)
__global__ void sumsh_k(const int* __restrict__ cnt8, int* __restrict__ cnt)
{
  int g = blockIdx.x * 256 + threadIdx.x;
  if (g >= NTOT) return;
  int s = 0;
#pragma unroll
  for (int k = 0; k < NSH; k++) s += cnt8[k * NTOT + g];
  cnt[g] = s;
}

// merge each node's 8 shard-segments into the contiguous final CSR order
__global__ void compact_k(const int* __restrict__ rp8, const int* __restrict__ rp,
    const int* __restrict__ ssh, int* __restrict__ ssrc)
{
  int g = blockIdx.x * 256 + threadIdx.x;
  if (g >= NTOT) return;
  int w = rp[g];
#pragma unroll
  for (int s = 0; s < NSH; s++) {
    int b0 = rp8[s * NTOT + g], b1 = rp8[s * NTOT + g + 1];
    for (int e = b0; e < b1; e++) ssrc[w++] = ssh[e];
  }
}

// per-block inclusive scan (256 thr x 8) of in -> rp1 (=rp+1); totals -> bsum
__global__ __launch_bounds__(256) void scan_blk(const int* __restrict__ in,
    int* __restrict__ rp1, int* __restrict__ bsum, int n)
{
  __shared__ int sh[256];
  int base = blockIdx.x * 2048;
  int t = threadIdx.x;
  int v[8]; int s = 0;
#pragma unroll
  for (int k = 0; k < 8; k++) {
    int i = base + t * 8 + k;
    v[k] = (i < n) ? in[i] : 0; s += v[k];
  }
  sh[t] = s; __syncthreads();
  for (int o = 1; o < 256; o <<= 1) {
    int x = (t >= o) ? sh[t - o] : 0;
    __syncthreads(); sh[t] += x; __syncthreads();
  }
  int run = (t == 0) ? 0 : sh[t - 1];
  if (t == 255 && bsum) bsum[blockIdx.x] = sh[255];
#pragma unroll
  for (int k = 0; k < 8; k++) {
    int i = base + t * 8 + k;
    run += v[k];
    if (i < n) rp1[i] = run;
  }
}

// add inclusive block-offsets; writes rp[0]=0 and cursor init cur[i]=rp[i]
__global__ void scan_add2(int* __restrict__ rp, int* __restrict__ cur,
    const int* __restrict__ bsA, int n)
{
  int i = blockIdx.x * blockDim.x + threadIdx.x;
  if (i == 0) { rp[0] = 0; cur[0] = 0; }
  if (i < n) {
    int blk = i >> 11;
    int base = blk ? bsA[blk - 1] : 0;
    int v = rp[i + 1] + base;
    rp[i + 1] = v;
    if (i + 1 < n) cur[i + 1] = v;
  }
}

// add inclusive block-offsets (no cursor); writes rp[0]=0
__global__ void scan_add(int* __restrict__ rp, const int* __restrict__ bsA, int n)
{
  int i = blockIdx.x * blockDim.x + threadIdx.x;
  if (i == 0) rp[0] = 0;
  if (i < n) {
    int blk = i >> 11;
    int base = blk ? bsA[blk - 1] : 0;
    rp[i + 1] += base;
  }
}

// =============== atomic-free GAT aggregation, node per lane-group ==========
// F=128: 16 lanes/node (4 nodes/wave); F=64: 8 lanes/node (8 nodes/wave).
// Lane-private softmax state (features of one head per lane); single pass
// exp without max-subtract (alphas O(1), clamp 30); ReLU + bf16 store.
struct AggTask {
  int g0, Nd;
  const float* als; const float* ald;
  const ushort* z;  ushort* out;
};

template<int F>
__global__ __launch_bounds__(256) void agg_multi(const int* __restrict__ rp,
    const int* __restrict__ ssrc, AggTask T0, AggTask T1, AggTask T2, AggTask T3,
    int c1, int c2, int c3)
{
  constexpr int LPN = (F == 128) ? 16 : 8;   // lanes per node
  constexpr int NPW = 64 / LPN;              // nodes per wave
  int b = blockIdx.x;
  AggTask T; int lb;
  if      (b < c1) { T = T0; lb = b; }
  else if (b < c2) { T = T1; lb = b - c1; }
  else if (b < c3) { T = T2; lb = b - c2; }
  else             { T = T3; lb = b - c3; }
  int wv = threadIdx.x >> 6, lane = threadIdx.x & 63;
  int grp = lane / LPN, lg = lane % LPN;
  int n = (lb * 4 + wv) * NPW + grp;
  if (n >= T.Nd) return;
  int g = T.g0 + n;
  int start = rp[g], end = rp[g + 1];
  int hh = (F == 128) ? (lg >> 1) : lg;      // head owning this lane's feats
  float ad_h = T.ald[(size_t)n * 8 + hh];

  float den = 0.f;
  float acc[8] = {};
  for (int e = start; e < end; e++) {
    int sn = ssrc[e];
    uint4 zv = *reinterpret_cast<const uint4*>(T.z + (size_t)sn * F + lg * 8);
    float a = T.als[(size_t)sn * 8 + hh] + ad_h;
    a = a > 0.f ? a : 0.2f * a;
    float p = __expf(fminf(a, 30.f));
    den += p;
    acc[0] = fmaf(p, u2f_lo(zv.x), acc[0]);
    acc[1] = fmaf(p, u2f_hi(zv.x), acc[1]);
    acc[2] = fmaf(p, u2f_lo(zv.y), acc[2]);
    acc[3] = fmaf(p, u2f_hi(zv.y), acc[3]);
    acc[4] = fmaf(p, u2f_lo(zv.z), acc[4]);
    acc[5] = fmaf(p, u2f_hi(zv.z), acc[5]);
    acc[6] = fmaf(p, u2f_lo(zv.w), acc[6]);
    acc[7] = fmaf(p, u2f_hi(zv.w), acc[7]);
  }
  float inv = 1.f / fmaxf(den, 1e-16f);
  unsigned int pk[4];
#pragma unroll
  for (int k2 = 0; k2 < 4; k2++)
    pk[k2] = (unsigned int)f2b(fmaxf(acc[2*k2] * inv, 0.f))
           | ((unsigned int)f2b(fmaxf(acc[2*k2+1] * inv, 0.f)) << 16);
  *reinterpret_cast<uint4*>(T.out + (size_t)n * F + lg * 8)
      = make_uint4(pk[0], pk[1], pk[2], pk[3]);
}

// ---- semantic softmax (K=2) combine + LayerNorm + ReLU, 2 tasks, F=128 ----
__global__ __launch_bounds__(256) void combine2_k(
    const ushort* __restrict__ o00, const ushort* __restrict__ o01,
    const float* __restrict__ sc0, float invn0, ushort* __restrict__ out0, int N0,
    const ushort* __restrict__ o10, const ushort* __restrict__ o11,
    const float* __restrict__ sc1, float invn1, ushort* __restrict__ out1, int N1,
    const float* __restrict__ g, const float* __restrict__ bb)
{
  int c1 = (N0 + 3) / 4;
  int b = blockIdx.x;
  const ushort *o0, *o1; const float* sc; float invn; ushort* outp; int N, lb;
  if (b < c1) { o0=o00; o1=o01; sc=sc0; invn=invn0; outp=out0; N=N0; lb=b; }
  else        { o0=o10; o1=o11; sc=sc1; invn=invn1; outp=out1; N=N1; lb=b-c1; }
  int wv = threadIdx.x >> 6, lane = threadIdx.x & 63;
  int n = lb * 4 + wv;
  if (n >= N) return;
  float s0 = sc[0] * invn, s1 = sc[1] * invn;
  float mx = fmaxf(s0, s1);
  float e0 = __expf(s0 - mx), e1 = __expf(s1 - mx);
  float w0 = e0 / (e0 + e1), w1 = e1 / (e0 + e1);
  float x[2];
#pragma unroll
  for (int jj = 0; jj < 2; jj++) {
    int idx = lane + 64 * jj;
    x[jj] = w0 * b2f(o0[(size_t)n * 128 + idx]) + w1 * b2f(o1[(size_t)n * 128 + idx]);
  }
  float sum = x[0] + x[1];
#pragma unroll
  for (int o = 32; o > 0; o >>= 1) sum += __shfl_xor(sum, o);
  float mu = sum / 128.f;
  float vs = 0.f;
#pragma unroll
  for (int jj = 0; jj < 2; jj++) { float dd = x[jj] - mu; vs = fmaf(dd, dd, vs); }
#pragma unroll
  for (int o = 32; o > 0; o >>= 1) vs += __shfl_xor(vs, o);
  float rstd = rsqrtf(vs / 128.f + 1e-5f);
#pragma unroll
  for (int jj = 0; jj < 2; jj++) {
    int idx = lane + 64 * jj;
    float y = (x[jj] - mu) * rstd * g[idx] + bb[idx];
    outp[(size_t)n * 128 + idx] = f2b(fmaxf(y, 0.f));
  }
}

// ---- layer-2 combine + LN + ReLU + final linear [64]->[2], F=64 ----------
__global__ __launch_bounds__(256) void combine_final_k(
    const ushort* __restrict__ o0, const ushort* __restrict__ o1,
    const float* __restrict__ sc, float invn,
    const float* __restrict__ g, const float* __restrict__ bb,
    const float* __restrict__ lw, const float* __restrict__ lb,
    float* __restrict__ outp, int N)
{
  int wv = threadIdx.x >> 6, lane = threadIdx.x & 63;
  int n = blockIdx.x * 4 + wv;
  if (n >= N) return;
  float s0 = sc[0] * invn, s1 = sc[1] * invn;
  float mx = fmaxf(s0, s1);
  float e0 = __expf(s0 - mx), e1 = __expf(s1 - mx);
  float w0 = e0 / (e0 + e1), w1 = e1 / (e0 + e1);
  float x = w0 * b2f(o0[(size_t)n * 64 + lane]) + w1 * b2f(o1[(size_t)n * 64 + lane]);
  float sum = x;
#pragma unroll
  for (int o = 32; o > 0; o >>= 1) sum += __shfl_xor(sum, o);
  float mu = sum / 64.f;
  float dd = x - mu;
  float vs = dd * dd;
#pragma unroll
  for (int o = 32; o > 0; o >>= 1) vs += __shfl_xor(vs, o);
  float rstd = rsqrtf(vs / 64.f + 1e-5f);
  float y = fmaxf((x - mu) * rstd * g[lane] + bb[lane], 0.f);
  float p0 = y * lw[lane * 2 + 0];
  float p1 = y * lw[lane * 2 + 1];
#pragma unroll
  for (int o = 32; o > 0; o >>= 1) { p0 += __shfl_xor(p0, o); p1 += __shfl_xor(p1, o); }
  if (lane == 0) {
    outp[(size_t)n * 2 + 0] = p0 + lb[0];
    outp[(size_t)n * 2 + 1] = p1 + lb[1];
  }
}

extern "C" void kernel_launch(void* const* d_in, const int* in_sizes, int n_in,
                              void* d_out, int out_size, void* d_ws, size_t ws_size,
                              hipStream_t stream)
{
  (void)in_sizes; (void)n_in; (void)out_size;
  const float* x_a = (const float*)d_in[0];
  const float* x_t = (const float*)d_in[1];
  const int* eat_s = (const int*)d_in[2];
  const int* eat_d = (const int*)d_in[3];
  const int* eta_s = (const int*)d_in[4];
  const int* eta_d = (const int*)d_in[5];
  const int* eaa_s = (const int*)d_in[6];
  const int* eaa_d = (const int*)d_in[7];
  const int* ett_s = (const int*)d_in[8];
  const int* ett_d = (const int*)d_in[9];
  const float* W_a1 = (const float*)d_in[10]; const float* b_a1 = (const float*)d_in[11];
  const float* W_t1 = (const float*)d_in[12]; const float* b_t1 = (const float*)d_in[13];
  const float* as_at1 = (const float*)d_in[14]; const float* ad_at1 = (const float*)d_in[15];
  const float* as_ta1 = (const float*)d_in[16]; const float* ad_ta1 = (const float*)d_in[17];
  const float* as_aa1 = (const float*)d_in[18]; const float* ad_aa1 = (const float*)d_in[19];
  const float* as_tt1 = (const float*)d_in[20]; const float* ad_tt1 = (const float*)d_in[21];
  const float* k1_W = (const float*)d_in[22]; const float* k1_b = (const float*)d_in[23];
  const float* q1   = (const float*)d_in[24];
  const float* W_a2 = (const float*)d_in[25]; const float* b_a2 = (const float*)d_in[26];
  const float* W_t2 = (const float*)d_in[27]; const float* b_t2 = (const float*)d_in[28];
  const float* as_ta2 = (const float*)d_in[31]; const float* ad_ta2 = (const float*)d_in[32];
  const float* as_aa2 = (const float*)d_in[33]; const float* ad_aa2 = (const float*)d_in[34];
  const float* k2_W = (const float*)d_in[37]; const float* k2_b = (const float*)d_in[38];
  const float* q2   = (const float*)d_in[39];
  const float* ln1_g = (const float*)d_in[40]; const float* ln1_b = (const float*)d_in[41];
  const float* ln2_g = (const float*)d_in[42]; const float* ln2_b = (const float*)d_in[43];
  const float* lin_W = (const float*)d_in[44]; const float* lin_b = (const float*)d_in[45];

  char* ws = (char*)d_ws;
  size_t off = 0;
  auto alloc = [&](size_t bytes) {
    size_t o = off; off += (bytes + 255) & ~(size_t)255; return o;
  };
  size_t ZA1 = alloc((size_t)NA * HID * 2);     // bf16 z_a; layer2 za2 aliases
  size_t ZT1 = alloc((size_t)NT * HID * 2);     // bf16 z_t; layer2 zt2 aliases
  size_t OTA = alloc((size_t)NA * HID * 2);     // bf16 o_ta -> xa1 in-place
  size_t OAA = alloc((size_t)NA * HID * 2);     // bf16 o_aa; L2: ota2|oaa2 alias
  size_t OAT = alloc((size_t)NT * HID * 2);     // bf16 o_at -> xt1 in-place
  size_t OTT = alloc((size_t)NT * HID * 2);
  size_t A_AS_AT = alloc((size_t)NA * 8 * 4);
  size_t A_AD_TA = alloc((size_t)NA * 8 * 4);
  size_t A_AS_AA = alloc((size_t)NA * 8 * 4);
  size_t A_AD_AA = alloc((size_t)NA * 8 * 4);
  size_t A_T_D_AT = alloc((size_t)NT * 8 * 4);
  size_t A_T_S_TA = alloc((size_t)NT * 8 * 4);
  size_t A_T_S_TT = alloc((size_t)NT * 8 * 4);
  size_t A_T_D_TT = alloc((size_t)NT * 8 * 4);
  // sharded CSR build + compacted final CSR
  size_t RP8  = alloc(((size_t)NSH * NTOT + 1) * 4);
  size_t CUR8 = alloc((size_t)NSH * NTOT * 4);  // doubles as sharded hist
  size_t SSH  = alloc((size_t)ETOT * 4);
  size_t RP   = alloc((size_t)(NTOT + 1) * 4);
  size_t CNT  = alloc((size_t)NTOT * 4);
  size_t SS   = alloc((size_t)ETOT * 4);
  size_t BSM  = alloc(2048 * 4);
  size_t BSM2 = alloc(256 * 4);
  size_t SC   = alloc(256);                     // 6 score accumulators
  if (off > ws_size) return;                    // fail visibly

  ushort* za1 = (ushort*)(ws + ZA1);
  ushort* zt1 = (ushort*)(ws + ZT1);
  ushort* ota = (ushort*)(ws + OTA);
  ushort* oaa = (ushort*)(ws + OAA);
  ushort* oat = (ushort*)(ws + OAT);
  ushort* ott = (ushort*)(ws + OTT);
  float* aASAT = (float*)(ws + A_AS_AT);
  float* aADTA = (float*)(ws + A_AD_TA);
  float* aASAA = (float*)(ws + A_AS_AA);
  float* aADAA = (float*)(ws + A_AD_AA);
  float* aTDAT = (float*)(ws + A_T_D_AT);
  float* aTSTA = (float*)(ws + A_T_S_TA);
  float* aTSTT = (float*)(ws + A_T_S_TT);
  float* aTDTT = (float*)(ws + A_T_D_TT);
  int* rp8  = (int*)(ws + RP8);
  int* cur8 = (int*)(ws + CUR8);
  int* ssh  = (int*)(ws + SSH);
  int* rp   = (int*)(ws + RP);
  int* cnt  = (int*)(ws + CNT);
  int* ssrc = (int*)(ws + SS);
  int* bsum = (int*)(ws + BSM);
  int* bsum2= (int*)(ws + BSM2);
  float* scp = (float*)(ws + SC);
  // layer-2 aliases
  ushort* za2 = za1;                                   // [NA,64] bf16
  ushort* zt2 = zt1;                                   // [NT,64] bf16
  ushort* ota2 = oaa;                                  // [NA,64] bf16
  ushort* oaa2 = (ushort*)(ws + OAA + (size_t)NA * OUTF * 2);  // [NA,64] bf16

  const int GA = (NA + 63) / 64, GT = (NT + 63) / 64;
  const int EBL = (ETOT + 255) / 256;
  const int SCN8 = NSH * NTOT;                 // 2.4M sharded scan elements
  const int SBL8 = (SCN8 + 2047) / 2048;       // 1172
  const int SBL1 = (NTOT + 2047) / 2048;       // 147

  // ---- sharded CSR build + compact ----
  hipMemsetAsync(cur8, 0, (size_t)SCN8 * 4, stream);
  hist4_sh<<<EBL, 256, 0, stream>>>(eat_d, eta_d, eaa_d, ett_d, cur8, scp);
  sumsh_k<<<(NTOT + 255) / 256, 256, 0, stream>>>(cur8, cnt);
  scan_blk<<<SBL8, 256, 0, stream>>>(cur8, rp8 + 1, bsum, SCN8);
  scan_blk<<<1, 256, 0, stream>>>(bsum, bsum, nullptr, SBL8);
  scan_add2<<<(SCN8 + 255) / 256, 256, 0, stream>>>(rp8, cur8, bsum, SCN8);
  scan_blk<<<SBL1, 256, 0, stream>>>(cnt, rp + 1, bsum2, NTOT);
  scan_blk<<<1, 256, 0, stream>>>(bsum2, bsum2, nullptr, SBL1);
  scan_add<<<(NTOT + 255) / 256, 256, 0, stream>>>(rp, bsum2, NTOT);
  scatter_sh<<<EBL, 256, 0, stream>>>(eat_s, eat_d, eta_s, eta_d,
                                      eaa_s, eaa_d, ett_s, ett_d, cur8, ssh);
  compact_k<<<(NTOT + 255) / 256, 256, 0, stream>>>(rp8, rp, ssh, ssrc);

  // ============ Layer 1 ============
  zgemm_k<4,16,FA,float><<<dim3(GA,2),256,0,stream>>>(x_a, W_a1, b_a1,
      as_at1, ad_ta1, as_aa1, ad_aa1, aASAT, aADTA, aASAA, aADAA,
      za1, NA, HID);
  zgemm_k<4,16,FT,float><<<dim3(GT,2),256,0,stream>>>(x_t, W_t1, b_t1,
      ad_at1, as_ta1, as_tt1, ad_tt1, aTDAT, aTSTA, aTSTT, aTDTT,
      zt1, NT, HID);
  {
    // F=128: 16 nodes per block (4 waves x 4 nodes)
    const int BT = (NT + 15) / 16, BA = (NA + 15) / 16;
    AggTask T0{0,          NT, aASAT, aTDAT, za1, oat};
    AggTask T1{NT,         NA, aTSTA, aADTA, zt1, ota};
    AggTask T2{NT+NA,      NA, aASAA, aADAA, za1, oaa};
    AggTask T3{NT+2*NA,    NT, aTSTT, aTDTT, zt1, ott};
    agg_multi<128><<<2*BT + 2*BA, 256, 0, stream>>>(rp, ssrc,
        T0, T1, T2, T3, BT, BT + BA, BT + 2*BA);
  }
  score_k<HID><<<4*GA + 4*GT, 256, 0, stream>>>(ota, oaa, oat, ott,
      k1_W, k1_b, q1, scp,
      make_int4(2*GA, 4*GA, 4*GA + 2*GT, 4*GA + 4*GT),
      make_int4(NA, NA, NT, NT), make_int4(GA, GA, GT, GT), HID);
  combine2_k<<<(NA/4) + (NT/4), 256, 0, stream>>>(
      ota, oaa, scp + 0, 1.f/NA, ota, NA,
      oat, ott, scp + 2, 1.f/NT, oat, NT, ln1_g, ln1_b);

  // ============ Layer 2 (only the address path feeds the output) ============
  zgemm_k<3,8,HID,ushort><<<dim3(GA,1),256,0,stream>>>(ota, W_a2, b_a2,
      ad_ta2, as_aa2, ad_aa2, nullptr, aADTA, aASAA, aADAA, nullptr,
      za2, NA, OUTF);
  zgemm_k<1,8,HID,ushort><<<dim3(GT,1),256,0,stream>>>(oat, W_t2, b_t2,
      as_ta2, nullptr, nullptr, nullptr, aTSTA, nullptr, nullptr, nullptr,
      zt2, NT, OUTF);
  {
    // F=64: 32 nodes per block (4 waves x 8 nodes)
    const int BA2 = (NA + 31) / 32;
    AggTask T0{NT,    NA, aTSTA, aADTA, zt2, ota2};
    AggTask T1{NT+NA, NA, aASAA, aADAA, za2, oaa2};
    agg_multi<64><<<2*BA2, 256, 0, stream>>>(rp, ssrc,
        T0, T1, T1, T1, BA2, 2*BA2, 2*BA2);
  }
  score_k<OUTF><<<2*GA, 256, 0, stream>>>(ota2, oaa2, ota2, ota2,
      k2_W, k2_b, q2, scp + 4,
      make_int4(GA, 2*GA, 2*GA, 2*GA),
      make_int4(NA, NA, NA, NA), make_int4(GA, GA, GA, GA), OUTF);
  combine_final_k<<<NA/4, 256, 0, stream>>>(ota2, oaa2, scp + 4, 1.f/NA,
      ln2_g, ln2_b, lin_W, lin_b, (float*)d_out, NA);
}

// Round 9
// 518.380 us; speedup vs baseline: 2.0618x; 1.1588x over previous
//
#include <hip/hip_runtime.h>
#include <cstdint>
#include <cstddef>
#include <type_traits>

#define NA 50000
#define NT 100000
#define FA 128
#define FT 64
#define HID 128
#define OUTF 64
#define HEADS 8
#define E1 500000
#define E2 250000
#define NTOT (2*NT + 2*NA)          // concatenated dst-node space [at|ta|aa|tt]
#define ETOT (2*E1 + 2*E2)          // concatenated edge space
#define NSH 8                       // CSR build shards (== XCDs heuristic)

typedef __attribute__((ext_vector_type(8))) short short8;
typedef __attribute__((ext_vector_type(4))) float f32x4;

static __device__ __forceinline__ ushort f2b(float f) {  // f32 -> bf16 RNE
  unsigned int u = __float_as_uint(f);
  return (ushort)((u + 0x7fffu + ((u >> 16) & 1u)) >> 16);
}
static __device__ __forceinline__ float b2f(ushort b) {
  return __uint_as_float(((unsigned int)b) << 16);
}
static __device__ __forceinline__ float u2f_lo(unsigned int u) {
  return __uint_as_float(u << 16);
}
static __device__ __forceinline__ float u2f_hi(unsigned int u) {
  return __uint_as_float(u & 0xffff0000u);
}

// ============== shared GEMM building blocks (XOR-swizzled LDS) =============
// LDS elem index: row-major [row][KK] bf16, 16B slots XOR'd by (row&7) so the
// 16-rows-same-column MFMA fragment reads are conflict-free (2-way max).
template<int KK>
static __device__ __forceinline__ int lidx(int row, int off) {
  return row * KK + (off ^ ((row & 7) << 3));
}

// stage W[KK][M] f32 -> Bls[M][KK] bf16 (transposed, swizzled). Loads are
// coalesced across lanes (consecutive threads read consecutive W cols).
template<int KK, int M>
static __device__ __forceinline__ void stageB(const float* __restrict__ W,
                                              ushort* __restrict__ Bls)
{
  constexpr int TPC = 256 / M;          // threads per col
  constexpr int CH  = KK / TPC;         // k-chunk per thread
  constexpr int BL  = (CH < 16) ? CH : 16;
  int t = threadIdx.x;
  int col = t % M;
  int k0 = (t / M) * CH;
  const float* Wp = W + col;
#pragma unroll
  for (int b = 0; b < CH; b += BL) {
    float v[BL];
#pragma unroll
    for (int i = 0; i < BL; i++) v[i] = Wp[(size_t)(k0 + b + i) * M];
#pragma unroll
    for (int q = 0; q < BL / 8; q++) {
      union { ushort u[8]; uint4 x; } p;
#pragma unroll
      for (int i = 0; i < 8; i++) p.u[i] = f2b(v[q * 8 + i]);
      *reinterpret_cast<uint4*>(&Bls[lidx<KK>(col, k0 + b + q * 8)]) = p.x;
    }
  }
}

// A-tile register staging: issue all loads (MLP), write to LDS later.
template<int KK, typename AT>
struct ARegs {
  float4 f[std::is_same<AT, float>::value ? KK / 16 : 1];
  uint4  u[std::is_same<AT, float>::value ? 1 : KK / 32];
};

template<int KK, typename AT>
static __device__ __forceinline__ void loadA(const AT* __restrict__ A, int N,
                                             int row0, ARegs<KK, AT>& R)
{
  int t = threadIdx.x;
  int arow = t >> 2, ac0 = (t & 3) * (KK / 4);
  int row = row0 + arow;
  bool ok = row < N;
  const AT* Ap = A + (size_t)row * KK + ac0;
  if constexpr (std::is_same<AT, float>::value) {
#pragma unroll
    for (int j = 0; j < KK / 16; j++)
      R.f[j] = ok ? *reinterpret_cast<const float4*>(Ap + j * 4)
                  : make_float4(0.f, 0.f, 0.f, 0.f);
  } else {
#pragma unroll
    for (int j = 0; j < KK / 32; j++)
      R.u[j] = ok ? *reinterpret_cast<const uint4*>(Ap + j * 8)
                  : make_uint4(0, 0, 0, 0);
  }
}

template<int KK, typename AT>
static __device__ __forceinline__ void writeA(const ARegs<KK, AT>& R,
                                              ushort* __restrict__ Als)
{
  int t = threadIdx.x;
  int arow = t >> 2, ac0 = (t & 3) * (KK / 4);
#pragma unroll
  for (int j = 0; j < KK / 32; j++) {
    uint4 w;
    if constexpr (std::is_same<AT, float>::value) {
      union { ushort u[8]; uint4 x; } p;
      float4 a0 = R.f[2 * j], a1 = R.f[2 * j + 1];
      p.u[0] = f2b(a0.x); p.u[1] = f2b(a0.y); p.u[2] = f2b(a0.z); p.u[3] = f2b(a0.w);
      p.u[4] = f2b(a1.x); p.u[5] = f2b(a1.y); p.u[6] = f2b(a1.z); p.u[7] = f2b(a1.w);
      w = p.x;
    } else {
      w = R.u[j];
    }
    *reinterpret_cast<uint4*>(&Als[lidx<KK>(arow, ac0 + j * 8)]) = w;
  }
}

template<int KK, int NCT>
static __device__ __forceinline__ void mfma_tile(const ushort* __restrict__ Als,
    const ushort* __restrict__ Bls, f32x4* acc)
{
  int lane = threadIdx.x & 63, w = threadIdx.x >> 6;
  int l15 = lane & 15, l4 = lane >> 4;
#pragma unroll
  for (int ks = 0; ks < KK / 32; ks++) {
    short8 af = *reinterpret_cast<const short8*>(
        &Als[lidx<KK>(16 * w + l15, ks * 32 + l4 * 8)]);
#pragma unroll
    for (int n = 0; n < NCT; n++) {
      short8 bf = *reinterpret_cast<const short8*>(
          &Bls[lidx<KK>(16 * n + l15, ks * 32 + l4 * 8)]);
      acc[n] = __builtin_amdgcn_mfma_f32_16x16x32_bf16(af, bf, acc[n], 0, 0, 0);
    }
  }
}

// ====== z-projection GEMM (full M per block, TPB row-tiles, W staged once) =
// bf16 z store + fused per-node alpha epilogue. DD = head dim; NV vectors.
template<int NV, int DD, int KK, int M, int TPB, typename AT>
__global__ __launch_bounds__(256) void zgemm_k(
    const AT* __restrict__ A, const float* __restrict__ W,
    const float* __restrict__ bias,
    const float* __restrict__ v0, const float* __restrict__ v1,
    const float* __restrict__ v2, const float* __restrict__ v3,
    float* __restrict__ o0, float* __restrict__ o1,
    float* __restrict__ o2, float* __restrict__ o3,
    ushort* __restrict__ Cb, int N)
{
  constexpr int NCT = M / 16;
  __shared__ __align__(16) ushort Bls[M * KK];
  __shared__ __align__(16) ushort Als[64 * KK];
  int t = threadIdx.x, w = t >> 6, lane = t & 63;
  int l15 = lane & 15, l4 = lane >> 4;
  int ntiles = (N + 63) >> 6;
  int tile0 = blockIdx.x * TPB;
  int nt = min(TPB, ntiles - tile0);

  stageB<KK, M>(W, Bls);
  ARegs<KK, AT> R;
  loadA<KK, AT>(A, N, tile0 * 64, R);

  // hoist per-column constants
  float bv[NCT], aw0[NCT], aw1[NCT], aw2[NCT], aw3[NCT];
#pragma unroll
  for (int n = 0; n < NCT; n++) {
    int col = 16 * n + l15;
    bv[n] = bias[col];
    int head = (DD == 16) ? n : (n * 2 + (l15 >> 3));
    int vi = head * DD + (l15 & (DD - 1));
    aw0[n] = v0[vi];
    aw1[n] = (NV > 1) ? v1[vi] : 0.f;
    aw2[n] = (NV > 2) ? v2[vi] : 0.f;
    aw3[n] = (NV > 3) ? v3[vi] : 0.f;
  }

  for (int i = 0; i < nt; i++) {
    int row0 = (tile0 + i) * 64;
    __syncthreads();
    writeA<KK, AT>(R, Als);
    __syncthreads();
    if (i + 1 < nt) loadA<KK, AT>(A, N, row0 + 64, R);
    f32x4 acc[NCT];
#pragma unroll
    for (int n = 0; n < NCT; n++) acc[n] = (f32x4){0.f, 0.f, 0.f, 0.f};
    mfma_tile<KK, NCT>(Als, Bls, acc);

#pragma unroll
    for (int n = 0; n < NCT; n++) {
      int col = 16 * n + l15;
      int head = (DD == 16) ? n : (n * 2 + (l15 >> 3));
#pragma unroll
      for (int r = 0; r < 4; r++) {
        int row = row0 + 16 * w + l4 * 4 + r;
        float v = acc[n][r] + bv[n];
        if (row < N) Cb[(size_t)row * M + col] = f2b(v);
        float a0 = v * aw0[n], a1 = v * aw1[n], a2 = v * aw2[n], a3 = v * aw3[n];
#pragma unroll
        for (int o = 1; o < DD; o <<= 1) {
          a0 += __shfl_xor(a0, o);
          if (NV > 1) a1 += __shfl_xor(a1, o);
          if (NV > 2) a2 += __shfl_xor(a2, o);
          if (NV > 3) a3 += __shfl_xor(a3, o);
        }
        if ((l15 & (DD - 1)) == 0 && row < N) {
          o0[(size_t)row * 8 + head] = a0;
          if (NV > 1) o1[(size_t)row * 8 + head] = a1;
          if (NV > 2) o2[(size_t)row * 8 + head] = a2;
          if (NV > 3) o3[(size_t)row * 8 + head] = a3;
        }
      }
    }
  }
}

// ====== multi-task score GEMM: atomicAdd(scp[t], sum tanh(C+b)*q) ==========
template<int KK, int M, int TPB>
__global__ __launch_bounds__(256) void score_k(
    const ushort* __restrict__ A0, const ushort* __restrict__ A1,
    const ushort* __restrict__ A2, const ushort* __restrict__ A3,
    const float* __restrict__ W, const float* __restrict__ bias,
    const float* __restrict__ qv, float* __restrict__ scp,
    int4 cumB, int4 Ns)
{
  constexpr int NCT = M / 16;
  __shared__ __align__(16) ushort Bls[M * KK];
  __shared__ __align__(16) ushort Als[64 * KK];
  __shared__ float red[4];
  int b = blockIdx.x;
  int tsk, bbase, N; const ushort* A;
  if      (b < cumB.x) { tsk = 0; bbase = 0;      N = Ns.x; A = A0; }
  else if (b < cumB.y) { tsk = 1; bbase = cumB.x; N = Ns.y; A = A1; }
  else if (b < cumB.z) { tsk = 2; bbase = cumB.y; N = Ns.z; A = A2; }
  else                 { tsk = 3; bbase = cumB.z; N = Ns.w; A = A3; }
  int t = threadIdx.x, w = t >> 6, lane = t & 63;
  int l15 = lane & 15, l4 = lane >> 4;
  int ntiles = (N + 63) >> 6;
  int tile0 = (b - bbase) * TPB;
  int nt = min(TPB, ntiles - tile0);

  stageB<KK, M>(W, Bls);
  ARegs<KK, ushort> R;
  loadA<KK, ushort>(A, N, tile0 * 64, R);

  float bb[NCT], qb[NCT];
#pragma unroll
  for (int n = 0; n < NCT; n++) {
    int col = 16 * n + l15;
    bb[n] = bias[col]; qb[n] = qv[col];
  }

  float ls = 0.f;
  for (int i = 0; i < nt; i++) {
    int row0 = (tile0 + i) * 64;
    __syncthreads();
    writeA<KK, ushort>(R, Als);
    __syncthreads();
    if (i + 1 < nt) loadA<KK, ushort>(A, N, row0 + 64, R);
    f32x4 acc[NCT];
#pragma unroll
    for (int n = 0; n < NCT; n++) acc[n] = (f32x4){0.f, 0.f, 0.f, 0.f};
    mfma_tile<KK, NCT>(Als, Bls, acc);
#pragma unroll
    for (int n = 0; n < NCT; n++) {
#pragma unroll
      for (int r = 0; r < 4; r++) {
        int row = row0 + 16 * w + l4 * 4 + r;
        if (row < N) ls += tanhf(acc[n][r] + bb[n]) * qb[n];
      }
    }
  }
#pragma unroll
  for (int o = 32; o > 0; o >>= 1) ls += __shfl_xor(ls, o);
  if (lane == 0) red[w] = ls;
  __syncthreads();
  if (t == 0) atomicAdd(&scp[tsk], red[0] + red[1] + red[2] + red[3]);
}

// ============== XCD-sharded CSR build + compaction =========================
__global__ void hist4_sh(const int* __restrict__ d0, const int* __restrict__ d1,
    const int* __restrict__ d2, const int* __restrict__ d3,
    int* __restrict__ cnt8, float* __restrict__ scp)
{
  if (blockIdx.x == 0 && threadIdx.x < 8) scp[threadIdx.x] = 0.f;
  int e = blockIdx.x * 256 + threadIdx.x;
  int sh = blockIdx.x & (NSH - 1);
  int d;
  if      (e < E1)          d = d0[e];
  else if (e < 2*E1)        d = d1[e - E1] + NT;
  else if (e < 2*E1 + E2)   d = d2[e - 2*E1] + NT + NA;
  else if (e < ETOT)        d = d3[e - 2*E1 - E2] + NT + 2*NA;
  else return;
  atomicAdd(&cnt8[sh * NTOT + d], 1);
}

__global__ void scatter_sh(const int* __restrict__ s0, const int* __restrict__ d0,
    const int* __restrict__ s1, const int* __restrict__ d1,
    const int* __restrict__ s2, const int* __restrict__ d2,
    const int* __restrict__ s3, const int* __restrict__ d3,
    int* __restrict__ cur8, int* __restrict__ ssh)
{
  int e = blockIdx.x * 256 + threadIdx.x;
  int sh = blockIdx.x & (NSH - 1);
  int d, s;
  if      (e < E1)          { d = d0[e];                           s = s0[e]; }
  else if (e < 2*E1)        { d = d1[e - E1] + NT;                 s = s1[e - E1]; }
  else if (e < 2*E1 + E2)   { d = d2[e - 2*E1] + NT + NA;          s = s2[e - 2*E1]; }
  else if (e < ETOT)        { d = d3[e - 2*E1 - E2] + NT + 2*NA;   s = s3[e - 2*E1 - E2]; }
  else return;
  int p = atomicAdd(&cur8[sh * NTOT + d], 1);
  ssh[p] = s;
}

// per-node total degree = sum of the 8 shard counts (run before cnt8 scan)
__global__ void sumsh_k(const int* __restrict__ cnt8, int* __restrict__ cnt)
{
  int g = blockIdx.x * 256 + threadIdx.x;
  if (g >= NTOT) return;
  int s = 0;
#pragma unroll
  for (int k = 0; k < NSH; k++) s += cnt8[k * NTOT + g];
  cnt[g] = s;
}

// merge each node's 8 shard-segments into the contiguous final CSR order
__global__ void compact_k(const int* __restrict__ rp8, const int* __restrict__ rp,
    const int* __restrict__ ssh, int* __restrict__ ssrc)
{
  int g = blockIdx.x * 256 + threadIdx.x;
  if (g >= NTOT) return;
  int w = rp[g];
#pragma unroll
  for (int s = 0; s < NSH; s++) {
    int b0 = rp8[s * NTOT + g], b1 = rp8[s * NTOT + g + 1];
    for (int e = b0; e < b1; e++) ssrc[w++] = ssh[e];
  }
}

// per-block inclusive scan (256 thr x 8) of in -> rp1 (=rp+1); totals -> bsum
__global__ __launch_bounds__(256) void scan_blk(const int* __restrict__ in,
    int* __restrict__ rp1, int* __restrict__ bsum, int n)
{
  __shared__ int sh[256];
  int base = blockIdx.x * 2048;
  int t = threadIdx.x;
  int v[8]; int s = 0;
#pragma unroll
  for (int k = 0; k < 8; k++) {
    int i = base + t * 8 + k;
    v[k] = (i < n) ? in[i] : 0; s += v[k];
  }
  sh[t] = s; __syncthreads();
  for (int o = 1; o < 256; o <<= 1) {
    int x = (t >= o) ? sh[t - o] : 0;
    __syncthreads(); sh[t] += x; __syncthreads();
  }
  int run = (t == 0) ? 0 : sh[t - 1];
  if (t == 255 && bsum) bsum[blockIdx.x] = sh[255];
#pragma unroll
  for (int k = 0; k < 8; k++) {
    int i = base + t * 8 + k;
    run += v[k];
    if (i < n) rp1[i] = run;
  }
}

// add inclusive block-offsets; writes rp[0]=0 and cursor init cur[i]=rp[i]
__global__ void scan_add2(int* __restrict__ rp, int* __restrict__ cur,
    const int* __restrict__ bsA, int n)
{
  int i = blockIdx.x * blockDim.x + threadIdx.x;
  if (i == 0) { rp[0] = 0; cur[0] = 0; }
  if (i < n) {
    int blk = i >> 11;
    int base = blk ? bsA[blk - 1] : 0;
    int v = rp[i + 1] + base;
    rp[i + 1] = v;
    if (i + 1 < n) cur[i + 1] = v;
  }
}

// add inclusive block-offsets (no cursor); writes rp[0]=0
__global__ void scan_add(int* __restrict__ rp, const int* __restrict__ bsA, int n)
{
  int i = blockIdx.x * blockDim.x + threadIdx.x;
  if (i == 0) rp[0] = 0;
  if (i < n) {
    int blk = i >> 11;
    int base = blk ? bsA[blk - 1] : 0;
    rp[i + 1] += base;
  }
}

// =============== atomic-free GAT aggregation, node per lane-group ==========
struct AggTask {
  int g0, Nd;
  const float* als; const float* ald;
  const ushort* z;  ushort* out;
};

template<int F>
__global__ __launch_bounds__(256) void agg_multi(const int* __restrict__ rp,
    const int* __restrict__ ssrc, AggTask T0, AggTask T1, AggTask T2, AggTask T3,
    int c1, int c2, int c3)
{
  constexpr int LPN = (F == 128) ? 16 : 8;   // lanes per node
  constexpr int NPW = 64 / LPN;              // nodes per wave
  int b = blockIdx.x;
  AggTask T; int lb;
  if      (b < c1) { T = T0; lb = b; }
  else if (b < c2) { T = T1; lb = b - c1; }
  else if (b < c3) { T = T2; lb = b - c2; }
  else             { T = T3; lb = b - c3; }
  int wv = threadIdx.x >> 6, lane = threadIdx.x & 63;
  int grp = lane / LPN, lg = lane % LPN;
  int n = (lb * 4 + wv) * NPW + grp;
  if (n >= T.Nd) return;
  int g = T.g0 + n;
  int start = rp[g], end = rp[g + 1];
  int hh = (F == 128) ? (lg >> 1) : lg;      // head owning this lane's feats
  float ad_h = T.ald[(size_t)n * 8 + hh];

  float den = 0.f;
  float acc[8] = {};
  for (int e = start; e < end; e++) {
    int sn = ssrc[e];
    uint4 zv = *reinterpret_cast<const uint4*>(T.z + (size_t)sn * F + lg * 8);
    float a = T.als[(size_t)sn * 8 + hh] + ad_h;
    a = a > 0.f ? a : 0.2f * a;
    float p = __expf(fminf(a, 30.f));
    den += p;
    acc[0] = fmaf(p, u2f_lo(zv.x), acc[0]);
    acc[1] = fmaf(p, u2f_hi(zv.x), acc[1]);
    acc[2] = fmaf(p, u2f_lo(zv.y), acc[2]);
    acc[3] = fmaf(p, u2f_hi(zv.y), acc[3]);
    acc[4] = fmaf(p, u2f_lo(zv.z), acc[4]);
    acc[5] = fmaf(p, u2f_hi(zv.z), acc[5]);
    acc[6] = fmaf(p, u2f_lo(zv.w), acc[6]);
    acc[7] = fmaf(p, u2f_hi(zv.w), acc[7]);
  }
  float inv = 1.f / fmaxf(den, 1e-16f);
  unsigned int pk[4];
#pragma unroll
  for (int k2 = 0; k2 < 4; k2++)
    pk[k2] = (unsigned int)f2b(fmaxf(acc[2*k2] * inv, 0.f))
           | ((unsigned int)f2b(fmaxf(acc[2*k2+1] * inv, 0.f)) << 16);
  *reinterpret_cast<uint4*>(T.out + (size_t)n * F + lg * 8)
      = make_uint4(pk[0], pk[1], pk[2], pk[3]);
}

// ---- semantic softmax (K=2) combine + LayerNorm + ReLU, 2 tasks, F=128 ----
__global__ __launch_bounds__(256) void combine2_k(
    const ushort* __restrict__ o00, const ushort* __restrict__ o01,
    const float* __restrict__ sc0, float invn0, ushort* __restrict__ out0, int N0,
    const ushort* __restrict__ o10, const ushort* __restrict__ o11,
    const float* __restrict__ sc1, float invn1, ushort* __restrict__ out1, int N1,
    const float* __restrict__ g, const float* __restrict__ bb)
{
  int c1 = (N0 + 3) / 4;
  int b = blockIdx.x;
  const ushort *o0, *o1; const float* sc; float invn; ushort* outp; int N, lb;
  if (b < c1) { o0=o00; o1=o01; sc=sc0; invn=invn0; outp=out0; N=N0; lb=b; }
  else        { o0=o10; o1=o11; sc=sc1; invn=invn1; outp=out1; N=N1; lb=b-c1; }
  int wv = threadIdx.x >> 6, lane = threadIdx.x & 63;
  int n = lb * 4 + wv;
  if (n >= N) return;
  float s0 = sc[0] * invn, s1 = sc[1] * invn;
  float mx = fmaxf(s0, s1);
  float e0 = __expf(s0 - mx), e1 = __expf(s1 - mx);
  float w0 = e0 / (e0 + e1), w1 = e1 / (e0 + e1);
  float x[2];
#pragma unroll
  for (int jj = 0; jj < 2; jj++) {
    int idx = lane + 64 * jj;
    x[jj] = w0 * b2f(o0[(size_t)n * 128 + idx]) + w1 * b2f(o1[(size_t)n * 128 + idx]);
  }
  float sum = x[0] + x[1];
#pragma unroll
  for (int o = 32; o > 0; o >>= 1) sum += __shfl_xor(sum, o);
  float mu = sum / 128.f;
  float vs = 0.f;
#pragma unroll
  for (int jj = 0; jj < 2; jj++) { float dd = x[jj] - mu; vs = fmaf(dd, dd, vs); }
#pragma unroll
  for (int o = 32; o > 0; o >>= 1) vs += __shfl_xor(vs, o);
  float rstd = rsqrtf(vs / 128.f + 1e-5f);
#pragma unroll
  for (int jj = 0; jj < 2; jj++) {
    int idx = lane + 64 * jj;
    float y = (x[jj] - mu) * rstd * g[idx] + bb[idx];
    outp[(size_t)n * 128 + idx] = f2b(fmaxf(y, 0.f));
  }
}

// ---- layer-2 combine + LN + ReLU + final linear [64]->[2], F=64 ----------
__global__ __launch_bounds__(256) void combine_final_k(
    const ushort* __restrict__ o0, const ushort* __restrict__ o1,
    const float* __restrict__ sc, float invn,
    const float* __restrict__ g, const float* __restrict__ bb,
    const float* __restrict__ lw, const float* __restrict__ lb,
    float* __restrict__ outp, int N)
{
  int wv = threadIdx.x >> 6, lane = threadIdx.x & 63;
  int n = blockIdx.x * 4 + wv;
  if (n >= N) return;
  float s0 = sc[0] * invn, s1 = sc[1] * invn;
  float mx = fmaxf(s0, s1);
  float e0 = __expf(s0 - mx), e1 = __expf(s1 - mx);
  float w0 = e0 / (e0 + e1), w1 = e1 / (e0 + e1);
  float x = w0 * b2f(o0[(size_t)n * 64 + lane]) + w1 * b2f(o1[(size_t)n * 64 + lane]);
  float sum = x;
#pragma unroll
  for (int o = 32; o > 0; o >>= 1) sum += __shfl_xor(sum, o);
  float mu = sum / 64.f;
  float dd = x - mu;
  float vs = dd * dd;
#pragma unroll
  for (int o = 32; o > 0; o >>= 1) vs += __shfl_xor(vs, o);
  float rstd = rsqrtf(vs / 64.f + 1e-5f);
  float y = fmaxf((x - mu) * rstd * g[lane] + bb[lane], 0.f);
  float p0 = y * lw[lane * 2 + 0];
  float p1 = y * lw[lane * 2 + 1];
#pragma unroll
  for (int o = 32; o > 0; o >>= 1) { p0 += __shfl_xor(p0, o); p1 += __shfl_xor(p1, o); }
  if (lane == 0) {
    outp[(size_t)n * 2 + 0] = p0 + lb[0];
    outp[(size_t)n * 2 + 1] = p1 + lb[1];
  }
}

extern "C" void kernel_launch(void* const* d_in, const int* in_sizes, int n_in,
                              void* d_out, int out_size, void* d_ws, size_t ws_size,
                              hipStream_t stream)
{
  (void)in_sizes; (void)n_in; (void)out_size;
  const float* x_a = (const float*)d_in[0];
  const float* x_t = (const float*)d_in[1];
  const int* eat_s = (const int*)d_in[2];
  const int* eat_d = (const int*)d_in[3];
  const int* eta_s = (const int*)d_in[4];
  const int* eta_d = (const int*)d_in[5];
  const int* eaa_s = (const int*)d_in[6];
  const int* eaa_d = (const int*)d_in[7];
  const int* ett_s = (const int*)d_in[8];
  const int* ett_d = (const int*)d_in[9];
  const float* W_a1 = (const float*)d_in[10]; const float* b_a1 = (const float*)d_in[11];
  const float* W_t1 = (const float*)d_in[12]; const float* b_t1 = (const float*)d_in[13];
  const float* as_at1 = (const float*)d_in[14]; const float* ad_at1 = (const float*)d_in[15];
  const float* as_ta1 = (const float*)d_in[16]; const float* ad_ta1 = (const float*)d_in[17];
  const float* as_aa1 = (const float*)d_in[18]; const float* ad_aa1 = (const float*)d_in[19];
  const float* as_tt1 = (const float*)d_in[20]; const float* ad_tt1 = (const float*)d_in[21];
  const float* k1_W = (const float*)d_in[22]; const float* k1_b = (const float*)d_in[23];
  const float* q1   = (const float*)d_in[24];
  const float* W_a2 = (const float*)d_in[25]; const float* b_a2 = (const float*)d_in[26];
  const float* W_t2 = (const float*)d_in[27]; const float* b_t2 = (const float*)d_in[28];
  const float* as_ta2 = (const float*)d_in[31]; const float* ad_ta2 = (const float*)d_in[32];
  const float* as_aa2 = (const float*)d_in[33]; const float* ad_aa2 = (const float*)d_in[34];
  const float* k2_W = (const float*)d_in[37]; const float* k2_b = (const float*)d_in[38];
  const float* q2   = (const float*)d_in[39];
  const float* ln1_g = (const float*)d_in[40]; const float* ln1_b = (const float*)d_in[41];
  const float* ln2_g = (const float*)d_in[42]; const float* ln2_b = (const float*)d_in[43];
  const float* lin_W = (const float*)d_in[44]; const float* lin_b = (const float*)d_in[45];

  char* ws = (char*)d_ws;
  size_t off = 0;
  auto alloc = [&](size_t bytes) {
    size_t o = off; off += (bytes + 255) & ~(size_t)255; return o;
  };
  size_t ZA1 = alloc((size_t)NA * HID * 2);     // bf16 z_a; layer2 za2 aliases
  size_t ZT1 = alloc((size_t)NT * HID * 2);     // bf16 z_t; layer2 zt2 aliases
  size_t OTA = alloc((size_t)NA * HID * 2);     // bf16 o_ta -> xa1 in-place
  size_t OAA = alloc((size_t)NA * HID * 2);     // bf16 o_aa; L2: ota2|oaa2 alias
  size_t OAT = alloc((size_t)NT * HID * 2);     // bf16 o_at -> xt1 in-place
  size_t OTT = alloc((size_t)NT * HID * 2);
  size_t A_AS_AT = alloc((size_t)NA * 8 * 4);
  size_t A_AD_TA = alloc((size_t)NA * 8 * 4);
  size_t A_AS_AA = alloc((size_t)NA * 8 * 4);
  size_t A_AD_AA = alloc((size_t)NA * 8 * 4);
  size_t A_T_D_AT = alloc((size_t)NT * 8 * 4);
  size_t A_T_S_TA = alloc((size_t)NT * 8 * 4);
  size_t A_T_S_TT = alloc((size_t)NT * 8 * 4);
  size_t A_T_D_TT = alloc((size_t)NT * 8 * 4);
  // sharded CSR build + compacted final CSR
  size_t RP8  = alloc(((size_t)NSH * NTOT + 1) * 4);
  size_t CUR8 = alloc((size_t)NSH * NTOT * 4);  // doubles as sharded hist
  size_t SSH  = alloc((size_t)ETOT * 4);
  size_t RP   = alloc((size_t)(NTOT + 1) * 4);
  size_t CNT  = alloc((size_t)NTOT * 4);
  size_t SS   = alloc((size_t)ETOT * 4);
  size_t BSM  = alloc(2048 * 4);
  size_t BSM2 = alloc(256 * 4);
  size_t SC   = alloc(256);                     // 6 score accumulators
  if (off > ws_size) return;                    // fail visibly

  ushort* za1 = (ushort*)(ws + ZA1);
  ushort* zt1 = (ushort*)(ws + ZT1);
  ushort* ota = (ushort*)(ws + OTA);
  ushort* oaa = (ushort*)(ws + OAA);
  ushort* oat = (ushort*)(ws + OAT);
  ushort* ott = (ushort*)(ws + OTT);
  float* aASAT = (float*)(ws + A_AS_AT);
  float* aADTA = (float*)(ws + A_AD_TA);
  float* aASAA = (float*)(ws + A_AS_AA);
  float* aADAA = (float*)(ws + A_AD_AA);
  float* aTDAT = (float*)(ws + A_T_D_AT);
  float* aTSTA = (float*)(ws + A_T_S_TA);
  float* aTSTT = (float*)(ws + A_T_S_TT);
  float* aTDTT = (float*)(ws + A_T_D_TT);
  int* rp8  = (int*)(ws + RP8);
  int* cur8 = (int*)(ws + CUR8);
  int* ssh  = (int*)(ws + SSH);
  int* rp   = (int*)(ws + RP);
  int* cnt  = (int*)(ws + CNT);
  int* ssrc = (int*)(ws + SS);
  int* bsum = (int*)(ws + BSM);
  int* bsum2= (int*)(ws + BSM2);
  float* scp = (float*)(ws + SC);
  // layer-2 aliases
  ushort* za2 = za1;                                   // [NA,64] bf16
  ushort* zt2 = zt1;                                   // [NT,64] bf16
  ushort* ota2 = oaa;                                  // [NA,64] bf16
  ushort* oaa2 = (ushort*)(ws + OAA + (size_t)NA * OUTF * 2);  // [NA,64] bf16

  const int TA = (NA + 63) / 64, TT = (NT + 63) / 64;  // row tiles
  const int EBL = (ETOT + 255) / 256;
  const int SCN8 = NSH * NTOT;
  const int SBL8 = (SCN8 + 2047) / 2048;
  const int SBL1 = (NTOT + 2047) / 2048;

  // ---- sharded CSR build + compact ----
  hipMemsetAsync(cur8, 0, (size_t)SCN8 * 4, stream);
  hist4_sh<<<EBL, 256, 0, stream>>>(eat_d, eta_d, eaa_d, ett_d, cur8, scp);
  sumsh_k<<<(NTOT + 255) / 256, 256, 0, stream>>>(cur8, cnt);
  scan_blk<<<SBL8, 256, 0, stream>>>(cur8, rp8 + 1, bsum, SCN8);
  scan_blk<<<1, 256, 0, stream>>>(bsum, bsum, nullptr, SBL8);
  scan_add2<<<(SCN8 + 255) / 256, 256, 0, stream>>>(rp8, cur8, bsum, SCN8);
  scan_blk<<<SBL1, 256, 0, stream>>>(cnt, rp + 1, bsum2, NTOT);
  scan_blk<<<1, 256, 0, stream>>>(bsum2, bsum2, nullptr, SBL1);
  scan_add<<<(NTOT + 255) / 256, 256, 0, stream>>>(rp, bsum2, NTOT);
  scatter_sh<<<EBL, 256, 0, stream>>>(eat_s, eat_d, eta_s, eta_d,
                                      eaa_s, eaa_d, ett_s, ett_d, cur8, ssh);
  compact_k<<<(NTOT + 255) / 256, 256, 0, stream>>>(rp8, rp, ssh, ssrc);

  // ============ Layer 1 ============
  zgemm_k<4,16,FA,HID,2,float><<<(TA+1)/2,256,0,stream>>>(x_a, W_a1, b_a1,
      as_at1, ad_ta1, as_aa1, ad_aa1, aASAT, aADTA, aASAA, aADAA, za1, NA);
  zgemm_k<4,16,FT,HID,4,float><<<(TT+3)/4,256,0,stream>>>(x_t, W_t1, b_t1,
      ad_at1, as_ta1, as_tt1, ad_tt1, aTDAT, aTSTA, aTSTT, aTDTT, zt1, NT);
  {
    // F=128: 16 nodes per block (4 waves x 4 nodes)
    const int BT = (NT + 15) / 16, BA = (NA + 15) / 16;
    AggTask T0{0,          NT, aASAT, aTDAT, za1, oat};
    AggTask T1{NT,         NA, aTSTA, aADTA, zt1, ota};
    AggTask T2{NT+NA,      NA, aASAA, aADAA, za1, oaa};
    AggTask T3{NT+2*NA,    NT, aTSTT, aTDTT, zt1, ott};
    agg_multi<128><<<2*BT + 2*BA, 256, 0, stream>>>(rp, ssrc,
        T0, T1, T2, T3, BT, BT + BA, BT + 2*BA);
  }
  {
    const int bA = (TA + 3) / 4, bT = (TT + 3) / 4;
    score_k<HID,HID,4><<<2*bA + 2*bT, 256, 0, stream>>>(ota, oaa, oat, ott,
        k1_W, k1_b, q1, scp,
        make_int4(bA, 2*bA, 2*bA + bT, 2*bA + 2*bT),
        make_int4(NA, NA, NT, NT));
  }
  combine2_k<<<(NA/4) + (NT/4), 256, 0, stream>>>(
      ota, oaa, scp + 0, 1.f/NA, ota, NA,
      oat, ott, scp + 2, 1.f/NT, oat, NT, ln1_g, ln1_b);

  // ============ Layer 2 (only the address path feeds the output) ============
  zgemm_k<3,8,HID,OUTF,2,ushort><<<(TA+1)/2,256,0,stream>>>(ota, W_a2, b_a2,
      ad_ta2, as_aa2, ad_aa2, nullptr, aADTA, aASAA, aADAA, nullptr, za2, NA);
  zgemm_k<1,8,HID,OUTF,4,ushort><<<(TT+3)/4,256,0,stream>>>(oat, W_t2, b_t2,
      as_ta2, nullptr, nullptr, nullptr, aTSTA, nullptr, nullptr, nullptr, zt2, NT);
  {
    // F=64: 32 nodes per block (4 waves x 8 nodes)
    const int BA2 = (NA + 31) / 32;
    AggTask T0{NT,    NA, aTSTA, aADTA, zt2, ota2};
    AggTask T1{NT+NA, NA, aASAA, aADAA, za2, oaa2};
    agg_multi<64><<<2*BA2, 256, 0, stream>>>(rp, ssrc,
        T0, T1, T1, T1, BA2, 2*BA2, 2*BA2);
  }
  {
    const int bA = (TA + 3) / 4;
    score_k<OUTF,OUTF,4><<<2*bA, 256, 0, stream>>>(ota2, oaa2, ota2, ota2,
        k2_W, k2_b, q2, scp + 4,
        make_int4(bA, 2*bA, 2*bA, 2*bA),
        make_int4(NA, NA, NA, NA));
  }
  combine_final_k<<<NA/4, 256, 0, stream>>>(ota2, oaa2, scp + 4, 1.f/NA,
      ln2_g, ln2_b, lin_W, lin_b, (float*)d_out, NA);
}